// Round 1
// baseline (2805.032 us; speedup 1.0000x reference)
//
#include <hip/hip_runtime.h>
#include <hip/hip_bf16.h>

typedef __hip_bfloat16 bf16;
typedef __bf16 bf16x8 __attribute__((ext_vector_type(8)));
typedef float  f32x4  __attribute__((ext_vector_type(4)));

#define NB 8
#define NQ 900
#define DM 256
#define NHEADS 8
#define DHEAD 32
#define NFF 1024
#define NLAY 6
#define NS 13294
#define BQ (NB*NQ)            // 7200
#define LN_EPS 1e-5f
#define ATT_SCALE 0.17677669529663687f   // 1/sqrt(32)
#define SAK 40                // LDS row stride (bf16): 80B, stride-5 in 16B units

__device__ __forceinline__ float bfd(const bf16* p, size_t i){ return __bfloat162float(p[i]); }

// mode: 0 = fp32 (internal), 1 = bf16 (internal), 2 = external (dtype per flag)
__device__ __forceinline__ float ldv(const void* p, size_t i, int mode, bool extF32)
{
    if (mode == 0) return ((const float*)p)[i];
    if (mode == 1) return bfd((const bf16*)p, i);
    return extF32 ? ((const float*)p)[i] : bfd((const bf16*)p, i);
}

// unpack 8 bf16 (16B) to floats
__device__ __forceinline__ void unpack8(uint4 u, float* t)
{
    t[0] = __uint_as_float((u.x & 0xffffu) << 16);
    t[1] = __uint_as_float(u.x & 0xffff0000u);
    t[2] = __uint_as_float((u.y & 0xffffu) << 16);
    t[3] = __uint_as_float(u.y & 0xffff0000u);
    t[4] = __uint_as_float((u.z & 0xffffu) << 16);
    t[5] = __uint_as_float(u.z & 0xffff0000u);
    t[6] = __uint_as_float((u.w & 0xffffu) << 16);
    t[7] = __uint_as_float(u.w & 0xffff0000u);
}

// ---------------------------------------------------------------------------
// dtype detector (inputs proved fp32; kept for robustness)
// ---------------------------------------------------------------------------
__global__ __launch_bounds__(256) void detect_dtype(const void* __restrict__ tgt,
        float* __restrict__ flag)
{
    __shared__ float red[256];
    int t = threadIdx.x;
    const unsigned short* u = (const unsigned short*)tgt;
    float m = 0.f;
    for (int i = t; i < 2048; i += 256) {
        unsigned int bits = ((unsigned int)u[i]) << 16;
        float v = fabsf(__uint_as_float(bits));
        if (!isfinite(v)) v = 1e30f;
        m = fmaxf(m, v);
    }
    red[t] = m;
    __syncthreads();
    for (int st = 128; st; st >>= 1) {
        if (t < st) red[t] = fmaxf(red[t], red[t + st]);
        __syncthreads();
    }
    if (t == 0) flag[0] = (red[0] > 1e8f) ? 1.f : 0.f;
}

// ---------------------------------------------------------------------------
// weight pre-convert: external dtype -> bf16, 8 elems/thread (size = grid*2048)
// ---------------------------------------------------------------------------
__global__ __launch_bounds__(256) void convert_w(const void* __restrict__ src,
        bf16* __restrict__ dst, const float* __restrict__ flagp)
{
    const bool ef = flagp[0] > 0.5f;
    size_t base = ((size_t)blockIdx.x * 256 + threadIdx.x) * 8;
    if (ef) {
        const float* s = (const float*)src + base;
        float4 f0 = *(const float4*)s;
        float4 f1 = *(const float4*)(s + 4);
        union { bf16 a[8]; uint4 u; } t;
        t.a[0] = __float2bfloat16(f0.x); t.a[1] = __float2bfloat16(f0.y);
        t.a[2] = __float2bfloat16(f0.z); t.a[3] = __float2bfloat16(f0.w);
        t.a[4] = __float2bfloat16(f1.x); t.a[5] = __float2bfloat16(f1.y);
        t.a[6] = __float2bfloat16(f1.z); t.a[7] = __float2bfloat16(f1.w);
        *(uint4*)(dst + base) = t.u;
    } else {
        *(uint4*)(dst + base) = *(const uint4*)((const bf16*)src + base);
    }
}

// ---------------------------------------------------------------------------
// A-fragment loader for direct MFMA GEMM: 8 contiguous elems at (row, col)
// ---------------------------------------------------------------------------
__device__ __forceinline__ bf16x8 load_afrag(const void* A, bool abf, int row,
        int K, int col, bool valid)
{
    union { bf16 a[8]; uint4 u; bf16x8 v; } t;
    if (!valid) {
        t.u = make_uint4(0u, 0u, 0u, 0u);
        return t.v;
    }
    if (abf) {
        t.u = *(const uint4*)((const bf16*)A + (size_t)row * K + col);
        return t.v;
    }
    const float* ap = (const float*)A + (size_t)row * K + col;
    float4 f0 = *(const float4*)ap;
    float4 f1 = *(const float4*)(ap + 4);
    t.a[0] = __float2bfloat16(f0.x); t.a[1] = __float2bfloat16(f0.y);
    t.a[2] = __float2bfloat16(f0.z); t.a[3] = __float2bfloat16(f0.w);
    t.a[4] = __float2bfloat16(f1.x); t.a[5] = __float2bfloat16(f1.y);
    t.a[6] = __float2bfloat16(f1.z); t.a[7] = __float2bfloat16(f1.w);
    return t.v;
}

// ---------------------------------------------------------------------------
// Direct MFMA GEMM: no LDS, no barriers. Block = 64 rows x 256 cols.
// 4 waves as 2x2: wave (wr,wc) computes 32 rows x 128 cols = 16 MFMAs/K-step.
// A: [M,K] per amode; Wb: [N,K] pre-converted bf16 (L2-resident);
// fragments loaded straight from global (contiguous 16B per lane).
// grid: (N/256, ceil(M/64)).
// ---------------------------------------------------------------------------
__global__ __launch_bounds__(256) void gemm_direct(const void* __restrict__ A, int amode,
        const bf16* __restrict__ Wb, const void* __restrict__ bias,
        void* __restrict__ C, int cmode, int M, int N, int K, int relu,
        const float* __restrict__ flagp)
{
    const bool ef = flagp[0] > 0.5f;
    const bool a_bf16 = (amode == 1) || (amode == 2 && !ef);
    const int tid  = threadIdx.x;
    const int w    = tid >> 6;
    const int lane = tid & 63;
    const int lm   = lane & 15;
    const int lq   = lane >> 4;
    const int wr   = w >> 1;            // 0..1 : row half
    const int wc   = w & 1;             // 0..1 : col half
    const int m0   = blockIdx.y * 64;
    const int n0   = blockIdx.x * 256;

    const int r0 = m0 + wr * 32 + lm;
    const int r1 = r0 + 16;
    const bool v0 = r0 < M, v1 = r1 < M;
    const bf16* wbase = Wb + (size_t)(n0 + wc * 128 + lm) * K + lq * 8;

    f32x4 acc[2][8];
    #pragma unroll
    for (int mi = 0; mi < 2; mi++)
        #pragma unroll
        for (int nt = 0; nt < 8; nt++)
            acc[mi][nt] = (f32x4){0.f, 0.f, 0.f, 0.f};

    for (int k0 = 0; k0 < K; k0 += 32) {
        bf16x8 af0 = load_afrag(A, a_bf16, r0, K, k0 + lq * 8, v0);
        bf16x8 af1 = load_afrag(A, a_bf16, r1, K, k0 + lq * 8, v1);
        #pragma unroll
        for (int nt = 0; nt < 8; nt++) {
            bf16x8 bfr = *(const bf16x8*)(wbase + (size_t)nt * 16 * K + k0);
            acc[0][nt] = __builtin_amdgcn_mfma_f32_16x16x32_bf16(af0, bfr, acc[0][nt], 0, 0, 0);
            acc[1][nt] = __builtin_amdgcn_mfma_f32_16x16x32_bf16(af1, bfr, acc[1][nt], 0, 0, 0);
        }
    }

    #pragma unroll
    for (int nt = 0; nt < 8; nt++) {
        int n = n0 + wc * 128 + nt * 16 + lm;
        float bv = ldv(bias, n, 2, ef);
        #pragma unroll
        for (int mi = 0; mi < 2; mi++) {
            #pragma unroll
            for (int r = 0; r < 4; r++) {
                int m = m0 + wr * 32 + mi * 16 + lq * 4 + r;
                if (m >= M) continue;
                float v = acc[mi][nt][r] + bv;
                if (relu) v = fmaxf(v, 0.f);
                size_t ci = (size_t)m * N + n;
                if (cmode == 0) ((float*)C)[ci] = v;
                else            ((bf16*)C)[ci] = __float2bfloat16(v);
            }
        }
    }
}

// ---------------------------------------------------------------------------
// Legacy LDS MFMA GEMM — kept for the N=128 attention-weights GEMM
// ---------------------------------------------------------------------------
__global__ __launch_bounds__(256) void gemm_mfma(const void* __restrict__ A, int amode,
        const void* __restrict__ W, const void* __restrict__ bias,
        void* __restrict__ C, int cmode, int M, int N, int K, int relu,
        const float* __restrict__ flagp)
{
    const bool ef = flagp[0] > 0.5f;
    const bool a_bf16 = (amode == 1) || (amode == 2 && !ef);
    const bool w_bf16 = !ef;
    __shared__ __align__(16) bf16 As[64 * SAK];
    __shared__ __align__(16) bf16 Ws[64 * SAK];
    const int tid = threadIdx.x;
    const int m0 = blockIdx.y * 64, n0 = blockIdx.x * 64;
    const int w    = tid >> 6;
    const int lane = tid & 63;
    const int lm   = lane & 15;
    const int lq   = lane >> 4;
    const int srow = tid >> 2;
    const int sk   = (tid & 3) * 8;

    f32x4 acc[4] = {{0.f,0.f,0.f,0.f},{0.f,0.f,0.f,0.f},
                    {0.f,0.f,0.f,0.f},{0.f,0.f,0.f,0.f}};

    const int arow = m0 + srow;
    const bool avalid = arow < M;

    for (int k0 = 0; k0 < K; k0 += 32) {
        {
            bf16 tmp[8];
            if (avalid) {
                size_t base = (size_t)arow * K + k0 + sk;
                if (a_bf16) {
                    *(uint4*)tmp = *(const uint4*)((const bf16*)A + base);
                } else {
                    const float* ap = (const float*)A + base;
                    float4 f0 = *(const float4*)ap;
                    float4 f1 = *(const float4*)(ap + 4);
                    tmp[0] = __float2bfloat16(f0.x); tmp[1] = __float2bfloat16(f0.y);
                    tmp[2] = __float2bfloat16(f0.z); tmp[3] = __float2bfloat16(f0.w);
                    tmp[4] = __float2bfloat16(f1.x); tmp[5] = __float2bfloat16(f1.y);
                    tmp[6] = __float2bfloat16(f1.z); tmp[7] = __float2bfloat16(f1.w);
                }
            } else {
                #pragma unroll
                for (int i = 0; i < 8; i++) tmp[i] = __float2bfloat16(0.f);
            }
            *(uint4*)&As[srow * SAK + sk] = *(const uint4*)tmp;
        }
        {
            bf16 tmp[8];
            size_t base = (size_t)(n0 + srow) * K + k0 + sk;
            if (w_bf16) {
                *(uint4*)tmp = *(const uint4*)((const bf16*)W + base);
            } else {
                const float* wp = (const float*)W + base;
                float4 f0 = *(const float4*)wp;
                float4 f1 = *(const float4*)(wp + 4);
                tmp[0] = __float2bfloat16(f0.x); tmp[1] = __float2bfloat16(f0.y);
                tmp[2] = __float2bfloat16(f0.z); tmp[3] = __float2bfloat16(f0.w);
                tmp[4] = __float2bfloat16(f1.x); tmp[5] = __float2bfloat16(f1.y);
                tmp[6] = __float2bfloat16(f1.z); tmp[7] = __float2bfloat16(f1.w);
            }
            *(uint4*)&Ws[srow * SAK + sk] = *(const uint4*)tmp;
        }
        __syncthreads();
        bf16x8 af = *(const bf16x8*)&As[(w * 16 + lm) * SAK + lq * 8];
        #pragma unroll
        for (int nt = 0; nt < 4; nt++) {
            bf16x8 bfr = *(const bf16x8*)&Ws[(nt * 16 + lm) * SAK + lq * 8];
            acc[nt] = __builtin_amdgcn_mfma_f32_16x16x32_bf16(af, bfr, acc[nt], 0, 0, 0);
        }
        __syncthreads();
    }

    #pragma unroll
    for (int nt = 0; nt < 4; nt++) {
        int n = n0 + nt * 16 + lm;
        float bv = ldv(bias, n, 2, ef);
        #pragma unroll
        for (int r = 0; r < 4; r++) {
            int m = m0 + w * 16 + lq * 4 + r;
            if (m >= M) continue;
            float v = acc[nt][r] + bv;
            if (relu) v = fmaxf(v, 0.f);
            size_t ci = (size_t)m * N + n;
            if (cmode == 0) ((float*)C)[ci] = v;
            else            ((bf16*)C)[ci] = __float2bfloat16(v);
        }
    }
}

// ---------------------------------------------------------------------------
__global__ __launch_bounds__(256) void add_qpos(const void* __restrict__ a, int amode,
        const void* __restrict__ qp, float* __restrict__ o, const float* __restrict__ flagp)
{
    const bool ef = flagp[0] > 0.5f;
    int i = blockIdx.x * 256 + threadIdx.x;
    o[i] = ldv(a, i, amode, ef) + ldv(qp, i, 2, ef);
}

// ---------------------------------------------------------------------------
// MFMA flash MHA. grid (15 qtiles, 8 h, 8 b), 256 thr = 4 waves.
// ---------------------------------------------------------------------------
__global__ __launch_bounds__(256) void mha_mfma(const bf16* __restrict__ qkv,
        float* __restrict__ out)
{
    const int qt = blockIdx.x, h = blockIdx.y, b = blockIdx.z;
    const int q0 = qt * 64;
    const int tid = threadIdx.x;
    const int w = tid >> 6, lane = tid & 63;
    const int lm = lane & 15, lq = lane >> 4;
    const int srow = tid >> 2, sc = (tid & 3) * 8;

    __shared__ __align__(16) bf16 Qs[64][SAK];
    __shared__ __align__(16) bf16 Ks[64][SAK];
    __shared__ __align__(16) bf16 Vt[32][66];
    __shared__ __align__(16) bf16 Pt[64][66];

    const bf16* base = qkv + (size_t)b * NQ * 768;

    // ---- stage Q (pre-scaled) ----
    {
        bf16 tmp[8];
        if (q0 + srow < NQ) {
            uint4 u = *(const uint4*)(base + (size_t)(q0 + srow) * 768 + h * DHEAD + sc);
            float t[8]; unpack8(u, t);
            #pragma unroll
            for (int i = 0; i < 8; i++) tmp[i] = __float2bfloat16(t[i] * ATT_SCALE);
        } else {
            #pragma unroll
            for (int i = 0; i < 8; i++) tmp[i] = __float2bfloat16(0.f);
        }
        *(uint4*)&Qs[srow][sc] = *(const uint4*)tmp;
    }
    __syncthreads();
    const bf16x8 qf = *(const bf16x8*)&Qs[w * 16 + lm][lq * 8];

    f32x4 O[2] = {{0.f,0.f,0.f,0.f},{0.f,0.f,0.f,0.f}};
    float mrow = -1e30f, lrow = 0.f;

    for (int k0 = 0; k0 < NQ; k0 += 64) {
        __syncthreads();
        {
            uint4 uk = {0u,0u,0u,0u}, uv = {0u,0u,0u,0u};
            if (k0 + srow < NQ) {
                const bf16* rp = base + (size_t)(k0 + srow) * 768 + h * DHEAD + sc;
                uk = *(const uint4*)(rp + 256);
                uv = *(const uint4*)(rp + 512);
            }
            *(uint4*)&Ks[srow][sc] = uk;
            const bf16* vv = (const bf16*)&uv;
            #pragma unroll
            for (int i = 0; i < 8; i++) Vt[sc + i][srow] = vv[i];
        }
        __syncthreads();

        float sv[16];
        #pragma unroll
        for (int mt = 0; mt < 4; mt++) {
            bf16x8 kf = *(const bf16x8*)&Ks[mt * 16 + lm][lq * 8];
            f32x4 d = __builtin_amdgcn_mfma_f32_16x16x32_bf16(kf, qf,
                        (f32x4){0.f,0.f,0.f,0.f}, 0, 0, 0);
            sv[mt*4+0] = d[0]; sv[mt*4+1] = d[1]; sv[mt*4+2] = d[2]; sv[mt*4+3] = d[3];
        }
        #pragma unroll
        for (int mt = 0; mt < 4; mt++)
            #pragma unroll
            for (int r = 0; r < 4; r++)
                if (k0 + mt * 16 + lq * 4 + r >= NQ) sv[mt*4+r] = -1e30f;

        float tmax = sv[0];
        #pragma unroll
        for (int j = 1; j < 16; j++) tmax = fmaxf(tmax, sv[j]);
        tmax = fmaxf(tmax, __shfl_xor(tmax, 16, 64));
        tmax = fmaxf(tmax, __shfl_xor(tmax, 32, 64));
        float mnew = fmaxf(mrow, tmax);
        float alpha = __expf(mrow - mnew);
        mrow = mnew;
        float psum = 0.f;
        #pragma unroll
        for (int j = 0; j < 16; j++) {
            float p = __expf(sv[j] - mnew);
            sv[j] = p; psum += p;
        }
        psum += __shfl_xor(psum, 16, 64);
        psum += __shfl_xor(psum, 32, 64);
        lrow = lrow * alpha + psum;

        #pragma unroll
        for (int mt = 0; mt < 4; mt++)
            #pragma unroll
            for (int r = 0; r < 4; r++)
                Pt[mt * 16 + lq * 4 + r][w * 16 + lm] = __float2bfloat16(sv[mt*4+r]);

        #pragma unroll
        for (int mt = 0; mt < 2; mt++)
            #pragma unroll
            for (int r = 0; r < 4; r++) O[mt][r] *= alpha;
        #pragma unroll
        for (int ks = 0; ks < 2; ks++) {
            union { bf16 a[8]; bf16x8 v; } pf;
            #pragma unroll
            for (int j = 0; j < 8; j++)
                pf.a[j] = Pt[ks * 32 + lq * 8 + j][w * 16 + lm];
            #pragma unroll
            for (int mt = 0; mt < 2; mt++) {
                bf16x8 vf = *(const bf16x8*)&Vt[mt * 16 + lm][ks * 32 + lq * 8];
                O[mt] = __builtin_amdgcn_mfma_f32_16x16x32_bf16(vf, pf.v, O[mt], 0, 0, 0);
            }
        }
    }

    int q = q0 + w * 16 + lm;
    if (q < NQ) {
        float invl = 1.f / lrow;
        float* op = out + ((size_t)(b * NQ + q)) * DM + h * DHEAD;
        #pragma unroll
        for (int mt = 0; mt < 2; mt++)
            #pragma unroll
            for (int r = 0; r < 4; r++)
                op[mt * 16 + lq * 4 + r] = O[mt][r] * invl;
    }
}

// ---------------------------------------------------------------------------
// LayerNorm: one wave per row, float4 loads, shfl_xor reductions (no barriers)
// grid: BQ/4 blocks of 256 threads (4 rows/block)
// ---------------------------------------------------------------------------
__global__ __launch_bounds__(256) void ln_kernel(const float* res,
        const float* __restrict__ x, const void* __restrict__ gw,
        const void* __restrict__ bw, float* out, void* __restrict__ oout,
        size_t obase, const float* __restrict__ flagp)
{
    const bool ef = flagp[0] > 0.5f;
    const int w = threadIdx.x >> 6, lane = threadIdx.x & 63;
    const int row = blockIdx.x * 4 + w;
    const size_t off = (size_t)row * DM + lane * 4;

    float4 a = *(const float4*)(res + off);
    float4 b = *(const float4*)(x + off);
    float v[4] = {a.x + b.x, a.y + b.y, a.z + b.z, a.w + b.w};

    float s = v[0] + v[1] + v[2] + v[3];
    #pragma unroll
    for (int st = 1; st < 64; st <<= 1) s += __shfl_xor(s, st, 64);
    float mu = s * (1.f / DM);

    float q = 0.f;
    #pragma unroll
    for (int i = 0; i < 4; i++) { float d = v[i] - mu; q += d * d; }
    #pragma unroll
    for (int st = 1; st < 64; st <<= 1) q += __shfl_xor(q, st, 64);
    float rstd = rsqrtf(q * (1.f / DM) + LN_EPS);

    float o[4];
    #pragma unroll
    for (int i = 0; i < 4; i++)
        o[i] = (v[i] - mu) * rstd * ldv(gw, lane * 4 + i, 2, ef)
             + ldv(bw, lane * 4 + i, 2, ef);

    *(float4*)(out + off) = make_float4(o[0], o[1], o[2], o[3]);
    if (oout) {
        if (ef) {
            *(float4*)((float*)oout + obase + off) = make_float4(o[0], o[1], o[2], o[3]);
        } else {
            union { bf16 t[4]; uint2 u; } p;
            #pragma unroll
            for (int i = 0; i < 4; i++) p.t[i] = __float2bfloat16(o[i]);
            *(uint2*)((bf16*)oout + obase + off) = p.u;
        }
    }
}

// ---------------------------------------------------------------------------
__global__ __launch_bounds__(256) void aw_softmax(float* __restrict__ aw)
{
    int i = blockIdx.x * 256 + threadIdx.x;
    if (i >= BQ * NHEADS) return;
    float* p = aw + (size_t)i * 16;
    float mx = -1e30f;
    #pragma unroll
    for (int j = 0; j < 16; j++) mx = fmaxf(mx, p[j]);
    float s = 0.f;
    #pragma unroll
    for (int j = 0; j < 16; j++) { float e = __expf(p[j] - mx); p[j] = e; s += e; }
    float inv = 1.f / s;
    #pragma unroll
    for (int j = 0; j < 16; j++) p[j] *= inv;
}

// ---------------------------------------------------------------------------
__global__ __launch_bounds__(256) void msda_sample(const bf16* __restrict__ value,
        const float* __restrict__ off, const float* __restrict__ aw,
        const void* __restrict__ refp, const void* __restrict__ vr,
        float* __restrict__ out, const float* __restrict__ flagp)
{
    const bool ef = flagp[0] > 0.5f;
    int bq = blockIdx.x; int b = bq / NQ;
    int tid = threadIdx.x; int h = tid >> 5, d = tid & 31;
    __shared__ float sOff[256];
    __shared__ float sAw[128];
    __shared__ float sref[2];
    __shared__ float svr[8];
    sOff[tid] = off[(size_t)bq * 256 + tid];
    if (tid < 128) sAw[tid] = aw[(size_t)bq * 128 + tid];
    if (tid < 2)   sref[tid] = ldv(refp, bq * 2 + tid, 2, ef);
    if (tid < 8)   svr[tid]  = ldv(vr, b * 8 + tid, 2, ef);
    __syncthreads();
    const bf16* vb = value + (size_t)b * NS * DM + h * DHEAD + d;
    const int HS[4] = {100, 50, 25, 13};
    const int ST[4] = {0, 10000, 12500, 13125};
    float acc = 0.f;
    #pragma unroll
    for (int lvl = 0; lvl < 4; lvl++) {
        int W_ = HS[lvl], H_ = HS[lvl], st = ST[lvl];
        float rx = sref[0] * svr[lvl*2 + 0] * (float)W_;
        float ry = sref[1] * svr[lvl*2 + 1] * (float)H_;
        #pragma unroll
        for (int p = 0; p < 4; p++) {
            int oi = h * 32 + lvl * 8 + p * 2;
            float x = fminf(fmaxf(rx + sOff[oi]     - 0.5f, -4.f), (float)W_ + 4.f);
            float y = fminf(fmaxf(ry + sOff[oi + 1] - 0.5f, -4.f), (float)H_ + 4.f);
            float x0f = floorf(x), y0f = floorf(y);
            float wx = x - x0f, wy = y - y0f;
            int x0 = (int)x0f, y0 = (int)y0f;
            int x1i = x0 + 1, y1i = y0 + 1;
            bool vx0 = (x0 >= 0) && (x0 < W_), vx1 = (x1i >= 0) && (x1i < W_);
            bool vy0 = (y0 >= 0) && (y0 < H_), vy1 = (y1i >= 0) && (y1i < H_);
            float g = 0.f;
            if (vy0) {
                int rowo = (st + y0 * W_) * DM;
                if (vx0) g += (1.f - wx) * (1.f - wy) * __bfloat162float(vb[rowo + x0  * DM]);
                if (vx1) g += wx         * (1.f - wy) * __bfloat162float(vb[rowo + x1i * DM]);
            }
            if (vy1) {
                int rowo = (st + y1i * W_) * DM;
                if (vx0) g += (1.f - wx) * wy * __bfloat162float(vb[rowo + x0  * DM]);
                if (vx1) g += wx         * wy * __bfloat162float(vb[rowo + x1i * DM]);
            }
            acc += g * sAw[h * 16 + lvl * 4 + p];
        }
    }
    out[(size_t)bq * DM + tid] = acc;
}

// ---------------------------------------------------------------------------
__global__ __launch_bounds__(256) void copy_refs(const void* __restrict__ refp,
        void* __restrict__ out, const float* __restrict__ flagp)
{
    const bool ef = flagp[0] > 0.5f;
    int i = blockIdx.x * 256 + threadIdx.x;
    if (i >= NLAY * BQ * 2) return;
    float v = ldv(refp, i % (BQ * 2), 2, ef);
    size_t oi = (size_t)NLAY * BQ * DM + i;
    if (ef) ((float*)out)[oi] = v;
    else    ((bf16*)out)[oi] = __float2bfloat16(v);
}

// ---------------------------------------------------------------------------
extern "C" void kernel_launch(void* const* d_in, const int* in_sizes, int n_in,
                              void* d_out, int out_size, void* d_ws, size_t ws_size,
                              hipStream_t stream)
{
    const void* tgt     = d_in[0];
    const void* refp    = d_in[1];
    const void* memory  = d_in[2];
    const void* vr      = d_in[5];
    const void* qp      = d_in[6];
    const void* sa_in_w = d_in[7];
    const void* sa_in_b = d_in[8];
    const void* sa_out_w= d_in[9];
    const void* sa_out_b= d_in[10];
    const void* n1_g    = d_in[11];
    const void* n1_b    = d_in[12];
    const void* n2_g    = d_in[13];
    const void* n2_b    = d_in[14];
    const void* n3_g    = d_in[15];
    const void* n3_b    = d_in[16];
    const void* vp_w    = d_in[17];
    const void* vp_b    = d_in[18];
    const void* so_w    = d_in[19];
    const void* so_b    = d_in[20];
    const void* aw_w    = d_in[21];
    const void* aw_b    = d_in[22];
    const void* op_w    = d_in[23];
    const void* op_b    = d_in[24];
    const void* ff1_w   = d_in[25];
    const void* ff1_b   = d_in[26];
    const void* ff2_w   = d_in[27];
    const void* ff2_b   = d_in[28];

    // ---- workspace layout ----
    char* w = (char*)d_ws;
    float* flagp  = (float*)w;  w += 256;
    bf16*  value  = (bf16*)w;   w += (size_t)NB * NS * DM * 2;   // 54.45 MB
    float* outbuf = (float*)w;  w += (size_t)BQ * DM * 4;
    float* x1samp = (float*)w;  w += (size_t)BQ * DM * 4;        // x1, later samp
    bf16*  bigb   = (bf16*)w;   w += (size_t)BQ * NFF * 2;       // qkv / ffn hidden
    float* attoff = (float*)w;  w += (size_t)BQ * DM * 4;        // attn, later offsets
    float* t2     = (float*)w;  w += (size_t)BQ * DM * 4;
    float* awb    = (float*)w;  w += (size_t)BQ * 128 * 4;
    // pre-converted bf16 weights (~1.97 MB)
    bf16* wb_sa_in = (bf16*)w;  w += (size_t)768 * 256 * 2;
    bf16* wb_sa_out= (bf16*)w;  w += (size_t)256 * 256 * 2;
    bf16* wb_so    = (bf16*)w;  w += (size_t)256 * 256 * 2;
    bf16* wb_op    = (bf16*)w;  w += (size_t)256 * 256 * 2;
    bf16* wb_ff1   = (bf16*)w;  w += (size_t)NFF * 256 * 2;
    bf16* wb_ff2   = (bf16*)w;  w += (size_t)256 * NFF * 2;
    bf16* wb_vp    = (bf16*)w;  w += (size_t)256 * 256 * 2;

    const int gy = (BQ + 63) / 64;      // 113
    const int MV = NB * NS;             // 106352

    // 0) detect external dtype, pre-convert weights to bf16
    detect_dtype<<<1, 256, 0, stream>>>(tgt, flagp);
    convert_w<<< 96, 256, 0, stream>>>(sa_in_w,  wb_sa_in,  flagp);
    convert_w<<< 32, 256, 0, stream>>>(sa_out_w, wb_sa_out, flagp);
    convert_w<<< 32, 256, 0, stream>>>(so_w,     wb_so,     flagp);
    convert_w<<< 32, 256, 0, stream>>>(op_w,     wb_op,     flagp);
    convert_w<<<128, 256, 0, stream>>>(ff1_w,    wb_ff1,    flagp);
    convert_w<<<128, 256, 0, stream>>>(ff2_w,    wb_ff2,    flagp);
    convert_w<<< 32, 256, 0, stream>>>(vp_w,     wb_vp,     flagp);

    // 1) value projection (layer-invariant): direct GEMM, A read exactly once
    gemm_direct<<<dim3(1, (MV + 63) / 64), 256, 0, stream>>>(
        memory, 2, wb_vp, vp_b, value, 1, MV, DM, DM, 0, flagp);

    // 2) inter_refs output
    copy_refs<<<(NLAY * BQ * 2 + 255) / 256, 256, 0, stream>>>(refp, d_out, flagp);

    for (int l = 0; l < NLAY; l++) {
        // x1 = output + query_pos
        if (l == 0) add_qpos<<<BQ * DM / 256, 256, 0, stream>>>(tgt, 2, qp, x1samp, flagp);
        else        add_qpos<<<BQ * DM / 256, 256, 0, stream>>>(outbuf, 0, qp, x1samp, flagp);

        // self-attention
        gemm_direct<<<dim3(3, gy), 256, 0, stream>>>(
            x1samp, 0, wb_sa_in, sa_in_b, bigb, 1, BQ, 768, DM, 0, flagp);
        mha_mfma<<<dim3(15, NHEADS, NB), 256, 0, stream>>>(bigb, attoff);
        gemm_direct<<<dim3(1, gy), 256, 0, stream>>>(
            attoff, 0, wb_sa_out, sa_out_b, t2, 0, BQ, DM, DM, 0, flagp);
        ln_kernel<<<BQ / 4, 256, 0, stream>>>(x1samp, t2, n1_g, n1_b, outbuf,
                                              nullptr, 0, flagp);

        // MSDA
        gemm_direct<<<dim3(1, gy), 256, 0, stream>>>(
            outbuf, 0, wb_so, so_b, attoff, 0, BQ, DM, DM, 0, flagp);
        gemm_mfma<<<dim3(2, gy), 256, 0, stream>>>(
            outbuf, 0, aw_w, aw_b, awb, 0, BQ, 128, DM, 0, flagp);
        aw_softmax<<<(BQ * NHEADS + 255) / 256, 256, 0, stream>>>(awb);
        msda_sample<<<BQ, 256, 0, stream>>>(value, attoff, awb, refp, vr, x1samp, flagp);
        gemm_direct<<<dim3(1, gy), 256, 0, stream>>>(
            x1samp, 0, wb_op, op_b, t2, 0, BQ, DM, DM, 0, flagp);
        ln_kernel<<<BQ / 4, 256, 0, stream>>>(outbuf, t2, n2_g, n2_b, outbuf,
                                              nullptr, 0, flagp);

        // FFN
        gemm_direct<<<dim3(4, gy), 256, 0, stream>>>(
            outbuf, 0, wb_ff1, ff1_b, bigb, 1, BQ, NFF, DM, 1, flagp);
        gemm_direct<<<dim3(1, gy), 256, 0, stream>>>(
            bigb, 1, wb_ff2, ff2_b, t2, 0, BQ, DM, NFF, 0, flagp);
        ln_kernel<<<BQ / 4, 256, 0, stream>>>(outbuf, t2, n3_g, n3_b, outbuf,
                                              d_out, (size_t)l * BQ * DM, flagp);
    }
}

// Round 2
// 2214.009 us; speedup vs baseline: 1.2669x; 1.2669x over previous
//
#include <hip/hip_runtime.h>
#include <hip/hip_bf16.h>

typedef __hip_bfloat16 bf16;
typedef __bf16 bf16x8 __attribute__((ext_vector_type(8)));
typedef float  f32x4  __attribute__((ext_vector_type(4)));

#define NB 8
#define NQ 900
#define DM 256
#define NHEADS 8
#define DHEAD 32
#define NFF 1024
#define NLAY 6
#define NS 13294
#define BQ (NB*NQ)            // 7200
#define LN_EPS 1e-5f
#define ATT_SCALE 0.17677669529663687f   // 1/sqrt(32)
#define SAK 40                // LDS row stride (bf16): 80B — measured ~2-way (free)

__device__ __forceinline__ float bfd(const bf16* p, size_t i){ return __bfloat162float(p[i]); }

// mode: 0 = fp32 (internal), 1 = bf16 (internal), 2 = external (dtype per flag)
__device__ __forceinline__ float ldv(const void* p, size_t i, int mode, bool extF32)
{
    if (mode == 0) return ((const float*)p)[i];
    if (mode == 1) return bfd((const bf16*)p, i);
    return extF32 ? ((const float*)p)[i] : bfd((const bf16*)p, i);
}

// unpack 8 bf16 (16B) to floats
__device__ __forceinline__ void unpack8(uint4 u, float* t)
{
    t[0] = __uint_as_float((u.x & 0xffffu) << 16);
    t[1] = __uint_as_float(u.x & 0xffff0000u);
    t[2] = __uint_as_float((u.y & 0xffffu) << 16);
    t[3] = __uint_as_float(u.y & 0xffff0000u);
    t[4] = __uint_as_float((u.z & 0xffffu) << 16);
    t[5] = __uint_as_float(u.z & 0xffff0000u);
    t[6] = __uint_as_float((u.w & 0xffffu) << 16);
    t[7] = __uint_as_float(u.w & 0xffff0000u);
}

// ---------------------------------------------------------------------------
// dtype detector (inputs proved fp32; kept for robustness)
// ---------------------------------------------------------------------------
__global__ __launch_bounds__(256) void detect_dtype(const void* __restrict__ tgt,
        float* __restrict__ flag)
{
    __shared__ float red[256];
    int t = threadIdx.x;
    const unsigned short* u = (const unsigned short*)tgt;
    float m = 0.f;
    for (int i = t; i < 2048; i += 256) {
        unsigned int bits = ((unsigned int)u[i]) << 16;
        float v = fabsf(__uint_as_float(bits));
        if (!isfinite(v)) v = 1e30f;
        m = fmaxf(m, v);
    }
    red[t] = m;
    __syncthreads();
    for (int st = 128; st; st >>= 1) {
        if (t < st) red[t] = fmaxf(red[t], red[t + st]);
        __syncthreads();
    }
    if (t == 0) flag[0] = (red[0] > 1e8f) ? 1.f : 0.f;
}

// ---------------------------------------------------------------------------
// weight pre-convert: external dtype -> bf16, 8 elems/thread (size = grid*2048)
// ---------------------------------------------------------------------------
__global__ __launch_bounds__(256) void convert_w(const void* __restrict__ src,
        bf16* __restrict__ dst, const float* __restrict__ flagp)
{
    const bool ef = flagp[0] > 0.5f;
    size_t base = ((size_t)blockIdx.x * 256 + threadIdx.x) * 8;
    if (ef) {
        const float* s = (const float*)src + base;
        float4 f0 = *(const float4*)s;
        float4 f1 = *(const float4*)(s + 4);
        union { bf16 a[8]; uint4 u; } t;
        t.a[0] = __float2bfloat16(f0.x); t.a[1] = __float2bfloat16(f0.y);
        t.a[2] = __float2bfloat16(f0.z); t.a[3] = __float2bfloat16(f0.w);
        t.a[4] = __float2bfloat16(f1.x); t.a[5] = __float2bfloat16(f1.y);
        t.a[6] = __float2bfloat16(f1.z); t.a[7] = __float2bfloat16(f1.w);
        *(uint4*)(dst + base) = t.u;
    } else {
        *(uint4*)(dst + base) = *(const uint4*)((const bf16*)src + base);
    }
}

// ---------------------------------------------------------------------------
// 128x128-tile MFMA GEMM (m93-class structure). 256 thr = 4 waves in 2x2.
// Wave (wr,wc) computes 64x64: 4 m-frags x 4 n-frags, 16 MFMAs per K-step
// between one pair of barriers (4x the MFMA:barrier ratio of the 64^2 tile).
// A: [M,K] per amode (bf16 fast path; fp32 staged+converted);
// Wb: [N,K] pre-converted bf16. LDS padded stride SAK=40 (~2-way, free).
// grid: (N/128, ceil(M/128)).
// ---------------------------------------------------------------------------
__global__ __launch_bounds__(256) void gemm128(const void* __restrict__ A, int amode,
        const bf16* __restrict__ Wb, const void* __restrict__ bias,
        void* __restrict__ C, int cmode, int M, int N, int K, int relu,
        const float* __restrict__ flagp)
{
    const bool ef = flagp[0] > 0.5f;
    const bool a_bf16 = (amode == 1) || (amode == 2 && !ef);
    __shared__ __align__(16) bf16 As[128 * SAK];
    __shared__ __align__(16) bf16 Ws[128 * SAK];
    const int tid  = threadIdx.x;
    const int m0   = blockIdx.y * 128, n0 = blockIdx.x * 128;
    const int w    = tid >> 6;
    const int lane = tid & 63;
    const int lm   = lane & 15;
    const int lq   = lane >> 4;
    const int wr   = w >> 1;            // row half of 2x2 wave grid
    const int wc   = w & 1;             // col half
    const int srow = tid >> 2;          // 0..63
    const int scol = (tid & 3) * 8;     // 0,8,16,24

    f32x4 acc[4][4];
    #pragma unroll
    for (int mi = 0; mi < 4; mi++)
        #pragma unroll
        for (int nt = 0; nt < 4; nt++)
            acc[mi][nt] = (f32x4){0.f, 0.f, 0.f, 0.f};

    for (int k0 = 0; k0 < K; k0 += 32) {
        // ---- stage A-tile [128][32] and W-tile [128][32], 8 elems/thread x2 ----
        #pragma unroll
        for (int it = 0; it < 2; it++) {
            const int row  = it * 64 + srow;
            const int arow = m0 + row;
            bf16 tmp[8];
            if (arow < M) {
                size_t base = (size_t)arow * K + k0 + scol;
                if (a_bf16) {
                    *(uint4*)tmp = *(const uint4*)((const bf16*)A + base);
                } else {
                    const float* ap = (const float*)A + base;
                    float4 f0 = *(const float4*)ap;
                    float4 f1 = *(const float4*)(ap + 4);
                    tmp[0] = __float2bfloat16(f0.x); tmp[1] = __float2bfloat16(f0.y);
                    tmp[2] = __float2bfloat16(f0.z); tmp[3] = __float2bfloat16(f0.w);
                    tmp[4] = __float2bfloat16(f1.x); tmp[5] = __float2bfloat16(f1.y);
                    tmp[6] = __float2bfloat16(f1.z); tmp[7] = __float2bfloat16(f1.w);
                }
            } else {
                #pragma unroll
                for (int i = 0; i < 8; i++) tmp[i] = __float2bfloat16(0.f);
            }
            *(uint4*)&As[row * SAK + scol] = *(const uint4*)tmp;
            // W rows always valid: N is a multiple of 128
            *(uint4*)&Ws[row * SAK + scol] =
                *(const uint4*)(Wb + (size_t)(n0 + row) * K + k0 + scol);
        }
        __syncthreads();

        bf16x8 af[4], bfr[4];
        #pragma unroll
        for (int mi = 0; mi < 4; mi++)
            af[mi] = *(const bf16x8*)&As[(wr * 64 + mi * 16 + lm) * SAK + lq * 8];
        #pragma unroll
        for (int nt = 0; nt < 4; nt++)
            bfr[nt] = *(const bf16x8*)&Ws[(wc * 64 + nt * 16 + lm) * SAK + lq * 8];
        #pragma unroll
        for (int mi = 0; mi < 4; mi++)
            #pragma unroll
            for (int nt = 0; nt < 4; nt++)
                acc[mi][nt] = __builtin_amdgcn_mfma_f32_16x16x32_bf16(
                                  af[mi], bfr[nt], acc[mi][nt], 0, 0, 0);
        __syncthreads();
    }

    #pragma unroll
    for (int nt = 0; nt < 4; nt++) {
        int n = n0 + wc * 64 + nt * 16 + lm;
        float bv = ldv(bias, n, 2, ef);
        #pragma unroll
        for (int mi = 0; mi < 4; mi++) {
            #pragma unroll
            for (int r = 0; r < 4; r++) {
                int m = m0 + wr * 64 + mi * 16 + lq * 4 + r;
                if (m >= M) continue;
                float v = acc[mi][nt][r] + bv;
                if (relu) v = fmaxf(v, 0.f);
                size_t ci = (size_t)m * N + n;
                if (cmode == 0) ((float*)C)[ci] = v;
                else            ((bf16*)C)[ci] = __float2bfloat16(v);
            }
        }
    }
}

// ---------------------------------------------------------------------------
// add_qpos: fp32 out (residual) + bf16 out (GEMM A operand)
// ---------------------------------------------------------------------------
__global__ __launch_bounds__(256) void add_qpos(const void* __restrict__ a, int amode,
        const void* __restrict__ qp, float* __restrict__ o, bf16* __restrict__ ob,
        const float* __restrict__ flagp)
{
    const bool ef = flagp[0] > 0.5f;
    int i = blockIdx.x * 256 + threadIdx.x;
    float v = ldv(a, i, amode, ef) + ldv(qp, i, 2, ef);
    o[i]  = v;
    ob[i] = __float2bfloat16(v);
}

// ---------------------------------------------------------------------------
// MFMA flash MHA. grid (15 qtiles, 8 h, 8 b), 256 thr = 4 waves.
// Output now bf16 (feeds sa_out GEMM directly).
// ---------------------------------------------------------------------------
__global__ __launch_bounds__(256) void mha_mfma(const bf16* __restrict__ qkv,
        bf16* __restrict__ out)
{
    const int qt = blockIdx.x, h = blockIdx.y, b = blockIdx.z;
    const int q0 = qt * 64;
    const int tid = threadIdx.x;
    const int w = tid >> 6, lane = tid & 63;
    const int lm = lane & 15, lq = lane >> 4;
    const int srow = tid >> 2, sc = (tid & 3) * 8;

    __shared__ __align__(16) bf16 Qs[64][SAK];
    __shared__ __align__(16) bf16 Ks[64][SAK];
    __shared__ __align__(16) bf16 Vt[32][66];
    __shared__ __align__(16) bf16 Pt[64][66];

    const bf16* base = qkv + (size_t)b * NQ * 768;

    // ---- stage Q (pre-scaled) ----
    {
        bf16 tmp[8];
        if (q0 + srow < NQ) {
            uint4 u = *(const uint4*)(base + (size_t)(q0 + srow) * 768 + h * DHEAD + sc);
            float t[8]; unpack8(u, t);
            #pragma unroll
            for (int i = 0; i < 8; i++) tmp[i] = __float2bfloat16(t[i] * ATT_SCALE);
        } else {
            #pragma unroll
            for (int i = 0; i < 8; i++) tmp[i] = __float2bfloat16(0.f);
        }
        *(uint4*)&Qs[srow][sc] = *(const uint4*)tmp;
    }
    __syncthreads();
    const bf16x8 qf = *(const bf16x8*)&Qs[w * 16 + lm][lq * 8];

    f32x4 O[2] = {{0.f,0.f,0.f,0.f},{0.f,0.f,0.f,0.f}};
    float mrow = -1e30f, lrow = 0.f;

    for (int k0 = 0; k0 < NQ; k0 += 64) {
        __syncthreads();
        {
            uint4 uk = {0u,0u,0u,0u}, uv = {0u,0u,0u,0u};
            if (k0 + srow < NQ) {
                const bf16* rp = base + (size_t)(k0 + srow) * 768 + h * DHEAD + sc;
                uk = *(const uint4*)(rp + 256);
                uv = *(const uint4*)(rp + 512);
            }
            *(uint4*)&Ks[srow][sc] = uk;
            const bf16* vv = (const bf16*)&uv;
            #pragma unroll
            for (int i = 0; i < 8; i++) Vt[sc + i][srow] = vv[i];
        }
        __syncthreads();

        float sv[16];
        #pragma unroll
        for (int mt = 0; mt < 4; mt++) {
            bf16x8 kf = *(const bf16x8*)&Ks[mt * 16 + lm][lq * 8];
            f32x4 d = __builtin_amdgcn_mfma_f32_16x16x32_bf16(kf, qf,
                        (f32x4){0.f,0.f,0.f,0.f}, 0, 0, 0);
            sv[mt*4+0] = d[0]; sv[mt*4+1] = d[1]; sv[mt*4+2] = d[2]; sv[mt*4+3] = d[3];
        }
        #pragma unroll
        for (int mt = 0; mt < 4; mt++)
            #pragma unroll
            for (int r = 0; r < 4; r++)
                if (k0 + mt * 16 + lq * 4 + r >= NQ) sv[mt*4+r] = -1e30f;

        float tmax = sv[0];
        #pragma unroll
        for (int j = 1; j < 16; j++) tmax = fmaxf(tmax, sv[j]);
        tmax = fmaxf(tmax, __shfl_xor(tmax, 16, 64));
        tmax = fmaxf(tmax, __shfl_xor(tmax, 32, 64));
        float mnew = fmaxf(mrow, tmax);
        float alpha = __expf(mrow - mnew);
        mrow = mnew;
        float psum = 0.f;
        #pragma unroll
        for (int j = 0; j < 16; j++) {
            float p = __expf(sv[j] - mnew);
            sv[j] = p; psum += p;
        }
        psum += __shfl_xor(psum, 16, 64);
        psum += __shfl_xor(psum, 32, 64);
        lrow = lrow * alpha + psum;

        #pragma unroll
        for (int mt = 0; mt < 4; mt++)
            #pragma unroll
            for (int r = 0; r < 4; r++)
                Pt[mt * 16 + lq * 4 + r][w * 16 + lm] = __float2bfloat16(sv[mt*4+r]);

        #pragma unroll
        for (int mt = 0; mt < 2; mt++)
            #pragma unroll
            for (int r = 0; r < 4; r++) O[mt][r] *= alpha;
        #pragma unroll
        for (int ks = 0; ks < 2; ks++) {
            union { bf16 a[8]; bf16x8 v; } pf;
            #pragma unroll
            for (int j = 0; j < 8; j++)
                pf.a[j] = Pt[ks * 32 + lq * 8 + j][w * 16 + lm];
            #pragma unroll
            for (int mt = 0; mt < 2; mt++) {
                bf16x8 vf = *(const bf16x8*)&Vt[mt * 16 + lm][ks * 32 + lq * 8];
                O[mt] = __builtin_amdgcn_mfma_f32_16x16x32_bf16(vf, pf.v, O[mt], 0, 0, 0);
            }
        }
    }

    int q = q0 + w * 16 + lm;
    if (q < NQ) {
        float invl = 1.f / lrow;
        bf16* op = out + ((size_t)(b * NQ + q)) * DM + h * DHEAD;
        #pragma unroll
        for (int mt = 0; mt < 2; mt++)
            #pragma unroll
            for (int r = 0; r < 4; r++)
                op[mt * 16 + lq * 4 + r] = __float2bfloat16(O[mt][r] * invl);
    }
}

// ---------------------------------------------------------------------------
// LayerNorm: one wave per row, float4 loads, shfl_xor reductions (no barriers)
// grid: BQ/4 blocks of 256 threads (4 rows/block).
// Emits fp32 out (residual) + optional bf16 dup (GEMM A) + optional d_out.
// ---------------------------------------------------------------------------
__global__ __launch_bounds__(256) void ln_kernel(const float* res,
        const float* __restrict__ x, const void* __restrict__ gw,
        const void* __restrict__ bw, float* out, bf16* __restrict__ bfdup,
        void* __restrict__ oout, size_t obase, const float* __restrict__ flagp)
{
    const bool ef = flagp[0] > 0.5f;
    const int w = threadIdx.x >> 6, lane = threadIdx.x & 63;
    const int row = blockIdx.x * 4 + w;
    const size_t off = (size_t)row * DM + lane * 4;

    float4 a = *(const float4*)(res + off);
    float4 b = *(const float4*)(x + off);
    float v[4] = {a.x + b.x, a.y + b.y, a.z + b.z, a.w + b.w};

    float s = v[0] + v[1] + v[2] + v[3];
    #pragma unroll
    for (int st = 1; st < 64; st <<= 1) s += __shfl_xor(s, st, 64);
    float mu = s * (1.f / DM);

    float q = 0.f;
    #pragma unroll
    for (int i = 0; i < 4; i++) { float d = v[i] - mu; q += d * d; }
    #pragma unroll
    for (int st = 1; st < 64; st <<= 1) q += __shfl_xor(q, st, 64);
    float rstd = rsqrtf(q * (1.f / DM) + LN_EPS);

    float o[4];
    #pragma unroll
    for (int i = 0; i < 4; i++)
        o[i] = (v[i] - mu) * rstd * ldv(gw, lane * 4 + i, 2, ef)
             + ldv(bw, lane * 4 + i, 2, ef);

    *(float4*)(out + off) = make_float4(o[0], o[1], o[2], o[3]);
    if (bfdup) {
        union { bf16 t[4]; uint2 u; } p;
        #pragma unroll
        for (int i = 0; i < 4; i++) p.t[i] = __float2bfloat16(o[i]);
        *(uint2*)(bfdup + off) = p.u;
    }
    if (oout) {
        if (ef) {
            *(float4*)((float*)oout + obase + off) = make_float4(o[0], o[1], o[2], o[3]);
        } else {
            union { bf16 t[4]; uint2 u; } p;
            #pragma unroll
            for (int i = 0; i < 4; i++) p.t[i] = __float2bfloat16(o[i]);
            *(uint2*)((bf16*)oout + obase + off) = p.u;
        }
    }
}

// ---------------------------------------------------------------------------
__global__ __launch_bounds__(256) void aw_softmax(float* __restrict__ aw)
{
    int i = blockIdx.x * 256 + threadIdx.x;
    if (i >= BQ * NHEADS) return;
    float* p = aw + (size_t)i * 16;
    float mx = -1e30f;
    #pragma unroll
    for (int j = 0; j < 16; j++) mx = fmaxf(mx, p[j]);
    float s = 0.f;
    #pragma unroll
    for (int j = 0; j < 16; j++) { float e = __expf(p[j] - mx); p[j] = e; s += e; }
    float inv = 1.f / s;
    #pragma unroll
    for (int j = 0; j < 16; j++) p[j] *= inv;
}

// ---------------------------------------------------------------------------
// MSDA sampling — output now bf16 (feeds op GEMM directly)
// ---------------------------------------------------------------------------
__global__ __launch_bounds__(256) void msda_sample(const bf16* __restrict__ value,
        const float* __restrict__ off, const float* __restrict__ aw,
        const void* __restrict__ refp, const void* __restrict__ vr,
        bf16* __restrict__ out, const float* __restrict__ flagp)
{
    const bool ef = flagp[0] > 0.5f;
    int bq = blockIdx.x; int b = bq / NQ;
    int tid = threadIdx.x; int h = tid >> 5, d = tid & 31;
    __shared__ float sOff[256];
    __shared__ float sAw[128];
    __shared__ float sref[2];
    __shared__ float svr[8];
    sOff[tid] = off[(size_t)bq * 256 + tid];
    if (tid < 128) sAw[tid] = aw[(size_t)bq * 128 + tid];
    if (tid < 2)   sref[tid] = ldv(refp, bq * 2 + tid, 2, ef);
    if (tid < 8)   svr[tid]  = ldv(vr, b * 8 + tid, 2, ef);
    __syncthreads();
    const bf16* vb = value + (size_t)b * NS * DM + h * DHEAD + d;
    const int HS[4] = {100, 50, 25, 13};
    const int ST[4] = {0, 10000, 12500, 13125};
    float acc = 0.f;
    #pragma unroll
    for (int lvl = 0; lvl < 4; lvl++) {
        int W_ = HS[lvl], H_ = HS[lvl], st = ST[lvl];
        float rx = sref[0] * svr[lvl*2 + 0] * (float)W_;
        float ry = sref[1] * svr[lvl*2 + 1] * (float)H_;
        #pragma unroll
        for (int p = 0; p < 4; p++) {
            int oi = h * 32 + lvl * 8 + p * 2;
            float x = fminf(fmaxf(rx + sOff[oi]     - 0.5f, -4.f), (float)W_ + 4.f);
            float y = fminf(fmaxf(ry + sOff[oi + 1] - 0.5f, -4.f), (float)H_ + 4.f);
            float x0f = floorf(x), y0f = floorf(y);
            float wx = x - x0f, wy = y - y0f;
            int x0 = (int)x0f, y0 = (int)y0f;
            int x1i = x0 + 1, y1i = y0 + 1;
            bool vx0 = (x0 >= 0) && (x0 < W_), vx1 = (x1i >= 0) && (x1i < W_);
            bool vy0 = (y0 >= 0) && (y0 < H_), vy1 = (y1i >= 0) && (y1i < H_);
            float g = 0.f;
            if (vy0) {
                int rowo = (st + y0 * W_) * DM;
                if (vx0) g += (1.f - wx) * (1.f - wy) * __bfloat162float(vb[rowo + x0  * DM]);
                if (vx1) g += wx         * (1.f - wy) * __bfloat162float(vb[rowo + x1i * DM]);
            }
            if (vy1) {
                int rowo = (st + y1i * W_) * DM;
                if (vx0) g += (1.f - wx) * wy * __bfloat162float(vb[rowo + x0  * DM]);
                if (vx1) g += wx         * wy * __bfloat162float(vb[rowo + x1i * DM]);
            }
            acc += g * sAw[h * 16 + lvl * 4 + p];
        }
    }
    out[(size_t)bq * DM + tid] = __float2bfloat16(acc);
}

// ---------------------------------------------------------------------------
__global__ __launch_bounds__(256) void copy_refs(const void* __restrict__ refp,
        void* __restrict__ out, const float* __restrict__ flagp)
{
    const bool ef = flagp[0] > 0.5f;
    int i = blockIdx.x * 256 + threadIdx.x;
    if (i >= NLAY * BQ * 2) return;
    float v = ldv(refp, i % (BQ * 2), 2, ef);
    size_t oi = (size_t)NLAY * BQ * DM + i;
    if (ef) ((float*)out)[oi] = v;
    else    ((bf16*)out)[oi] = __float2bfloat16(v);
}

// ---------------------------------------------------------------------------
extern "C" void kernel_launch(void* const* d_in, const int* in_sizes, int n_in,
                              void* d_out, int out_size, void* d_ws, size_t ws_size,
                              hipStream_t stream)
{
    const void* tgt     = d_in[0];
    const void* refp    = d_in[1];
    const void* memory  = d_in[2];
    const void* vr      = d_in[5];
    const void* qp      = d_in[6];
    const void* sa_in_w = d_in[7];
    const void* sa_in_b = d_in[8];
    const void* sa_out_w= d_in[9];
    const void* sa_out_b= d_in[10];
    const void* n1_g    = d_in[11];
    const void* n1_b    = d_in[12];
    const void* n2_g    = d_in[13];
    const void* n2_b    = d_in[14];
    const void* n3_g    = d_in[15];
    const void* n3_b    = d_in[16];
    const void* vp_w    = d_in[17];
    const void* vp_b    = d_in[18];
    const void* so_w    = d_in[19];
    const void* so_b    = d_in[20];
    const void* aw_w    = d_in[21];
    const void* aw_b    = d_in[22];
    const void* op_w    = d_in[23];
    const void* op_b    = d_in[24];
    const void* ff1_w   = d_in[25];
    const void* ff1_b   = d_in[26];
    const void* ff2_w   = d_in[27];
    const void* ff2_b   = d_in[28];

    // ---- workspace layout ----
    char* w = (char*)d_ws;
    float* flagp  = (float*)w;  w += 256;
    bf16*  value  = (bf16*)w;   w += (size_t)NB * NS * DM * 2;   // 54.45 MB
    float* outbuf = (float*)w;  w += (size_t)BQ * DM * 4;
    float* x1samp = (float*)w;  w += (size_t)BQ * DM * 4;
    bf16*  bigb   = (bf16*)w;   w += (size_t)BQ * NFF * 2;       // qkv / ffn hidden
    float* attoff = (float*)w;  w += (size_t)BQ * DM * 4;        // sampling offsets
    float* t2     = (float*)w;  w += (size_t)BQ * DM * 4;
    float* awb    = (float*)w;  w += (size_t)BQ * 128 * 4;
    bf16*  abuf   = (bf16*)w;   w += (size_t)BQ * DM * 2;        // x1/mha/msda bf16 (time-shared)
    bf16*  outbf  = (bf16*)w;   w += (size_t)BQ * DM * 2;        // ln output bf16 dup
    // pre-converted bf16 weights (~2.03 MB)
    bf16* wb_sa_in = (bf16*)w;  w += (size_t)768 * 256 * 2;
    bf16* wb_sa_out= (bf16*)w;  w += (size_t)256 * 256 * 2;
    bf16* wb_so    = (bf16*)w;  w += (size_t)256 * 256 * 2;
    bf16* wb_aw    = (bf16*)w;  w += (size_t)128 * 256 * 2;
    bf16* wb_op    = (bf16*)w;  w += (size_t)256 * 256 * 2;
    bf16* wb_ff1   = (bf16*)w;  w += (size_t)NFF * 256 * 2;
    bf16* wb_ff2   = (bf16*)w;  w += (size_t)256 * NFF * 2;
    bf16* wb_vp    = (bf16*)w;  w += (size_t)256 * 256 * 2;

    const int gy = (BQ + 127) / 128;    // 57
    const int MV = NB * NS;             // 106352

    // 0) detect external dtype, pre-convert weights to bf16
    detect_dtype<<<1, 256, 0, stream>>>(tgt, flagp);
    convert_w<<< 96, 256, 0, stream>>>(sa_in_w,  wb_sa_in,  flagp);
    convert_w<<< 32, 256, 0, stream>>>(sa_out_w, wb_sa_out, flagp);
    convert_w<<< 32, 256, 0, stream>>>(so_w,     wb_so,     flagp);
    convert_w<<< 16, 256, 0, stream>>>(aw_w,     wb_aw,     flagp);
    convert_w<<< 32, 256, 0, stream>>>(op_w,     wb_op,     flagp);
    convert_w<<<128, 256, 0, stream>>>(ff1_w,    wb_ff1,    flagp);
    convert_w<<<128, 256, 0, stream>>>(ff2_w,    wb_ff2,    flagp);
    convert_w<<< 32, 256, 0, stream>>>(vp_w,     wb_vp,     flagp);

    // 1) value projection (layer-invariant)
    gemm128<<<dim3(DM/128, (MV + 127) / 128), 256, 0, stream>>>(
        memory, 2, wb_vp, vp_b, value, 1, MV, DM, DM, 0, flagp);

    // 2) inter_refs output
    copy_refs<<<(NLAY * BQ * 2 + 255) / 256, 256, 0, stream>>>(refp, d_out, flagp);

    for (int l = 0; l < NLAY; l++) {
        // x1 = output + query_pos (fp32 residual + bf16 GEMM operand)
        if (l == 0) add_qpos<<<BQ * DM / 256, 256, 0, stream>>>(tgt, 2, qp, x1samp, abuf, flagp);
        else        add_qpos<<<BQ * DM / 256, 256, 0, stream>>>(outbuf, 0, qp, x1samp, abuf, flagp);

        // self-attention
        gemm128<<<dim3(768/128, gy), 256, 0, stream>>>(
            abuf, 1, wb_sa_in, sa_in_b, bigb, 1, BQ, 768, DM, 0, flagp);
        mha_mfma<<<dim3(15, NHEADS, NB), 256, 0, stream>>>(bigb, abuf);
        gemm128<<<dim3(DM/128, gy), 256, 0, stream>>>(
            abuf, 1, wb_sa_out, sa_out_b, t2, 0, BQ, DM, DM, 0, flagp);
        ln_kernel<<<BQ / 4, 256, 0, stream>>>(x1samp, t2, n1_g, n1_b, outbuf,
                                              outbf, nullptr, 0, flagp);

        // MSDA
        gemm128<<<dim3(DM/128, gy), 256, 0, stream>>>(
            outbf, 1, wb_so, so_b, attoff, 0, BQ, DM, DM, 0, flagp);
        gemm128<<<dim3(1, gy), 256, 0, stream>>>(
            outbf, 1, wb_aw, aw_b, awb, 0, BQ, 128, DM, 0, flagp);
        aw_softmax<<<(BQ * NHEADS + 255) / 256, 256, 0, stream>>>(awb);
        msda_sample<<<BQ, 256, 0, stream>>>(value, attoff, awb, refp, vr, abuf, flagp);
        gemm128<<<dim3(DM/128, gy), 256, 0, stream>>>(
            abuf, 1, wb_op, op_b, t2, 0, BQ, DM, DM, 0, flagp);
        ln_kernel<<<BQ / 4, 256, 0, stream>>>(outbuf, t2, n2_g, n2_b, outbuf,
                                              outbf, nullptr, 0, flagp);

        // FFN
        gemm128<<<dim3(NFF/128, gy), 256, 0, stream>>>(
            outbf, 1, wb_ff1, ff1_b, bigb, 1, BQ, NFF, DM, 1, flagp);
        gemm128<<<dim3(DM/128, gy), 256, 0, stream>>>(
            bigb, 1, wb_ff2, ff2_b, t2, 0, BQ, DM, NFF, 0, flagp);
        ln_kernel<<<BQ / 4, 256, 0, stream>>>(outbuf, t2, n3_g, n3_b, outbuf,
                                              nullptr, d_out, (size_t)l * BQ * DM, flagp);
    }
}

// Round 3
// 1909.840 us; speedup vs baseline: 1.4687x; 1.1593x over previous
//
#include <hip/hip_runtime.h>
#include <hip/hip_bf16.h>

typedef __hip_bfloat16 bf16;
typedef __bf16 bf16x8 __attribute__((ext_vector_type(8)));
typedef float  f32x4  __attribute__((ext_vector_type(4)));

#define NB 8
#define NQ 900
#define DM 256
#define NHEADS 8
#define DHEAD 32
#define NFF 1024
#define NLAY 6
#define NS 13294
#define BQ (NB*NQ)            // 7200
#define LN_EPS 1e-5f
#define ATT_SCALE 0.17677669529663687f   // 1/sqrt(32)
#define SAK 40                // LDS row stride (bf16): 80B — measured ~2-way (free)

__device__ __forceinline__ float bfd(const bf16* p, size_t i){ return __bfloat162float(p[i]); }

// mode: 0 = fp32 (internal), 1 = bf16 (internal), 2 = external (dtype per flag)
__device__ __forceinline__ float ldv(const void* p, size_t i, int mode, bool extF32)
{
    if (mode == 0) return ((const float*)p)[i];
    if (mode == 1) return bfd((const bf16*)p, i);
    return extF32 ? ((const float*)p)[i] : bfd((const bf16*)p, i);
}

// unpack 8 bf16 (16B) to floats
__device__ __forceinline__ void unpack8(uint4 u, float* t)
{
    t[0] = __uint_as_float((u.x & 0xffffu) << 16);
    t[1] = __uint_as_float(u.x & 0xffff0000u);
    t[2] = __uint_as_float((u.y & 0xffffu) << 16);
    t[3] = __uint_as_float(u.y & 0xffff0000u);
    t[4] = __uint_as_float((u.z & 0xffffu) << 16);
    t[5] = __uint_as_float(u.z & 0xffff0000u);
    t[6] = __uint_as_float((u.w & 0xffffu) << 16);
    t[7] = __uint_as_float(u.w & 0xffff0000u);
}

// ---------------------------------------------------------------------------
__global__ __launch_bounds__(256) void detect_dtype(const void* __restrict__ tgt,
        float* __restrict__ flag)
{
    __shared__ float red[256];
    int t = threadIdx.x;
    const unsigned short* u = (const unsigned short*)tgt;
    float m = 0.f;
    for (int i = t; i < 2048; i += 256) {
        unsigned int bits = ((unsigned int)u[i]) << 16;
        float v = fabsf(__uint_as_float(bits));
        if (!isfinite(v)) v = 1e30f;
        m = fmaxf(m, v);
    }
    red[t] = m;
    __syncthreads();
    for (int st = 128; st; st >>= 1) {
        if (t < st) red[t] = fmaxf(red[t], red[t + st]);
        __syncthreads();
    }
    if (t == 0) flag[0] = (red[0] > 1e8f) ? 1.f : 0.f;
}

// ---------------------------------------------------------------------------
__global__ __launch_bounds__(256) void convert_w(const void* __restrict__ src,
        bf16* __restrict__ dst, const float* __restrict__ flagp)
{
    const bool ef = flagp[0] > 0.5f;
    size_t base = ((size_t)blockIdx.x * 256 + threadIdx.x) * 8;
    if (ef) {
        const float* s = (const float*)src + base;
        float4 f0 = *(const float4*)s;
        float4 f1 = *(const float4*)(s + 4);
        union { bf16 a[8]; uint4 u; } t;
        t.a[0] = __float2bfloat16(f0.x); t.a[1] = __float2bfloat16(f0.y);
        t.a[2] = __float2bfloat16(f0.z); t.a[3] = __float2bfloat16(f0.w);
        t.a[4] = __float2bfloat16(f1.x); t.a[5] = __float2bfloat16(f1.y);
        t.a[6] = __float2bfloat16(f1.z); t.a[7] = __float2bfloat16(f1.w);
        *(uint4*)(dst + base) = t.u;
    } else {
        *(uint4*)(dst + base) = *(const uint4*)((const bf16*)src + base);
    }
}

// ---------------------------------------------------------------------------
// Plain GEMM, tile 64 x 256 (full-N panels). 4 waves 2x2; wave = 32r x 128c,
// 16 MFMAs per barrier pair. A read exactly once across the grid.
// grid: (N/256, ceil(M/64)).
// ---------------------------------------------------------------------------
__global__ __launch_bounds__(256) void gemm_a(const void* __restrict__ A, int amode,
        const bf16* __restrict__ Wb, const void* __restrict__ bias,
        void* __restrict__ C, int cmode, int M, int N, int K, int relu,
        const float* __restrict__ flagp)
{
    const bool ef = flagp[0] > 0.5f;
    const bool a_bf16 = (amode == 1) || (amode == 2 && !ef);
    __shared__ __align__(16) bf16 As[64 * SAK];
    __shared__ __align__(16) bf16 Ws[256 * SAK];
    const int tid = threadIdx.x;
    const int m0 = blockIdx.y * 64, n0 = blockIdx.x * 256;
    const int w = tid >> 6, lane = tid & 63, lm = lane & 15, lq = lane >> 4;
    const int wr = w >> 1, wc = w & 1;
    const int srow = tid >> 2, scol = (tid & 3) * 8;

    f32x4 acc[2][8];
    #pragma unroll
    for (int mi = 0; mi < 2; mi++)
        #pragma unroll
        for (int nt = 0; nt < 8; nt++)
            acc[mi][nt] = (f32x4){0.f, 0.f, 0.f, 0.f};

    for (int k0 = 0; k0 < K; k0 += 32) {
        {
            const int arow = m0 + srow;
            bf16 tmp[8];
            if (arow < M) {
                size_t base = (size_t)arow * K + k0 + scol;
                if (a_bf16) {
                    *(uint4*)tmp = *(const uint4*)((const bf16*)A + base);
                } else {
                    const float* ap = (const float*)A + base;
                    float4 f0 = *(const float4*)ap;
                    float4 f1 = *(const float4*)(ap + 4);
                    tmp[0] = __float2bfloat16(f0.x); tmp[1] = __float2bfloat16(f0.y);
                    tmp[2] = __float2bfloat16(f0.z); tmp[3] = __float2bfloat16(f0.w);
                    tmp[4] = __float2bfloat16(f1.x); tmp[5] = __float2bfloat16(f1.y);
                    tmp[6] = __float2bfloat16(f1.z); tmp[7] = __float2bfloat16(f1.w);
                }
            } else {
                #pragma unroll
                for (int i = 0; i < 8; i++) tmp[i] = __float2bfloat16(0.f);
            }
            *(uint4*)&As[srow * SAK + scol] = *(const uint4*)tmp;
        }
        #pragma unroll
        for (int it = 0; it < 4; it++) {
            int rr = it * 64 + srow;
            *(uint4*)&Ws[rr * SAK + scol] =
                *(const uint4*)(Wb + (size_t)(n0 + rr) * K + k0 + scol);
        }
        __syncthreads();

        bf16x8 af0 = *(const bf16x8*)&As[(wr * 32 + lm) * SAK + lq * 8];
        bf16x8 af1 = *(const bf16x8*)&As[(wr * 32 + 16 + lm) * SAK + lq * 8];
        #pragma unroll
        for (int nt = 0; nt < 8; nt++) {
            bf16x8 bfr = *(const bf16x8*)&Ws[(wc * 128 + nt * 16 + lm) * SAK + lq * 8];
            acc[0][nt] = __builtin_amdgcn_mfma_f32_16x16x32_bf16(af0, bfr, acc[0][nt], 0, 0, 0);
            acc[1][nt] = __builtin_amdgcn_mfma_f32_16x16x32_bf16(af1, bfr, acc[1][nt], 0, 0, 0);
        }
        __syncthreads();
    }

    #pragma unroll
    for (int nt = 0; nt < 8; nt++) {
        int n = n0 + wc * 128 + nt * 16 + lm;
        float bv = ldv(bias, n, 2, ef);
        #pragma unroll
        for (int mi = 0; mi < 2; mi++) {
            #pragma unroll
            for (int r = 0; r < 4; r++) {
                int m = m0 + wr * 32 + mi * 16 + lq * 4 + r;
                if (m >= M) continue;
                float v = acc[mi][nt][r] + bv;
                if (relu) v = fmaxf(v, 0.f);
                size_t ci = (size_t)m * N + n;
                if (cmode == 0) ((float*)C)[ci] = v;
                else            ((bf16*)C)[ci] = __float2bfloat16(v);
            }
        }
    }
}

// ---------------------------------------------------------------------------
// Fused GEMM (N=256) + bias + residual + LayerNorm epilogue.
// Each block owns 64 complete rows -> LN in-block: 8-col/lane partials,
// shfl_xor across 16 lm lanes, tiny LDS exchange across the 2 wc waves.
// Outputs: out32 (fp32 residual chain), outbf (bf16 GEMM operand),
// optional dout (external dtype at obase, pre-qp), optional qp added after.
// grid: (1, ceil(M/64)).
// ---------------------------------------------------------------------------
__global__ __launch_bounds__(256) void gemm_ln(const bf16* __restrict__ A,
        const bf16* __restrict__ Wb, const void* __restrict__ bias,
        const float* __restrict__ res, const void* __restrict__ gw,
        const void* __restrict__ bw, float* __restrict__ out32,
        bf16* __restrict__ outbf, void* __restrict__ dout, size_t obase,
        const void* __restrict__ qp, int M, int K,
        const float* __restrict__ flagp)
{
    const bool ef = flagp[0] > 0.5f;
    __shared__ __align__(16) bf16 As[64 * SAK];
    __shared__ __align__(16) bf16 Ws[256 * SAK];
    const int tid = threadIdx.x;
    const int m0 = blockIdx.y * 64;
    const int w = tid >> 6, lane = tid & 63, lm = lane & 15, lq = lane >> 4;
    const int wr = w >> 1, wc = w & 1;
    const int srow = tid >> 2, scol = (tid & 3) * 8;

    f32x4 acc[2][8];
    #pragma unroll
    for (int mi = 0; mi < 2; mi++)
        #pragma unroll
        for (int nt = 0; nt < 8; nt++)
            acc[mi][nt] = (f32x4){0.f, 0.f, 0.f, 0.f};

    for (int k0 = 0; k0 < K; k0 += 32) {
        {
            const int arow = m0 + srow;
            uint4 ua = make_uint4(0u, 0u, 0u, 0u);
            if (arow < M)
                ua = *(const uint4*)(A + (size_t)arow * K + k0 + scol);
            *(uint4*)&As[srow * SAK + scol] = ua;
        }
        #pragma unroll
        for (int it = 0; it < 4; it++) {
            int rr = it * 64 + srow;
            *(uint4*)&Ws[rr * SAK + scol] =
                *(const uint4*)(Wb + (size_t)rr * K + k0 + scol);
        }
        __syncthreads();

        bf16x8 af0 = *(const bf16x8*)&As[(wr * 32 + lm) * SAK + lq * 8];
        bf16x8 af1 = *(const bf16x8*)&As[(wr * 32 + 16 + lm) * SAK + lq * 8];
        #pragma unroll
        for (int nt = 0; nt < 8; nt++) {
            bf16x8 bfr = *(const bf16x8*)&Ws[(wc * 128 + nt * 16 + lm) * SAK + lq * 8];
            acc[0][nt] = __builtin_amdgcn_mfma_f32_16x16x32_bf16(af0, bfr, acc[0][nt], 0, 0, 0);
            acc[1][nt] = __builtin_amdgcn_mfma_f32_16x16x32_bf16(af1, bfr, acc[1][nt], 0, 0, 0);
        }
        __syncthreads();
    }

    // ---- epilogue: v = acc + bias + res (in place) ----
    float bias_c[8], gcol[8], bcol[8];
    #pragma unroll
    for (int nt = 0; nt < 8; nt++) {
        int col = wc * 128 + nt * 16 + lm;
        bias_c[nt] = ldv(bias, col, 2, ef);
        gcol[nt]   = ldv(gw,   col, 2, ef);
        bcol[nt]   = ldv(bw,   col, 2, ef);
    }
    #pragma unroll
    for (int mi = 0; mi < 2; mi++)
        #pragma unroll
        for (int r = 0; r < 4; r++) {
            int row = m0 + wr * 32 + mi * 16 + lq * 4 + r;
            bool vr_ = row < M;
            #pragma unroll
            for (int nt = 0; nt < 8; nt++) {
                int col = wc * 128 + nt * 16 + lm;
                float rv = vr_ ? res[(size_t)row * DM + col] : 0.f;
                acc[mi][nt][r] += bias_c[nt] + rv;
            }
        }

    // ---- LN reductions (red[0..127]=mu partials, red[128..255]=var) ----
    float* red = (float*)As;
    float mu[2][4], rstd[2][4];
    #pragma unroll
    for (int mi = 0; mi < 2; mi++)
        #pragma unroll
        for (int r = 0; r < 4; r++) {
            float s = 0.f;
            #pragma unroll
            for (int nt = 0; nt < 8; nt++) s += acc[mi][nt][r];
            s += __shfl_xor(s, 1, 64); s += __shfl_xor(s, 2, 64);
            s += __shfl_xor(s, 4, 64); s += __shfl_xor(s, 8, 64);
            if (lm == 0) red[(wr * 32 + mi * 16 + lq * 4 + r) * 2 + wc] = s;
        }
    __syncthreads();
    #pragma unroll
    for (int mi = 0; mi < 2; mi++)
        #pragma unroll
        for (int r = 0; r < 4; r++) {
            int rl = wr * 32 + mi * 16 + lq * 4 + r;
            mu[mi][r] = (red[rl * 2] + red[rl * 2 + 1]) * (1.f / DM);
        }
    #pragma unroll
    for (int mi = 0; mi < 2; mi++)
        #pragma unroll
        for (int r = 0; r < 4; r++) {
            float q = 0.f;
            #pragma unroll
            for (int nt = 0; nt < 8; nt++) {
                float d = acc[mi][nt][r] - mu[mi][r];
                q += d * d;
            }
            q += __shfl_xor(q, 1, 64); q += __shfl_xor(q, 2, 64);
            q += __shfl_xor(q, 4, 64); q += __shfl_xor(q, 8, 64);
            if (lm == 0) red[128 + (wr * 32 + mi * 16 + lq * 4 + r) * 2 + wc] = q;
        }
    __syncthreads();
    #pragma unroll
    for (int mi = 0; mi < 2; mi++)
        #pragma unroll
        for (int r = 0; r < 4; r++) {
            int rl = wr * 32 + mi * 16 + lq * 4 + r;
            float var = (red[128 + rl * 2] + red[128 + rl * 2 + 1]) * (1.f / DM);
            rstd[mi][r] = rsqrtf(var + LN_EPS);
        }

    // ---- normalize & store ----
    #pragma unroll
    for (int mi = 0; mi < 2; mi++)
        #pragma unroll
        for (int r = 0; r < 4; r++) {
            int row = m0 + wr * 32 + mi * 16 + lq * 4 + r;
            if (row >= M) continue;
            size_t rbase = (size_t)row * DM;
            #pragma unroll
            for (int nt = 0; nt < 8; nt++) {
                int col = wc * 128 + nt * 16 + lm;
                float o = (acc[mi][nt][r] - mu[mi][r]) * rstd[mi][r] * gcol[nt] + bcol[nt];
                if (dout) {
                    if (ef) ((float*)dout)[obase + rbase + col] = o;
                    else    ((bf16*)dout)[obase + rbase + col] = __float2bfloat16(o);
                }
                float o2 = o + (qp ? ldv(qp, rbase + col, 2, ef) : 0.f);
                out32[rbase + col] = o2;
                outbf[rbase + col] = __float2bfloat16(o2);
            }
        }
}

// ---------------------------------------------------------------------------
// Fused sampling-offset + attention-weight GEMM: W = concat(so_w, aw_w) rows
// (N=384). Tile 64 x 128; block column 0-1 -> attoff (stride 256, so bias),
// column 2 -> awb (stride 128, aw bias). grid (3, ceil(M/64)).
// ---------------------------------------------------------------------------
__global__ __launch_bounds__(256) void gemm_soaw(const bf16* __restrict__ A,
        const bf16* __restrict__ Wb, const void* __restrict__ b1,
        const void* __restrict__ b2, float* __restrict__ C1,
        float* __restrict__ C2, int M, const float* __restrict__ flagp)
{
    const bool ef = flagp[0] > 0.5f;
    const int K = DM;
    __shared__ __align__(16) bf16 As[64 * SAK];
    __shared__ __align__(16) bf16 Ws[128 * SAK];
    const int tid = threadIdx.x;
    const int m0 = blockIdx.y * 64, n0 = blockIdx.x * 128;
    const int w = tid >> 6, lane = tid & 63, lm = lane & 15, lq = lane >> 4;
    const int wr = w >> 1, wc = w & 1;
    const int srow = tid >> 2, scol = (tid & 3) * 8;

    f32x4 acc[2][4];
    #pragma unroll
    for (int mi = 0; mi < 2; mi++)
        #pragma unroll
        for (int nt = 0; nt < 4; nt++)
            acc[mi][nt] = (f32x4){0.f, 0.f, 0.f, 0.f};

    for (int k0 = 0; k0 < K; k0 += 32) {
        {
            const int arow = m0 + srow;
            uint4 ua = make_uint4(0u, 0u, 0u, 0u);
            if (arow < M)
                ua = *(const uint4*)(A + (size_t)arow * K + k0 + scol);
            *(uint4*)&As[srow * SAK + scol] = ua;
        }
        #pragma unroll
        for (int it = 0; it < 2; it++) {
            int rr = it * 64 + srow;
            *(uint4*)&Ws[rr * SAK + scol] =
                *(const uint4*)(Wb + (size_t)(n0 + rr) * K + k0 + scol);
        }
        __syncthreads();

        bf16x8 af0 = *(const bf16x8*)&As[(wr * 32 + lm) * SAK + lq * 8];
        bf16x8 af1 = *(const bf16x8*)&As[(wr * 32 + 16 + lm) * SAK + lq * 8];
        #pragma unroll
        for (int nt = 0; nt < 4; nt++) {
            bf16x8 bfr = *(const bf16x8*)&Ws[(wc * 64 + nt * 16 + lm) * SAK + lq * 8];
            acc[0][nt] = __builtin_amdgcn_mfma_f32_16x16x32_bf16(af0, bfr, acc[0][nt], 0, 0, 0);
            acc[1][nt] = __builtin_amdgcn_mfma_f32_16x16x32_bf16(af1, bfr, acc[1][nt], 0, 0, 0);
        }
        __syncthreads();
    }

    float* Cd; const void* bsrc; int nst, c0;
    if (n0 < 256) { Cd = C1; bsrc = b1; nst = 256; c0 = n0; }
    else          { Cd = C2; bsrc = b2; nst = 128; c0 = n0 - 256; }

    #pragma unroll
    for (int nt = 0; nt < 4; nt++) {
        int cl = wc * 64 + nt * 16 + lm;        // 0..127 within block
        float bv = ldv(bsrc, c0 + cl, 2, ef);
        #pragma unroll
        for (int mi = 0; mi < 2; mi++) {
            #pragma unroll
            for (int r = 0; r < 4; r++) {
                int m = m0 + wr * 32 + mi * 16 + lq * 4 + r;
                if (m >= M) continue;
                Cd[(size_t)m * nst + c0 + cl] = acc[mi][nt][r] + bv;
            }
        }
    }
}

// ---------------------------------------------------------------------------
__global__ __launch_bounds__(256) void add_qpos(const void* __restrict__ a, int amode,
        const void* __restrict__ qp, float* __restrict__ o, bf16* __restrict__ ob,
        const float* __restrict__ flagp)
{
    const bool ef = flagp[0] > 0.5f;
    int i = blockIdx.x * 256 + threadIdx.x;
    float v = ldv(a, i, amode, ef) + ldv(qp, i, 2, ef);
    o[i]  = v;
    ob[i] = __float2bfloat16(v);
}

// ---------------------------------------------------------------------------
// MFMA flash MHA. grid (15 qtiles, 8 h, 8 b), 256 thr = 4 waves.
// ---------------------------------------------------------------------------
__global__ __launch_bounds__(256) void mha_mfma(const bf16* __restrict__ qkv,
        bf16* __restrict__ out)
{
    const int qt = blockIdx.x, h = blockIdx.y, b = blockIdx.z;
    const int q0 = qt * 64;
    const int tid = threadIdx.x;
    const int w = tid >> 6, lane = tid & 63;
    const int lm = lane & 15, lq = lane >> 4;
    const int srow = tid >> 2, sc = (tid & 3) * 8;

    __shared__ __align__(16) bf16 Qs[64][SAK];
    __shared__ __align__(16) bf16 Ks[64][SAK];
    __shared__ __align__(16) bf16 Vt[32][66];
    __shared__ __align__(16) bf16 Pt[64][66];

    const bf16* base = qkv + (size_t)b * NQ * 768;

    {
        bf16 tmp[8];
        if (q0 + srow < NQ) {
            uint4 u = *(const uint4*)(base + (size_t)(q0 + srow) * 768 + h * DHEAD + sc);
            float t[8]; unpack8(u, t);
            #pragma unroll
            for (int i = 0; i < 8; i++) tmp[i] = __float2bfloat16(t[i] * ATT_SCALE);
        } else {
            #pragma unroll
            for (int i = 0; i < 8; i++) tmp[i] = __float2bfloat16(0.f);
        }
        *(uint4*)&Qs[srow][sc] = *(const uint4*)tmp;
    }
    __syncthreads();
    const bf16x8 qf = *(const bf16x8*)&Qs[w * 16 + lm][lq * 8];

    f32x4 O[2] = {{0.f,0.f,0.f,0.f},{0.f,0.f,0.f,0.f}};
    float mrow = -1e30f, lrow = 0.f;

    for (int k0 = 0; k0 < NQ; k0 += 64) {
        __syncthreads();
        {
            uint4 uk = {0u,0u,0u,0u}, uv = {0u,0u,0u,0u};
            if (k0 + srow < NQ) {
                const bf16* rp = base + (size_t)(k0 + srow) * 768 + h * DHEAD + sc;
                uk = *(const uint4*)(rp + 256);
                uv = *(const uint4*)(rp + 512);
            }
            *(uint4*)&Ks[srow][sc] = uk;
            const bf16* vv = (const bf16*)&uv;
            #pragma unroll
            for (int i = 0; i < 8; i++) Vt[sc + i][srow] = vv[i];
        }
        __syncthreads();

        float sv[16];
        #pragma unroll
        for (int mt = 0; mt < 4; mt++) {
            bf16x8 kf = *(const bf16x8*)&Ks[mt * 16 + lm][lq * 8];
            f32x4 d = __builtin_amdgcn_mfma_f32_16x16x32_bf16(kf, qf,
                        (f32x4){0.f,0.f,0.f,0.f}, 0, 0, 0);
            sv[mt*4+0] = d[0]; sv[mt*4+1] = d[1]; sv[mt*4+2] = d[2]; sv[mt*4+3] = d[3];
        }
        #pragma unroll
        for (int mt = 0; mt < 4; mt++)
            #pragma unroll
            for (int r = 0; r < 4; r++)
                if (k0 + mt * 16 + lq * 4 + r >= NQ) sv[mt*4+r] = -1e30f;

        float tmax = sv[0];
        #pragma unroll
        for (int j = 1; j < 16; j++) tmax = fmaxf(tmax, sv[j]);
        tmax = fmaxf(tmax, __shfl_xor(tmax, 16, 64));
        tmax = fmaxf(tmax, __shfl_xor(tmax, 32, 64));
        float mnew = fmaxf(mrow, tmax);
        float alpha = __expf(mrow - mnew);
        mrow = mnew;
        float psum = 0.f;
        #pragma unroll
        for (int j = 0; j < 16; j++) {
            float p = __expf(sv[j] - mnew);
            sv[j] = p; psum += p;
        }
        psum += __shfl_xor(psum, 16, 64);
        psum += __shfl_xor(psum, 32, 64);
        lrow = lrow * alpha + psum;

        #pragma unroll
        for (int mt = 0; mt < 4; mt++)
            #pragma unroll
            for (int r = 0; r < 4; r++)
                Pt[mt * 16 + lq * 4 + r][w * 16 + lm] = __float2bfloat16(sv[mt*4+r]);

        #pragma unroll
        for (int mt = 0; mt < 2; mt++)
            #pragma unroll
            for (int r = 0; r < 4; r++) O[mt][r] *= alpha;
        #pragma unroll
        for (int ks = 0; ks < 2; ks++) {
            union { bf16 a[8]; bf16x8 v; } pf;
            #pragma unroll
            for (int j = 0; j < 8; j++)
                pf.a[j] = Pt[ks * 32 + lq * 8 + j][w * 16 + lm];
            #pragma unroll
            for (int mt = 0; mt < 2; mt++) {
                bf16x8 vf = *(const bf16x8*)&Vt[mt * 16 + lm][ks * 32 + lq * 8];
                O[mt] = __builtin_amdgcn_mfma_f32_16x16x32_bf16(vf, pf.v, O[mt], 0, 0, 0);
            }
        }
    }

    int q = q0 + w * 16 + lm;
    if (q < NQ) {
        float invl = 1.f / lrow;
        bf16* op = out + ((size_t)(b * NQ + q)) * DM + h * DHEAD;
        #pragma unroll
        for (int mt = 0; mt < 2; mt++)
            #pragma unroll
            for (int r = 0; r < 4; r++)
                op[mt * 16 + lq * 4 + r] = __float2bfloat16(O[mt][r] * invl);
    }
}

// ---------------------------------------------------------------------------
// MSDA sampling with inline attention-weight softmax (raw logits in).
// ---------------------------------------------------------------------------
__global__ __launch_bounds__(256) void msda_sample(const bf16* __restrict__ value,
        const float* __restrict__ off, const float* __restrict__ aw,
        const void* __restrict__ refp, const void* __restrict__ vr,
        bf16* __restrict__ out, const float* __restrict__ flagp)
{
    const bool ef = flagp[0] > 0.5f;
    int bq = blockIdx.x; int b = bq / NQ;
    int tid = threadIdx.x; int h = tid >> 5, d = tid & 31;
    __shared__ float sOff[256];
    __shared__ float sAw[128];
    __shared__ float sref[2];
    __shared__ float svr[8];
    sOff[tid] = off[(size_t)bq * 256 + tid];
    if (tid < 128) sAw[tid] = aw[(size_t)bq * 128 + tid];
    if (tid < 2)   sref[tid] = ldv(refp, bq * 2 + tid, 2, ef);
    if (tid < 8)   svr[tid]  = ldv(vr, b * 8 + tid, 2, ef);
    __syncthreads();
    if (tid < 8) {
        float* p = &sAw[tid * 16];
        float mx = -1e30f;
        #pragma unroll
        for (int j = 0; j < 16; j++) mx = fmaxf(mx, p[j]);
        float s = 0.f;
        #pragma unroll
        for (int j = 0; j < 16; j++) { float e = __expf(p[j] - mx); p[j] = e; s += e; }
        float inv = 1.f / s;
        #pragma unroll
        for (int j = 0; j < 16; j++) p[j] *= inv;
    }
    __syncthreads();
    const bf16* vb = value + (size_t)b * NS * DM + h * DHEAD + d;
    const int HS[4] = {100, 50, 25, 13};
    const int ST[4] = {0, 10000, 12500, 13125};
    float acc = 0.f;
    #pragma unroll
    for (int lvl = 0; lvl < 4; lvl++) {
        int W_ = HS[lvl], H_ = HS[lvl], st = ST[lvl];
        float rx = sref[0] * svr[lvl*2 + 0] * (float)W_;
        float ry = sref[1] * svr[lvl*2 + 1] * (float)H_;
        #pragma unroll
        for (int p = 0; p < 4; p++) {
            int oi = h * 32 + lvl * 8 + p * 2;
            float x = fminf(fmaxf(rx + sOff[oi]     - 0.5f, -4.f), (float)W_ + 4.f);
            float y = fminf(fmaxf(ry + sOff[oi + 1] - 0.5f, -4.f), (float)H_ + 4.f);
            float x0f = floorf(x), y0f = floorf(y);
            float wx = x - x0f, wy = y - y0f;
            int x0 = (int)x0f, y0 = (int)y0f;
            int x1i = x0 + 1, y1i = y0 + 1;
            bool vx0 = (x0 >= 0) && (x0 < W_), vx1 = (x1i >= 0) && (x1i < W_);
            bool vy0 = (y0 >= 0) && (y0 < H_), vy1 = (y1i >= 0) && (y1i < H_);
            float g = 0.f;
            if (vy0) {
                int rowo = (st + y0 * W_) * DM;
                if (vx0) g += (1.f - wx) * (1.f - wy) * __bfloat162float(vb[rowo + x0  * DM]);
                if (vx1) g += wx         * (1.f - wy) * __bfloat162float(vb[rowo + x1i * DM]);
            }
            if (vy1) {
                int rowo = (st + y1i * W_) * DM;
                if (vx0) g += (1.f - wx) * wy * __bfloat162float(vb[rowo + x0  * DM]);
                if (vx1) g += wx         * wy * __bfloat162float(vb[rowo + x1i * DM]);
            }
            acc += g * sAw[h * 16 + lvl * 4 + p];
        }
    }
    out[(size_t)bq * DM + tid] = __float2bfloat16(acc);
}

// ---------------------------------------------------------------------------
__global__ __launch_bounds__(256) void copy_refs(const void* __restrict__ refp,
        void* __restrict__ out, const float* __restrict__ flagp)
{
    const bool ef = flagp[0] > 0.5f;
    int i = blockIdx.x * 256 + threadIdx.x;
    if (i >= NLAY * BQ * 2) return;
    float v = ldv(refp, i % (BQ * 2), 2, ef);
    size_t oi = (size_t)NLAY * BQ * DM + i;
    if (ef) ((float*)out)[oi] = v;
    else    ((bf16*)out)[oi] = __float2bfloat16(v);
}

// ---------------------------------------------------------------------------
extern "C" void kernel_launch(void* const* d_in, const int* in_sizes, int n_in,
                              void* d_out, int out_size, void* d_ws, size_t ws_size,
                              hipStream_t stream)
{
    const void* tgt     = d_in[0];
    const void* refp    = d_in[1];
    const void* memory  = d_in[2];
    const void* vr      = d_in[5];
    const void* qp      = d_in[6];
    const void* sa_in_w = d_in[7];
    const void* sa_in_b = d_in[8];
    const void* sa_out_w= d_in[9];
    const void* sa_out_b= d_in[10];
    const void* n1_g    = d_in[11];
    const void* n1_b    = d_in[12];
    const void* n2_g    = d_in[13];
    const void* n2_b    = d_in[14];
    const void* n3_g    = d_in[15];
    const void* n3_b    = d_in[16];
    const void* vp_w    = d_in[17];
    const void* vp_b    = d_in[18];
    const void* so_w    = d_in[19];
    const void* so_b    = d_in[20];
    const void* aw_w    = d_in[21];
    const void* aw_b    = d_in[22];
    const void* op_w    = d_in[23];
    const void* op_b    = d_in[24];
    const void* ff1_w   = d_in[25];
    const void* ff1_b   = d_in[26];
    const void* ff2_w   = d_in[27];
    const void* ff2_b   = d_in[28];

    // ---- workspace layout ----
    char* w = (char*)d_ws;
    float* flagp  = (float*)w;  w += 256;
    bf16*  value  = (bf16*)w;   w += (size_t)NB * NS * DM * 2;   // 54.45 MB
    float* outbuf = (float*)w;  w += (size_t)BQ * DM * 4;
    float* x1samp = (float*)w;  w += (size_t)BQ * DM * 4;
    bf16*  bigb   = (bf16*)w;   w += (size_t)BQ * NFF * 2;       // qkv / ffn hidden
    float* attoff = (float*)w;  w += (size_t)BQ * DM * 4;        // sampling offsets
    float* awb    = (float*)w;  w += (size_t)BQ * 128 * 4;       // aw logits
    bf16*  abuf   = (bf16*)w;   w += (size_t)BQ * DM * 2;        // x1/mha/msda bf16
    bf16*  outbf  = (bf16*)w;   w += (size_t)BQ * DM * 2;        // ln bf16 dup
    // pre-converted bf16 weights
    bf16* wb_sa_in = (bf16*)w;  w += (size_t)768 * 256 * 2;
    bf16* wb_sa_out= (bf16*)w;  w += (size_t)256 * 256 * 2;
    bf16* wb_soaw  = (bf16*)w;  w += (size_t)384 * 256 * 2;      // so(256) ++ aw(128)
    bf16* wb_op    = (bf16*)w;  w += (size_t)256 * 256 * 2;
    bf16* wb_ff1   = (bf16*)w;  w += (size_t)NFF * 256 * 2;
    bf16* wb_ff2   = (bf16*)w;  w += (size_t)256 * NFF * 2;
    bf16* wb_vp    = (bf16*)w;  w += (size_t)256 * 256 * 2;

    const int gy = (BQ + 63) / 64;      // 113
    const int MV = NB * NS;             // 106352

    // 0) detect external dtype, pre-convert weights to bf16
    detect_dtype<<<1, 256, 0, stream>>>(tgt, flagp);
    convert_w<<< 96, 256, 0, stream>>>(sa_in_w,  wb_sa_in,  flagp);
    convert_w<<< 32, 256, 0, stream>>>(sa_out_w, wb_sa_out, flagp);
    convert_w<<< 32, 256, 0, stream>>>(so_w,     wb_soaw,   flagp);
    convert_w<<< 16, 256, 0, stream>>>(aw_w,     wb_soaw + 256 * 256, flagp);
    convert_w<<< 32, 256, 0, stream>>>(op_w,     wb_op,     flagp);
    convert_w<<<128, 256, 0, stream>>>(ff1_w,    wb_ff1,    flagp);
    convert_w<<<128, 256, 0, stream>>>(ff2_w,    wb_ff2,    flagp);
    convert_w<<< 32, 256, 0, stream>>>(vp_w,     wb_vp,     flagp);

    // 1) value projection (layer-invariant): A read once, full rows per block
    gemm_a<<<dim3(1, (MV + 63) / 64), 256, 0, stream>>>(
        memory, 2, wb_vp, vp_b, value, 1, MV, DM, DM, 0, flagp);

    // 2) inter_refs output
    copy_refs<<<(NLAY * BQ * 2 + 255) / 256, 256, 0, stream>>>(refp, d_out, flagp);

    // 3) x1 = tgt + query_pos (only needed for layer 0; later layers fused)
    add_qpos<<<BQ * DM / 256, 256, 0, stream>>>(tgt, 2, qp, x1samp, abuf, flagp);

    for (int l = 0; l < NLAY; l++) {
        // self-attention
        gemm_a<<<dim3(768/256, gy), 256, 0, stream>>>(
            abuf, 1, wb_sa_in, sa_in_b, bigb, 1, BQ, 768, DM, 0, flagp);
        mha_mfma<<<dim3(15, NHEADS, NB), 256, 0, stream>>>(bigb, abuf);
        gemm_ln<<<dim3(1, gy), 256, 0, stream>>>(
            abuf, wb_sa_out, sa_out_b, x1samp, n1_g, n1_b,
            outbuf, outbf, nullptr, 0, nullptr, BQ, DM, flagp);

        // MSDA: fused so+aw GEMM, sampling w/ inline softmax, op GEMM + LN2
        gemm_soaw<<<dim3(3, gy), 256, 0, stream>>>(
            outbf, wb_soaw, so_b, aw_b, attoff, awb, BQ, flagp);
        msda_sample<<<BQ, 256, 0, stream>>>(value, attoff, awb, refp, vr, abuf, flagp);
        gemm_ln<<<dim3(1, gy), 256, 0, stream>>>(
            abuf, wb_op, op_b, outbuf, n2_g, n2_b,
            outbuf, outbf, nullptr, 0, nullptr, BQ, DM, flagp);

        // FFN: ff1 (relu, bf16 hidden), ff2 + LN3 + d_out slice + next x1(+qp)
        gemm_a<<<dim3(NFF/256, gy), 256, 0, stream>>>(
            outbf, 1, wb_ff1, ff1_b, bigb, 1, BQ, NFF, DM, 1, flagp);
        gemm_ln<<<dim3(1, gy), 256, 0, stream>>>(
            bigb, wb_ff2, ff2_b, outbuf, n3_g, n3_b,
            x1samp, abuf, d_out, (size_t)l * BQ * DM, qp, BQ, NFF, flagp);
    }
}

// Round 4
// 1735.972 us; speedup vs baseline: 1.6158x; 1.1002x over previous
//
#include <hip/hip_runtime.h>
#include <hip/hip_bf16.h>

typedef __hip_bfloat16 bf16;
typedef __bf16 bf16x8 __attribute__((ext_vector_type(8)));
typedef float  f32x4  __attribute__((ext_vector_type(4)));

#define NB 8
#define NQ 900
#define DM 256
#define NHEADS 8
#define DHEAD 32
#define NFF 1024
#define NLAY 6
#define NS 13294
#define BQ (NB*NQ)            // 7200
#define LN_EPS 1e-5f
#define ATT_SCALE 0.17677669529663687f   // 1/sqrt(32)
#define SAK 40                // LDS row stride (bf16): 80B — measured ~2-way (free)

__device__ __forceinline__ float bfd(const bf16* p, size_t i){ return __bfloat162float(p[i]); }

// mode: 0 = fp32 (internal), 1 = bf16 (internal), 2 = external (dtype per flag)
__device__ __forceinline__ float ldv(const void* p, size_t i, int mode, bool extF32)
{
    if (mode == 0) return ((const float*)p)[i];
    if (mode == 1) return bfd((const bf16*)p, i);
    return extF32 ? ((const float*)p)[i] : bfd((const bf16*)p, i);
}

// unpack 8 bf16 (16B) to floats
__device__ __forceinline__ void unpack8(uint4 u, float* t)
{
    t[0] = __uint_as_float((u.x & 0xffffu) << 16);
    t[1] = __uint_as_float(u.x & 0xffff0000u);
    t[2] = __uint_as_float((u.y & 0xffffu) << 16);
    t[3] = __uint_as_float(u.y & 0xffff0000u);
    t[4] = __uint_as_float((u.z & 0xffffu) << 16);
    t[5] = __uint_as_float(u.z & 0xffff0000u);
    t[6] = __uint_as_float((u.w & 0xffffu) << 16);
    t[7] = __uint_as_float(u.w & 0xffff0000u);
}

// ---------------------------------------------------------------------------
__global__ __launch_bounds__(256) void detect_dtype(const void* __restrict__ tgt,
        float* __restrict__ flag)
{
    __shared__ float red[256];
    int t = threadIdx.x;
    const unsigned short* u = (const unsigned short*)tgt;
    float m = 0.f;
    for (int i = t; i < 2048; i += 256) {
        unsigned int bits = ((unsigned int)u[i]) << 16;
        float v = fabsf(__uint_as_float(bits));
        if (!isfinite(v)) v = 1e30f;
        m = fmaxf(m, v);
    }
    red[t] = m;
    __syncthreads();
    for (int st = 128; st; st >>= 1) {
        if (t < st) red[t] = fmaxf(red[t], red[t + st]);
        __syncthreads();
    }
    if (t == 0) flag[0] = (red[0] > 1e8f) ? 1.f : 0.f;
}

// ---------------------------------------------------------------------------
__global__ __launch_bounds__(256) void convert_w(const void* __restrict__ src,
        bf16* __restrict__ dst, const float* __restrict__ flagp)
{
    const bool ef = flagp[0] > 0.5f;
    size_t base = ((size_t)blockIdx.x * 256 + threadIdx.x) * 8;
    if (ef) {
        const float* s = (const float*)src + base;
        float4 f0 = *(const float4*)s;
        float4 f1 = *(const float4*)(s + 4);
        union { bf16 a[8]; uint4 u; } t;
        t.a[0] = __float2bfloat16(f0.x); t.a[1] = __float2bfloat16(f0.y);
        t.a[2] = __float2bfloat16(f0.z); t.a[3] = __float2bfloat16(f0.w);
        t.a[4] = __float2bfloat16(f1.x); t.a[5] = __float2bfloat16(f1.y);
        t.a[6] = __float2bfloat16(f1.z); t.a[7] = __float2bfloat16(f1.w);
        *(uint4*)(dst + base) = t.u;
    } else {
        *(uint4*)(dst + base) = *(const uint4*)((const bf16*)src + base);
    }
}

// ---------------------------------------------------------------------------
// stage A tile [32][32] : thread t -> row t>>3, col (t&7)*4  (uint2 / float4)
// ---------------------------------------------------------------------------
__device__ __forceinline__ void stage_a32(bf16* As, const void* A, bool a_bf16,
        int m0, int M, int K, int k0, int tid)
{
    const int row = tid >> 3, col = (tid & 7) * 4;
    const int arow = m0 + row;
    union { bf16 a[4]; uint2 u; } t;
    if (arow < M) {
        size_t base = (size_t)arow * K + k0 + col;
        if (a_bf16) {
            t.u = *(const uint2*)((const bf16*)A + base);
        } else {
            float4 f = *(const float4*)((const float*)A + base);
            t.a[0] = __float2bfloat16(f.x); t.a[1] = __float2bfloat16(f.y);
            t.a[2] = __float2bfloat16(f.z); t.a[3] = __float2bfloat16(f.w);
        }
    } else {
        t.u = make_uint2(0u, 0u);
    }
    *(uint2*)&As[row * SAK + col] = t.u;
}

// ---------------------------------------------------------------------------
// Plain GEMM, tile 32 x 256. 4 waves 2x2; wave = 16r x 128c, 8 MFMAs/K-step.
// acc = 32 AGPR -> ~104 regs/wave -> 16 waves/CU occupancy target.
// grid: (N/256, ceil(M/32)).
// ---------------------------------------------------------------------------
__global__ __launch_bounds__(256) void gemm_a(const void* __restrict__ A, int amode,
        const bf16* __restrict__ Wb, const void* __restrict__ bias,
        void* __restrict__ C, int cmode, int M, int N, int K, int relu,
        const float* __restrict__ flagp)
{
    const bool ef = flagp[0] > 0.5f;
    const bool a_bf16 = (amode == 1) || (amode == 2 && !ef);
    __shared__ __align__(16) bf16 As[32 * SAK];
    __shared__ __align__(16) bf16 Ws[256 * SAK];
    const int tid = threadIdx.x;
    const int m0 = blockIdx.y * 32, n0 = blockIdx.x * 256;
    const int w = tid >> 6, lane = tid & 63, lm = lane & 15, lq = lane >> 4;
    const int wr = w >> 1, wc = w & 1;
    const int srow = tid >> 2, scol = (tid & 3) * 8;

    f32x4 acc[8];
    #pragma unroll
    for (int nt = 0; nt < 8; nt++) acc[nt] = (f32x4){0.f, 0.f, 0.f, 0.f};

    for (int k0 = 0; k0 < K; k0 += 32) {
        stage_a32(As, A, a_bf16, m0, M, K, k0, tid);
        #pragma unroll
        for (int it = 0; it < 4; it++) {
            int rr = it * 64 + srow;
            *(uint4*)&Ws[rr * SAK + scol] =
                *(const uint4*)(Wb + (size_t)(n0 + rr) * K + k0 + scol);
        }
        __syncthreads();

        bf16x8 af = *(const bf16x8*)&As[(wr * 16 + lm) * SAK + lq * 8];
        #pragma unroll
        for (int nt = 0; nt < 8; nt++) {
            bf16x8 bfr = *(const bf16x8*)&Ws[(wc * 128 + nt * 16 + lm) * SAK + lq * 8];
            acc[nt] = __builtin_amdgcn_mfma_f32_16x16x32_bf16(af, bfr, acc[nt], 0, 0, 0);
        }
        __syncthreads();
    }

    #pragma unroll
    for (int nt = 0; nt < 8; nt++) {
        int n = n0 + wc * 128 + nt * 16 + lm;
        float bv = ldv(bias, n, 2, ef);
        #pragma unroll
        for (int r = 0; r < 4; r++) {
            int m = m0 + wr * 16 + lq * 4 + r;
            if (m >= M) continue;
            float v = acc[nt][r] + bv;
            if (relu) v = fmaxf(v, 0.f);
            size_t ci = (size_t)m * N + n;
            if (cmode == 0) ((float*)C)[ci] = v;
            else            ((bf16*)C)[ci] = __float2bfloat16(v);
        }
    }
}

// ---------------------------------------------------------------------------
// Fused GEMM (N=256) + bias + residual + LayerNorm. Tile 32 x 256.
// Block owns 32 complete rows; LN via shfl over 16 lm-lanes + LDS wc-exchange.
// grid: (1, ceil(M/32)).
// ---------------------------------------------------------------------------
__global__ __launch_bounds__(256) void gemm_ln(const bf16* __restrict__ A,
        const bf16* __restrict__ Wb, const void* __restrict__ bias,
        const float* __restrict__ res, const void* __restrict__ gw,
        const void* __restrict__ bw, float* __restrict__ out32,
        bf16* __restrict__ outbf, void* __restrict__ dout, size_t obase,
        const void* __restrict__ qp, int M, int K,
        const float* __restrict__ flagp)
{
    const bool ef = flagp[0] > 0.5f;
    __shared__ __align__(16) bf16 As[32 * SAK];
    __shared__ __align__(16) bf16 Ws[256 * SAK];
    const int tid = threadIdx.x;
    const int m0 = blockIdx.y * 32;
    const int w = tid >> 6, lane = tid & 63, lm = lane & 15, lq = lane >> 4;
    const int wr = w >> 1, wc = w & 1;
    const int srow = tid >> 2, scol = (tid & 3) * 8;

    f32x4 acc[8];
    #pragma unroll
    for (int nt = 0; nt < 8; nt++) acc[nt] = (f32x4){0.f, 0.f, 0.f, 0.f};

    for (int k0 = 0; k0 < K; k0 += 32) {
        stage_a32(As, A, true, m0, M, K, k0, tid);
        #pragma unroll
        for (int it = 0; it < 4; it++) {
            int rr = it * 64 + srow;
            *(uint4*)&Ws[rr * SAK + scol] =
                *(const uint4*)(Wb + (size_t)rr * K + k0 + scol);
        }
        __syncthreads();

        bf16x8 af = *(const bf16x8*)&As[(wr * 16 + lm) * SAK + lq * 8];
        #pragma unroll
        for (int nt = 0; nt < 8; nt++) {
            bf16x8 bfr = *(const bf16x8*)&Ws[(wc * 128 + nt * 16 + lm) * SAK + lq * 8];
            acc[nt] = __builtin_amdgcn_mfma_f32_16x16x32_bf16(af, bfr, acc[nt], 0, 0, 0);
        }
        __syncthreads();
    }

    // ---- epilogue: v = acc + bias + res ----
    float bias_c[8], gcol[8], bcol[8];
    #pragma unroll
    for (int nt = 0; nt < 8; nt++) {
        int col = wc * 128 + nt * 16 + lm;
        bias_c[nt] = ldv(bias, col, 2, ef);
        gcol[nt]   = ldv(gw,   col, 2, ef);
        bcol[nt]   = ldv(bw,   col, 2, ef);
    }
    #pragma unroll
    for (int r = 0; r < 4; r++) {
        int row = m0 + wr * 16 + lq * 4 + r;
        bool vr_ = row < M;
        #pragma unroll
        for (int nt = 0; nt < 8; nt++) {
            int col = wc * 128 + nt * 16 + lm;
            float rv = vr_ ? res[(size_t)row * DM + col] : 0.f;
            acc[nt][r] += bias_c[nt] + rv;
        }
    }

    // ---- LN reductions (red[0..63]=mean partials, red[64..127]=var) ----
    float* red = (float*)As;
    float mu[4], rstd[4];
    #pragma unroll
    for (int r = 0; r < 4; r++) {
        float s = 0.f;
        #pragma unroll
        for (int nt = 0; nt < 8; nt++) s += acc[nt][r];
        s += __shfl_xor(s, 1, 64); s += __shfl_xor(s, 2, 64);
        s += __shfl_xor(s, 4, 64); s += __shfl_xor(s, 8, 64);
        if (lm == 0) red[(wr * 16 + lq * 4 + r) * 2 + wc] = s;
    }
    __syncthreads();
    #pragma unroll
    for (int r = 0; r < 4; r++) {
        int rl = wr * 16 + lq * 4 + r;
        mu[r] = (red[rl * 2] + red[rl * 2 + 1]) * (1.f / DM);
    }
    #pragma unroll
    for (int r = 0; r < 4; r++) {
        float q = 0.f;
        #pragma unroll
        for (int nt = 0; nt < 8; nt++) {
            float d = acc[nt][r] - mu[r];
            q += d * d;
        }
        q += __shfl_xor(q, 1, 64); q += __shfl_xor(q, 2, 64);
        q += __shfl_xor(q, 4, 64); q += __shfl_xor(q, 8, 64);
        if (lm == 0) red[64 + (wr * 16 + lq * 4 + r) * 2 + wc] = q;
    }
    __syncthreads();
    #pragma unroll
    for (int r = 0; r < 4; r++) {
        int rl = wr * 16 + lq * 4 + r;
        float var = (red[64 + rl * 2] + red[64 + rl * 2 + 1]) * (1.f / DM);
        rstd[r] = rsqrtf(var + LN_EPS);
    }

    // ---- normalize & store ----
    #pragma unroll
    for (int r = 0; r < 4; r++) {
        int row = m0 + wr * 16 + lq * 4 + r;
        if (row >= M) continue;
        size_t rbase = (size_t)row * DM;
        #pragma unroll
        for (int nt = 0; nt < 8; nt++) {
            int col = wc * 128 + nt * 16 + lm;
            float o = (acc[nt][r] - mu[r]) * rstd[r] * gcol[nt] + bcol[nt];
            if (dout) {
                if (ef) ((float*)dout)[obase + rbase + col] = o;
                else    ((bf16*)dout)[obase + rbase + col] = __float2bfloat16(o);
            }
            float o2 = o + (qp ? ldv(qp, rbase + col, 2, ef) : 0.f);
            out32[rbase + col] = o2;
            outbf[rbase + col] = __float2bfloat16(o2);
        }
    }
}

// ---------------------------------------------------------------------------
// Fused sampling-offset + attention-weight GEMM: W = concat(so_w, aw_w) rows
// (N=384). Tile 32 x 128; grid (3, ceil(M/32)).
// ---------------------------------------------------------------------------
__global__ __launch_bounds__(256) void gemm_soaw(const bf16* __restrict__ A,
        const bf16* __restrict__ Wb, const void* __restrict__ b1,
        const void* __restrict__ b2, float* __restrict__ C1,
        float* __restrict__ C2, int M, const float* __restrict__ flagp)
{
    const bool ef = flagp[0] > 0.5f;
    const int K = DM;
    __shared__ __align__(16) bf16 As[32 * SAK];
    __shared__ __align__(16) bf16 Ws[128 * SAK];
    const int tid = threadIdx.x;
    const int m0 = blockIdx.y * 32, n0 = blockIdx.x * 128;
    const int w = tid >> 6, lane = tid & 63, lm = lane & 15, lq = lane >> 4;
    const int wr = w >> 1, wc = w & 1;
    const int srow = tid >> 2, scol = (tid & 3) * 8;

    f32x4 acc[4];
    #pragma unroll
    for (int nt = 0; nt < 4; nt++) acc[nt] = (f32x4){0.f, 0.f, 0.f, 0.f};

    for (int k0 = 0; k0 < K; k0 += 32) {
        stage_a32(As, A, true, m0, M, K, k0, tid);
        #pragma unroll
        for (int it = 0; it < 2; it++) {
            int rr = it * 64 + srow;
            *(uint4*)&Ws[rr * SAK + scol] =
                *(const uint4*)(Wb + (size_t)(n0 + rr) * K + k0 + scol);
        }
        __syncthreads();

        bf16x8 af = *(const bf16x8*)&As[(wr * 16 + lm) * SAK + lq * 8];
        #pragma unroll
        for (int nt = 0; nt < 4; nt++) {
            bf16x8 bfr = *(const bf16x8*)&Ws[(wc * 64 + nt * 16 + lm) * SAK + lq * 8];
            acc[nt] = __builtin_amdgcn_mfma_f32_16x16x32_bf16(af, bfr, acc[nt], 0, 0, 0);
        }
        __syncthreads();
    }

    float* Cd; const void* bsrc; int nst, c0;
    if (n0 < 256) { Cd = C1; bsrc = b1; nst = 256; c0 = n0; }
    else          { Cd = C2; bsrc = b2; nst = 128; c0 = n0 - 256; }

    #pragma unroll
    for (int nt = 0; nt < 4; nt++) {
        int cl = wc * 64 + nt * 16 + lm;
        float bv = ldv(bsrc, c0 + cl, 2, ef);
        #pragma unroll
        for (int r = 0; r < 4; r++) {
            int m = m0 + wr * 16 + lq * 4 + r;
            if (m >= M) continue;
            Cd[(size_t)m * nst + c0 + cl] = acc[nt][r] + bv;
        }
    }
}

// ---------------------------------------------------------------------------
__global__ __launch_bounds__(256) void add_qpos(const void* __restrict__ a, int amode,
        const void* __restrict__ qp, float* __restrict__ o, bf16* __restrict__ ob,
        const float* __restrict__ flagp)
{
    const bool ef = flagp[0] > 0.5f;
    int i = blockIdx.x * 256 + threadIdx.x;
    float v = ldv(a, i, amode, ef) + ldv(qp, i, 2, ef);
    o[i]  = v;
    ob[i] = __float2bfloat16(v);
}

// ---------------------------------------------------------------------------
// MFMA flash MHA. grid (15 qtiles, 8 h, 8 b), 256 thr = 4 waves.
// ---------------------------------------------------------------------------
__global__ __launch_bounds__(256) void mha_mfma(const bf16* __restrict__ qkv,
        bf16* __restrict__ out)
{
    const int qt = blockIdx.x, h = blockIdx.y, b = blockIdx.z;
    const int q0 = qt * 64;
    const int tid = threadIdx.x;
    const int w = tid >> 6, lane = tid & 63;
    const int lm = lane & 15, lq = lane >> 4;
    const int srow = tid >> 2, sc = (tid & 3) * 8;

    __shared__ __align__(16) bf16 Qs[64][SAK];
    __shared__ __align__(16) bf16 Ks[64][SAK];
    __shared__ __align__(16) bf16 Vt[32][66];
    __shared__ __align__(16) bf16 Pt[64][66];

    const bf16* base = qkv + (size_t)b * NQ * 768;

    {
        bf16 tmp[8];
        if (q0 + srow < NQ) {
            uint4 u = *(const uint4*)(base + (size_t)(q0 + srow) * 768 + h * DHEAD + sc);
            float t[8]; unpack8(u, t);
            #pragma unroll
            for (int i = 0; i < 8; i++) tmp[i] = __float2bfloat16(t[i] * ATT_SCALE);
        } else {
            #pragma unroll
            for (int i = 0; i < 8; i++) tmp[i] = __float2bfloat16(0.f);
        }
        *(uint4*)&Qs[srow][sc] = *(const uint4*)tmp;
    }
    __syncthreads();
    const bf16x8 qf = *(const bf16x8*)&Qs[w * 16 + lm][lq * 8];

    f32x4 O[2] = {{0.f,0.f,0.f,0.f},{0.f,0.f,0.f,0.f}};
    float mrow = -1e30f, lrow = 0.f;

    for (int k0 = 0; k0 < NQ; k0 += 64) {
        __syncthreads();
        {
            uint4 uk = {0u,0u,0u,0u}, uv = {0u,0u,0u,0u};
            if (k0 + srow < NQ) {
                const bf16* rp = base + (size_t)(k0 + srow) * 768 + h * DHEAD + sc;
                uk = *(const uint4*)(rp + 256);
                uv = *(const uint4*)(rp + 512);
            }
            *(uint4*)&Ks[srow][sc] = uk;
            const bf16* vv = (const bf16*)&uv;
            #pragma unroll
            for (int i = 0; i < 8; i++) Vt[sc + i][srow] = vv[i];
        }
        __syncthreads();

        float sv[16];
        #pragma unroll
        for (int mt = 0; mt < 4; mt++) {
            bf16x8 kf = *(const bf16x8*)&Ks[mt * 16 + lm][lq * 8];
            f32x4 d = __builtin_amdgcn_mfma_f32_16x16x32_bf16(kf, qf,
                        (f32x4){0.f,0.f,0.f,0.f}, 0, 0, 0);
            sv[mt*4+0] = d[0]; sv[mt*4+1] = d[1]; sv[mt*4+2] = d[2]; sv[mt*4+3] = d[3];
        }
        #pragma unroll
        for (int mt = 0; mt < 4; mt++)
            #pragma unroll
            for (int r = 0; r < 4; r++)
                if (k0 + mt * 16 + lq * 4 + r >= NQ) sv[mt*4+r] = -1e30f;

        float tmax = sv[0];
        #pragma unroll
        for (int j = 1; j < 16; j++) tmax = fmaxf(tmax, sv[j]);
        tmax = fmaxf(tmax, __shfl_xor(tmax, 16, 64));
        tmax = fmaxf(tmax, __shfl_xor(tmax, 32, 64));
        float mnew = fmaxf(mrow, tmax);
        float alpha = __expf(mrow - mnew);
        mrow = mnew;
        float psum = 0.f;
        #pragma unroll
        for (int j = 0; j < 16; j++) {
            float p = __expf(sv[j] - mnew);
            sv[j] = p; psum += p;
        }
        psum += __shfl_xor(psum, 16, 64);
        psum += __shfl_xor(psum, 32, 64);
        lrow = lrow * alpha + psum;

        #pragma unroll
        for (int mt = 0; mt < 4; mt++)
            #pragma unroll
            for (int r = 0; r < 4; r++)
                Pt[mt * 16 + lq * 4 + r][w * 16 + lm] = __float2bfloat16(sv[mt*4+r]);

        #pragma unroll
        for (int mt = 0; mt < 2; mt++)
            #pragma unroll
            for (int r = 0; r < 4; r++) O[mt][r] *= alpha;
        #pragma unroll
        for (int ks = 0; ks < 2; ks++) {
            union { bf16 a[8]; bf16x8 v; } pf;
            #pragma unroll
            for (int j = 0; j < 8; j++)
                pf.a[j] = Pt[ks * 32 + lq * 8 + j][w * 16 + lm];
            #pragma unroll
            for (int mt = 0; mt < 2; mt++) {
                bf16x8 vf = *(const bf16x8*)&Vt[mt * 16 + lm][ks * 32 + lq * 8];
                O[mt] = __builtin_amdgcn_mfma_f32_16x16x32_bf16(vf, pf.v, O[mt], 0, 0, 0);
            }
        }
    }

    int q = q0 + w * 16 + lm;
    if (q < NQ) {
        float invl = 1.f / lrow;
        bf16* op = out + ((size_t)(b * NQ + q)) * DM + h * DHEAD;
        #pragma unroll
        for (int mt = 0; mt < 2; mt++)
            #pragma unroll
            for (int r = 0; r < 4; r++)
                op[mt * 16 + lq * 4 + r] = __float2bfloat16(O[mt][r] * invl);
    }
}

// ---------------------------------------------------------------------------
// MSDA sampling with inline attention-weight softmax (raw logits in).
// ---------------------------------------------------------------------------
__global__ __launch_bounds__(256) void msda_sample(const bf16* __restrict__ value,
        const float* __restrict__ off, const float* __restrict__ aw,
        const void* __restrict__ refp, const void* __restrict__ vr,
        bf16* __restrict__ out, const float* __restrict__ flagp)
{
    const bool ef = flagp[0] > 0.5f;
    int bq = blockIdx.x; int b = bq / NQ;
    int tid = threadIdx.x; int h = tid >> 5, d = tid & 31;
    __shared__ float sOff[256];
    __shared__ float sAw[128];
    __shared__ float sref[2];
    __shared__ float svr[8];
    sOff[tid] = off[(size_t)bq * 256 + tid];
    if (tid < 128) sAw[tid] = aw[(size_t)bq * 128 + tid];
    if (tid < 2)   sref[tid] = ldv(refp, bq * 2 + tid, 2, ef);
    if (tid < 8)   svr[tid]  = ldv(vr, b * 8 + tid, 2, ef);
    __syncthreads();
    if (tid < 8) {
        float* p = &sAw[tid * 16];
        float mx = -1e30f;
        #pragma unroll
        for (int j = 0; j < 16; j++) mx = fmaxf(mx, p[j]);
        float s = 0.f;
        #pragma unroll
        for (int j = 0; j < 16; j++) { float e = __expf(p[j] - mx); p[j] = e; s += e; }
        float inv = 1.f / s;
        #pragma unroll
        for (int j = 0; j < 16; j++) p[j] *= inv;
    }
    __syncthreads();
    const bf16* vb = value + (size_t)b * NS * DM + h * DHEAD + d;
    const int HS[4] = {100, 50, 25, 13};
    const int ST[4] = {0, 10000, 12500, 13125};
    float acc = 0.f;
    #pragma unroll
    for (int lvl = 0; lvl < 4; lvl++) {
        int W_ = HS[lvl], H_ = HS[lvl], st = ST[lvl];
        float rx = sref[0] * svr[lvl*2 + 0] * (float)W_;
        float ry = sref[1] * svr[lvl*2 + 1] * (float)H_;
        #pragma unroll
        for (int p = 0; p < 4; p++) {
            int oi = h * 32 + lvl * 8 + p * 2;
            float x = fminf(fmaxf(rx + sOff[oi]     - 0.5f, -4.f), (float)W_ + 4.f);
            float y = fminf(fmaxf(ry + sOff[oi + 1] - 0.5f, -4.f), (float)H_ + 4.f);
            float x0f = floorf(x), y0f = floorf(y);
            float wx = x - x0f, wy = y - y0f;
            int x0 = (int)x0f, y0 = (int)y0f;
            int x1i = x0 + 1, y1i = y0 + 1;
            bool vx0 = (x0 >= 0) && (x0 < W_), vx1 = (x1i >= 0) && (x1i < W_);
            bool vy0 = (y0 >= 0) && (y0 < H_), vy1 = (y1i >= 0) && (y1i < H_);
            float g = 0.f;
            if (vy0) {
                int rowo = (st + y0 * W_) * DM;
                if (vx0) g += (1.f - wx) * (1.f - wy) * __bfloat162float(vb[rowo + x0  * DM]);
                if (vx1) g += wx         * (1.f - wy) * __bfloat162float(vb[rowo + x1i * DM]);
            }
            if (vy1) {
                int rowo = (st + y1i * W_) * DM;
                if (vx0) g += (1.f - wx) * wy * __bfloat162float(vb[rowo + x0  * DM]);
                if (vx1) g += wx         * wy * __bfloat162float(vb[rowo + x1i * DM]);
            }
            acc += g * sAw[h * 16 + lvl * 4 + p];
        }
    }
    out[(size_t)bq * DM + tid] = __float2bfloat16(acc);
}

// ---------------------------------------------------------------------------
__global__ __launch_bounds__(256) void copy_refs(const void* __restrict__ refp,
        void* __restrict__ out, const float* __restrict__ flagp)
{
    const bool ef = flagp[0] > 0.5f;
    int i = blockIdx.x * 256 + threadIdx.x;
    if (i >= NLAY * BQ * 2) return;
    float v = ldv(refp, i % (BQ * 2), 2, ef);
    size_t oi = (size_t)NLAY * BQ * DM + i;
    if (ef) ((float*)out)[oi] = v;
    else    ((bf16*)out)[oi] = __float2bfloat16(v);
}

// ---------------------------------------------------------------------------
extern "C" void kernel_launch(void* const* d_in, const int* in_sizes, int n_in,
                              void* d_out, int out_size, void* d_ws, size_t ws_size,
                              hipStream_t stream)
{
    const void* tgt     = d_in[0];
    const void* refp    = d_in[1];
    const void* memory  = d_in[2];
    const void* vr      = d_in[5];
    const void* qp      = d_in[6];
    const void* sa_in_w = d_in[7];
    const void* sa_in_b = d_in[8];
    const void* sa_out_w= d_in[9];
    const void* sa_out_b= d_in[10];
    const void* n1_g    = d_in[11];
    const void* n1_b    = d_in[12];
    const void* n2_g    = d_in[13];
    const void* n2_b    = d_in[14];
    const void* n3_g    = d_in[15];
    const void* n3_b    = d_in[16];
    const void* vp_w    = d_in[17];
    const void* vp_b    = d_in[18];
    const void* so_w    = d_in[19];
    const void* so_b    = d_in[20];
    const void* aw_w    = d_in[21];
    const void* aw_b    = d_in[22];
    const void* op_w    = d_in[23];
    const void* op_b    = d_in[24];
    const void* ff1_w   = d_in[25];
    const void* ff1_b   = d_in[26];
    const void* ff2_w   = d_in[27];
    const void* ff2_b   = d_in[28];

    // ---- workspace layout ----
    char* w = (char*)d_ws;
    float* flagp  = (float*)w;  w += 256;
    bf16*  value  = (bf16*)w;   w += (size_t)NB * NS * DM * 2;   // 54.45 MB
    float* outbuf = (float*)w;  w += (size_t)BQ * DM * 4;
    float* x1samp = (float*)w;  w += (size_t)BQ * DM * 4;
    bf16*  bigb   = (bf16*)w;   w += (size_t)BQ * NFF * 2;       // qkv / ffn hidden
    float* attoff = (float*)w;  w += (size_t)BQ * DM * 4;        // sampling offsets
    float* awb    = (float*)w;  w += (size_t)BQ * 128 * 4;       // aw logits
    bf16*  abuf   = (bf16*)w;   w += (size_t)BQ * DM * 2;        // x1/mha/msda bf16
    bf16*  outbf  = (bf16*)w;   w += (size_t)BQ * DM * 2;        // ln bf16 dup
    // pre-converted bf16 weights
    bf16* wb_sa_in = (bf16*)w;  w += (size_t)768 * 256 * 2;
    bf16* wb_sa_out= (bf16*)w;  w += (size_t)256 * 256 * 2;
    bf16* wb_soaw  = (bf16*)w;  w += (size_t)384 * 256 * 2;      // so(256) ++ aw(128)
    bf16* wb_op    = (bf16*)w;  w += (size_t)256 * 256 * 2;
    bf16* wb_ff1   = (bf16*)w;  w += (size_t)NFF * 256 * 2;
    bf16* wb_ff2   = (bf16*)w;  w += (size_t)256 * NFF * 2;
    bf16* wb_vp    = (bf16*)w;  w += (size_t)256 * 256 * 2;

    const int gy = (BQ + 31) / 32;      // 225
    const int MV = NB * NS;             // 106352

    // 0) detect external dtype, pre-convert weights to bf16
    detect_dtype<<<1, 256, 0, stream>>>(tgt, flagp);
    convert_w<<< 96, 256, 0, stream>>>(sa_in_w,  wb_sa_in,  flagp);
    convert_w<<< 32, 256, 0, stream>>>(sa_out_w, wb_sa_out, flagp);
    convert_w<<< 32, 256, 0, stream>>>(so_w,     wb_soaw,   flagp);
    convert_w<<< 16, 256, 0, stream>>>(aw_w,     wb_soaw + 256 * 256, flagp);
    convert_w<<< 32, 256, 0, stream>>>(op_w,     wb_op,     flagp);
    convert_w<<<128, 256, 0, stream>>>(ff1_w,    wb_ff1,    flagp);
    convert_w<<<128, 256, 0, stream>>>(ff2_w,    wb_ff2,    flagp);
    convert_w<<< 32, 256, 0, stream>>>(vp_w,     wb_vp,     flagp);

    // 1) value projection (layer-invariant): A read once, full rows per block
    gemm_a<<<dim3(1, (MV + 31) / 32), 256, 0, stream>>>(
        memory, 2, wb_vp, vp_b, value, 1, MV, DM, DM, 0, flagp);

    // 2) inter_refs output
    copy_refs<<<(NLAY * BQ * 2 + 255) / 256, 256, 0, stream>>>(refp, d_out, flagp);

    // 3) x1 = tgt + query_pos (layer 0 only; later layers fused into ff2 LN)
    add_qpos<<<BQ * DM / 256, 256, 0, stream>>>(tgt, 2, qp, x1samp, abuf, flagp);

    for (int l = 0; l < NLAY; l++) {
        // self-attention
        gemm_a<<<dim3(768/256, gy), 256, 0, stream>>>(
            abuf, 1, wb_sa_in, sa_in_b, bigb, 1, BQ, 768, DM, 0, flagp);
        mha_mfma<<<dim3(15, NHEADS, NB), 256, 0, stream>>>(bigb, abuf);
        gemm_ln<<<dim3(1, gy), 256, 0, stream>>>(
            abuf, wb_sa_out, sa_out_b, x1samp, n1_g, n1_b,
            outbuf, outbf, nullptr, 0, nullptr, BQ, DM, flagp);

        // MSDA: fused so+aw GEMM, sampling w/ inline softmax, op GEMM + LN2
        gemm_soaw<<<dim3(3, gy), 256, 0, stream>>>(
            outbf, wb_soaw, so_b, aw_b, attoff, awb, BQ, flagp);
        msda_sample<<<BQ, 256, 0, stream>>>(value, attoff, awb, refp, vr, abuf, flagp);
        gemm_ln<<<dim3(1, gy), 256, 0, stream>>>(
            abuf, wb_op, op_b, outbuf, n2_g, n2_b,
            outbuf, outbf, nullptr, 0, nullptr, BQ, DM, flagp);

        // FFN: ff1 (relu, bf16 hidden), ff2 + LN3 + d_out slice + next x1(+qp)
        gemm_a<<<dim3(NFF/256, gy), 256, 0, stream>>>(
            outbf, 1, wb_ff1, ff1_b, bigb, 1, BQ, NFF, DM, 1, flagp);
        gemm_ln<<<dim3(1, gy), 256, 0, stream>>>(
            bigb, wb_ff2, ff2_b, outbuf, n3_g, n3_b,
            x1samp, abuf, d_out, (size_t)l * BQ * DM, qp, BQ, NFF, flagp);
    }
}

// Round 5
// 1722.072 us; speedup vs baseline: 1.6289x; 1.0081x over previous
//
#include <hip/hip_runtime.h>
#include <hip/hip_bf16.h>

typedef __hip_bfloat16 bf16;
typedef __bf16 bf16x8 __attribute__((ext_vector_type(8)));
typedef float  f32x4  __attribute__((ext_vector_type(4)));

#define NB 8
#define NQ 900
#define DM 256
#define NHEADS 8
#define DHEAD 32
#define NFF 1024
#define NLAY 6
#define NS 13294
#define BQ (NB*NQ)            // 7200
#define LN_EPS 1e-5f
#define ATT_SCALE 0.17677669529663687f   // 1/sqrt(32)
#define SAK 40                // LDS row stride (bf16): 80B — measured ~2-way (free)
#define VWS 264               // vp kernel: W/A LDS row stride (256+8): 2-way banks

__device__ __forceinline__ float bfd(const bf16* p, size_t i){ return __bfloat162float(p[i]); }

// mode: 0 = fp32 (internal), 1 = bf16 (internal), 2 = external (dtype per flag)
__device__ __forceinline__ float ldv(const void* p, size_t i, int mode, bool extF32)
{
    if (mode == 0) return ((const float*)p)[i];
    if (mode == 1) return bfd((const bf16*)p, i);
    return extF32 ? ((const float*)p)[i] : bfd((const bf16*)p, i);
}

// unpack 8 bf16 (16B) to floats
__device__ __forceinline__ void unpack8(uint4 u, float* t)
{
    t[0] = __uint_as_float((u.x & 0xffffu) << 16);
    t[1] = __uint_as_float(u.x & 0xffff0000u);
    t[2] = __uint_as_float((u.y & 0xffffu) << 16);
    t[3] = __uint_as_float(u.y & 0xffff0000u);
    t[4] = __uint_as_float((u.z & 0xffffu) << 16);
    t[5] = __uint_as_float(u.z & 0xffff0000u);
    t[6] = __uint_as_float((u.w & 0xffffu) << 16);
    t[7] = __uint_as_float(u.w & 0xffff0000u);
}

// ---------------------------------------------------------------------------
__global__ __launch_bounds__(256) void detect_dtype(const void* __restrict__ tgt,
        float* __restrict__ flag)
{
    __shared__ float red[256];
    int t = threadIdx.x;
    const unsigned short* u = (const unsigned short*)tgt;
    float m = 0.f;
    for (int i = t; i < 2048; i += 256) {
        unsigned int bits = ((unsigned int)u[i]) << 16;
        float v = fabsf(__uint_as_float(bits));
        if (!isfinite(v)) v = 1e30f;
        m = fmaxf(m, v);
    }
    red[t] = m;
    __syncthreads();
    for (int st = 128; st; st >>= 1) {
        if (t < st) red[t] = fmaxf(red[t], red[t + st]);
        __syncthreads();
    }
    if (t == 0) flag[0] = (red[0] > 1e8f) ? 1.f : 0.f;
}

// ---------------------------------------------------------------------------
__global__ __launch_bounds__(256) void convert_w(const void* __restrict__ src,
        bf16* __restrict__ dst, const float* __restrict__ flagp)
{
    const bool ef = flagp[0] > 0.5f;
    size_t base = ((size_t)blockIdx.x * 256 + threadIdx.x) * 8;
    if (ef) {
        const float* s = (const float*)src + base;
        float4 f0 = *(const float4*)s;
        float4 f1 = *(const float4*)(s + 4);
        union { bf16 a[8]; uint4 u; } t;
        t.a[0] = __float2bfloat16(f0.x); t.a[1] = __float2bfloat16(f0.y);
        t.a[2] = __float2bfloat16(f0.z); t.a[3] = __float2bfloat16(f0.w);
        t.a[4] = __float2bfloat16(f1.x); t.a[5] = __float2bfloat16(f1.y);
        t.a[6] = __float2bfloat16(f1.z); t.a[7] = __float2bfloat16(f1.w);
        *(uint4*)(dst + base) = t.u;
    } else {
        *(uint4*)(dst + base) = *(const uint4*)((const bf16*)src + base);
    }
}

// ---------------------------------------------------------------------------
// Persistent value-projection GEMM: K=N=256. Whole W lives in LDS (132 KB,
// stride VWS=264 -> 2-way banks). Grid = 256 blocks (1/CU, 4 waves); each
// block stages W ONCE, then loops ~13 M-tiles of 32 rows: stage A (16.5 KB),
// 2 barriers, 8 K-steps fully from LDS = 64 MFMAs/wave per barrier pair.
// Wave w owns all 32 rows x 64-col quarter (2 m-frags x 4 n-frags).
// ---------------------------------------------------------------------------
__global__ __launch_bounds__(256) void gemm_vp(const void* __restrict__ A,
        const bf16* __restrict__ Wb, const void* __restrict__ bias,
        bf16* __restrict__ C, int M, const float* __restrict__ flagp)
{
    const bool ef = flagp[0] > 0.5f;          // true -> A is fp32
    __shared__ __align__(16) bf16 Wl[256 * VWS];   // 135168 B
    __shared__ __align__(16) bf16 Al[32 * VWS];    //  16896 B
    const int tid = threadIdx.x;
    const int w = tid >> 6, lane = tid & 63, lm = lane & 15, lq = lane >> 4;
    const int wq = w * 64;                    // wave's column quarter

    // ---- stage W once: 8192 uint4s over 256 threads ----
    for (int u = tid; u < 8192; u += 256) {
        int row = u >> 5, col = (u & 31) * 8;
        *(uint4*)&Wl[row * VWS + col] = *(const uint4*)(Wb + (size_t)row * 256 + col);
    }

    // bias for this wave's columns
    float bv[4];
    #pragma unroll
    for (int nt = 0; nt < 4; nt++) bv[nt] = ldv(bias, wq + nt * 16 + lm, 2, ef);

    const int arow_l = tid >> 3;              // 0..31
    const int acol   = (tid & 7) * 32;        // 0,32,..,224

    const int ntiles = (M + 31) / 32;
    for (int tile = blockIdx.x; tile < ntiles; tile += gridDim.x) {
        const int m0 = tile * 32;
        __syncthreads();                      // prior tile done reading Al (also covers W visibility on t0)
        // ---- stage A tile [32][256]: 32 cols per thread ----
        {
            const int grow = m0 + arow_l;
            if (grow < M) {
                if (ef) {
                    const float* ap = (const float*)A + (size_t)grow * 256 + acol;
                    #pragma unroll
                    for (int j = 0; j < 4; j++) {
                        float4 f0 = *(const float4*)(ap + j * 8);
                        float4 f1 = *(const float4*)(ap + j * 8 + 4);
                        union { bf16 a[8]; uint4 u; } t;
                        t.a[0] = __float2bfloat16(f0.x); t.a[1] = __float2bfloat16(f0.y);
                        t.a[2] = __float2bfloat16(f0.z); t.a[3] = __float2bfloat16(f0.w);
                        t.a[4] = __float2bfloat16(f1.x); t.a[5] = __float2bfloat16(f1.y);
                        t.a[6] = __float2bfloat16(f1.z); t.a[7] = __float2bfloat16(f1.w);
                        *(uint4*)&Al[arow_l * VWS + acol + j * 8] = t.u;
                    }
                } else {
                    const bf16* ap = (const bf16*)A + (size_t)grow * 256 + acol;
                    #pragma unroll
                    for (int j = 0; j < 4; j++)
                        *(uint4*)&Al[arow_l * VWS + acol + j * 8] =
                            *(const uint4*)(ap + j * 8);
                }
            } else {
                uint4 z = make_uint4(0u, 0u, 0u, 0u);
                #pragma unroll
                for (int j = 0; j < 4; j++)
                    *(uint4*)&Al[arow_l * VWS + acol + j * 8] = z;
            }
        }
        __syncthreads();                      // A tile ready

        // ---- compute: 8 K-steps x (2 m-frags x 4 n-frags) = 64 MFMAs ----
        f32x4 acc[2][4];
        #pragma unroll
        for (int mi = 0; mi < 2; mi++)
            #pragma unroll
            for (int nt = 0; nt < 4; nt++)
                acc[mi][nt] = (f32x4){0.f, 0.f, 0.f, 0.f};

        #pragma unroll
        for (int ks = 0; ks < 8; ks++) {
            bf16x8 af[2];
            #pragma unroll
            for (int mi = 0; mi < 2; mi++)
                af[mi] = *(const bf16x8*)&Al[(mi * 16 + lm) * VWS + ks * 32 + lq * 8];
            #pragma unroll
            for (int nt = 0; nt < 4; nt++) {
                bf16x8 bfr = *(const bf16x8*)&Wl[(wq + nt * 16 + lm) * VWS + ks * 32 + lq * 8];
                #pragma unroll
                for (int mi = 0; mi < 2; mi++)
                    acc[mi][nt] = __builtin_amdgcn_mfma_f32_16x16x32_bf16(
                                      af[mi], bfr, acc[mi][nt], 0, 0, 0);
            }
        }

        // ---- write C tile (bf16) ----
        #pragma unroll
        for (int mi = 0; mi < 2; mi++) {
            #pragma unroll
            for (int r = 0; r < 4; r++) {
                int m = m0 + mi * 16 + lq * 4 + r;
                if (m >= M) continue;
                #pragma unroll
                for (int nt = 0; nt < 4; nt++) {
                    int col = wq + nt * 16 + lm;
                    C[(size_t)m * 256 + col] = __float2bfloat16(acc[mi][nt][r] + bv[nt]);
                }
            }
        }
    }
}

// ---------------------------------------------------------------------------
// stage A tile [32][32] : thread t -> row t>>3, col (t&7)*4  (uint2 / float4)
// ---------------------------------------------------------------------------
__device__ __forceinline__ void stage_a32(bf16* As, const void* A, bool a_bf16,
        int m0, int M, int K, int k0, int tid)
{
    const int row = tid >> 3, col = (tid & 7) * 4;
    const int arow = m0 + row;
    union { bf16 a[4]; uint2 u; } t;
    if (arow < M) {
        size_t base = (size_t)arow * K + k0 + col;
        if (a_bf16) {
            t.u = *(const uint2*)((const bf16*)A + base);
        } else {
            float4 f = *(const float4*)((const float*)A + base);
            t.a[0] = __float2bfloat16(f.x); t.a[1] = __float2bfloat16(f.y);
            t.a[2] = __float2bfloat16(f.z); t.a[3] = __float2bfloat16(f.w);
        }
    } else {
        t.u = make_uint2(0u, 0u);
    }
    *(uint2*)&As[row * SAK + col] = t.u;
}

// ---------------------------------------------------------------------------
// Plain GEMM, tile 32 x 256. 4 waves 2x2; wave = 16r x 128c, 8 MFMAs/K-step.
// grid: (N/256, ceil(M/32)).
// ---------------------------------------------------------------------------
__global__ __launch_bounds__(256) void gemm_a(const void* __restrict__ A, int amode,
        const bf16* __restrict__ Wb, const void* __restrict__ bias,
        void* __restrict__ C, int cmode, int M, int N, int K, int relu,
        const float* __restrict__ flagp)
{
    const bool ef = flagp[0] > 0.5f;
    const bool a_bf16 = (amode == 1) || (amode == 2 && !ef);
    __shared__ __align__(16) bf16 As[32 * SAK];
    __shared__ __align__(16) bf16 Ws[256 * SAK];
    const int tid = threadIdx.x;
    const int m0 = blockIdx.y * 32, n0 = blockIdx.x * 256;
    const int w = tid >> 6, lane = tid & 63, lm = lane & 15, lq = lane >> 4;
    const int wr = w >> 1, wc = w & 1;
    const int srow = tid >> 2, scol = (tid & 3) * 8;

    f32x4 acc[8];
    #pragma unroll
    for (int nt = 0; nt < 8; nt++) acc[nt] = (f32x4){0.f, 0.f, 0.f, 0.f};

    for (int k0 = 0; k0 < K; k0 += 32) {
        stage_a32(As, A, a_bf16, m0, M, K, k0, tid);
        #pragma unroll
        for (int it = 0; it < 4; it++) {
            int rr = it * 64 + srow;
            *(uint4*)&Ws[rr * SAK + scol] =
                *(const uint4*)(Wb + (size_t)(n0 + rr) * K + k0 + scol);
        }
        __syncthreads();

        bf16x8 af = *(const bf16x8*)&As[(wr * 16 + lm) * SAK + lq * 8];
        #pragma unroll
        for (int nt = 0; nt < 8; nt++) {
            bf16x8 bfr = *(const bf16x8*)&Ws[(wc * 128 + nt * 16 + lm) * SAK + lq * 8];
            acc[nt] = __builtin_amdgcn_mfma_f32_16x16x32_bf16(af, bfr, acc[nt], 0, 0, 0);
        }
        __syncthreads();
    }

    #pragma unroll
    for (int nt = 0; nt < 8; nt++) {
        int n = n0 + wc * 128 + nt * 16 + lm;
        float bv = ldv(bias, n, 2, ef);
        #pragma unroll
        for (int r = 0; r < 4; r++) {
            int m = m0 + wr * 16 + lq * 4 + r;
            if (m >= M) continue;
            float v = acc[nt][r] + bv;
            if (relu) v = fmaxf(v, 0.f);
            size_t ci = (size_t)m * N + n;
            if (cmode == 0) ((float*)C)[ci] = v;
            else            ((bf16*)C)[ci] = __float2bfloat16(v);
        }
    }
}

// ---------------------------------------------------------------------------
// Fused GEMM (N=256) + bias + residual + LayerNorm. Tile 32 x 256.
// grid: (1, ceil(M/32)).
// ---------------------------------------------------------------------------
__global__ __launch_bounds__(256) void gemm_ln(const bf16* __restrict__ A,
        const bf16* __restrict__ Wb, const void* __restrict__ bias,
        const float* __restrict__ res, const void* __restrict__ gw,
        const void* __restrict__ bw, float* __restrict__ out32,
        bf16* __restrict__ outbf, void* __restrict__ dout, size_t obase,
        const void* __restrict__ qp, int M, int K,
        const float* __restrict__ flagp)
{
    const bool ef = flagp[0] > 0.5f;
    __shared__ __align__(16) bf16 As[32 * SAK];
    __shared__ __align__(16) bf16 Ws[256 * SAK];
    const int tid = threadIdx.x;
    const int m0 = blockIdx.y * 32;
    const int w = tid >> 6, lane = tid & 63, lm = lane & 15, lq = lane >> 4;
    const int wr = w >> 1, wc = w & 1;
    const int srow = tid >> 2, scol = (tid & 3) * 8;

    f32x4 acc[8];
    #pragma unroll
    for (int nt = 0; nt < 8; nt++) acc[nt] = (f32x4){0.f, 0.f, 0.f, 0.f};

    for (int k0 = 0; k0 < K; k0 += 32) {
        stage_a32(As, A, true, m0, M, K, k0, tid);
        #pragma unroll
        for (int it = 0; it < 4; it++) {
            int rr = it * 64 + srow;
            *(uint4*)&Ws[rr * SAK + scol] =
                *(const uint4*)(Wb + (size_t)rr * K + k0 + scol);
        }
        __syncthreads();

        bf16x8 af = *(const bf16x8*)&As[(wr * 16 + lm) * SAK + lq * 8];
        #pragma unroll
        for (int nt = 0; nt < 8; nt++) {
            bf16x8 bfr = *(const bf16x8*)&Ws[(wc * 128 + nt * 16 + lm) * SAK + lq * 8];
            acc[nt] = __builtin_amdgcn_mfma_f32_16x16x32_bf16(af, bfr, acc[nt], 0, 0, 0);
        }
        __syncthreads();
    }

    // ---- epilogue: v = acc + bias + res ----
    float bias_c[8], gcol[8], bcol[8];
    #pragma unroll
    for (int nt = 0; nt < 8; nt++) {
        int col = wc * 128 + nt * 16 + lm;
        bias_c[nt] = ldv(bias, col, 2, ef);
        gcol[nt]   = ldv(gw,   col, 2, ef);
        bcol[nt]   = ldv(bw,   col, 2, ef);
    }
    #pragma unroll
    for (int r = 0; r < 4; r++) {
        int row = m0 + wr * 16 + lq * 4 + r;
        bool vr_ = row < M;
        #pragma unroll
        for (int nt = 0; nt < 8; nt++) {
            int col = wc * 128 + nt * 16 + lm;
            float rv = vr_ ? res[(size_t)row * DM + col] : 0.f;
            acc[nt][r] += bias_c[nt] + rv;
        }
    }

    // ---- LN reductions ----
    float* red = (float*)As;
    float mu[4], rstd[4];
    #pragma unroll
    for (int r = 0; r < 4; r++) {
        float s = 0.f;
        #pragma unroll
        for (int nt = 0; nt < 8; nt++) s += acc[nt][r];
        s += __shfl_xor(s, 1, 64); s += __shfl_xor(s, 2, 64);
        s += __shfl_xor(s, 4, 64); s += __shfl_xor(s, 8, 64);
        if (lm == 0) red[(wr * 16 + lq * 4 + r) * 2 + wc] = s;
    }
    __syncthreads();
    #pragma unroll
    for (int r = 0; r < 4; r++) {
        int rl = wr * 16 + lq * 4 + r;
        mu[r] = (red[rl * 2] + red[rl * 2 + 1]) * (1.f / DM);
    }
    #pragma unroll
    for (int r = 0; r < 4; r++) {
        float q = 0.f;
        #pragma unroll
        for (int nt = 0; nt < 8; nt++) {
            float d = acc[nt][r] - mu[r];
            q += d * d;
        }
        q += __shfl_xor(q, 1, 64); q += __shfl_xor(q, 2, 64);
        q += __shfl_xor(q, 4, 64); q += __shfl_xor(q, 8, 64);
        if (lm == 0) red[64 + (wr * 16 + lq * 4 + r) * 2 + wc] = q;
    }
    __syncthreads();
    #pragma unroll
    for (int r = 0; r < 4; r++) {
        int rl = wr * 16 + lq * 4 + r;
        float var = (red[64 + rl * 2] + red[64 + rl * 2 + 1]) * (1.f / DM);
        rstd[r] = rsqrtf(var + LN_EPS);
    }

    // ---- normalize & store ----
    #pragma unroll
    for (int r = 0; r < 4; r++) {
        int row = m0 + wr * 16 + lq * 4 + r;
        if (row >= M) continue;
        size_t rbase = (size_t)row * DM;
        #pragma unroll
        for (int nt = 0; nt < 8; nt++) {
            int col = wc * 128 + nt * 16 + lm;
            float o = (acc[nt][r] - mu[r]) * rstd[r] * gcol[nt] + bcol[nt];
            if (dout) {
                if (ef) ((float*)dout)[obase + rbase + col] = o;
                else    ((bf16*)dout)[obase + rbase + col] = __float2bfloat16(o);
            }
            float o2 = o + (qp ? ldv(qp, rbase + col, 2, ef) : 0.f);
            out32[rbase + col] = o2;
            outbf[rbase + col] = __float2bfloat16(o2);
        }
    }
}

// ---------------------------------------------------------------------------
// Fused sampling-offset + attention-weight GEMM: W = concat(so_w, aw_w) rows
// (N=384). Tile 32 x 128; grid (3, ceil(M/32)).
// ---------------------------------------------------------------------------
__global__ __launch_bounds__(256) void gemm_soaw(const bf16* __restrict__ A,
        const bf16* __restrict__ Wb, const void* __restrict__ b1,
        const void* __restrict__ b2, float* __restrict__ C1,
        float* __restrict__ C2, int M, const float* __restrict__ flagp)
{
    const bool ef = flagp[0] > 0.5f;
    const int K = DM;
    __shared__ __align__(16) bf16 As[32 * SAK];
    __shared__ __align__(16) bf16 Ws[128 * SAK];
    const int tid = threadIdx.x;
    const int m0 = blockIdx.y * 32, n0 = blockIdx.x * 128;
    const int w = tid >> 6, lane = tid & 63, lm = lane & 15, lq = lane >> 4;
    const int wr = w >> 1, wc = w & 1;
    const int srow = tid >> 2, scol = (tid & 3) * 8;

    f32x4 acc[4];
    #pragma unroll
    for (int nt = 0; nt < 4; nt++) acc[nt] = (f32x4){0.f, 0.f, 0.f, 0.f};

    for (int k0 = 0; k0 < K; k0 += 32) {
        stage_a32(As, A, true, m0, M, K, k0, tid);
        #pragma unroll
        for (int it = 0; it < 2; it++) {
            int rr = it * 64 + srow;
            *(uint4*)&Ws[rr * SAK + scol] =
                *(const uint4*)(Wb + (size_t)(n0 + rr) * K + k0 + scol);
        }
        __syncthreads();

        bf16x8 af = *(const bf16x8*)&As[(wr * 16 + lm) * SAK + lq * 8];
        #pragma unroll
        for (int nt = 0; nt < 4; nt++) {
            bf16x8 bfr = *(const bf16x8*)&Ws[(wc * 64 + nt * 16 + lm) * SAK + lq * 8];
            acc[nt] = __builtin_amdgcn_mfma_f32_16x16x32_bf16(af, bfr, acc[nt], 0, 0, 0);
        }
        __syncthreads();
    }

    float* Cd; const void* bsrc; int nst, c0;
    if (n0 < 256) { Cd = C1; bsrc = b1; nst = 256; c0 = n0; }
    else          { Cd = C2; bsrc = b2; nst = 128; c0 = n0 - 256; }

    #pragma unroll
    for (int nt = 0; nt < 4; nt++) {
        int cl = wc * 64 + nt * 16 + lm;
        float bv = ldv(bsrc, c0 + cl, 2, ef);
        #pragma unroll
        for (int r = 0; r < 4; r++) {
            int m = m0 + wr * 16 + lq * 4 + r;
            if (m >= M) continue;
            Cd[(size_t)m * nst + c0 + cl] = acc[nt][r] + bv;
        }
    }
}

// ---------------------------------------------------------------------------
__global__ __launch_bounds__(256) void add_qpos(const void* __restrict__ a, int amode,
        const void* __restrict__ qp, float* __restrict__ o, bf16* __restrict__ ob,
        const float* __restrict__ flagp)
{
    const bool ef = flagp[0] > 0.5f;
    int i = blockIdx.x * 256 + threadIdx.x;
    float v = ldv(a, i, amode, ef) + ldv(qp, i, 2, ef);
    o[i]  = v;
    ob[i] = __float2bfloat16(v);
}

// ---------------------------------------------------------------------------
// MFMA flash MHA. grid (15 qtiles, 8 h, 8 b), 256 thr = 4 waves.
// ---------------------------------------------------------------------------
__global__ __launch_bounds__(256) void mha_mfma(const bf16* __restrict__ qkv,
        bf16* __restrict__ out)
{
    const int qt = blockIdx.x, h = blockIdx.y, b = blockIdx.z;
    const int q0 = qt * 64;
    const int tid = threadIdx.x;
    const int w = tid >> 6, lane = tid & 63;
    const int lm = lane & 15, lq = lane >> 4;
    const int srow = tid >> 2, sc = (tid & 3) * 8;

    __shared__ __align__(16) bf16 Qs[64][SAK];
    __shared__ __align__(16) bf16 Ks[64][SAK];
    __shared__ __align__(16) bf16 Vt[32][66];
    __shared__ __align__(16) bf16 Pt[64][66];

    const bf16* base = qkv + (size_t)b * NQ * 768;

    {
        bf16 tmp[8];
        if (q0 + srow < NQ) {
            uint4 u = *(const uint4*)(base + (size_t)(q0 + srow) * 768 + h * DHEAD + sc);
            float t[8]; unpack8(u, t);
            #pragma unroll
            for (int i = 0; i < 8; i++) tmp[i] = __float2bfloat16(t[i] * ATT_SCALE);
        } else {
            #pragma unroll
            for (int i = 0; i < 8; i++) tmp[i] = __float2bfloat16(0.f);
        }
        *(uint4*)&Qs[srow][sc] = *(const uint4*)tmp;
    }
    __syncthreads();
    const bf16x8 qf = *(const bf16x8*)&Qs[w * 16 + lm][lq * 8];

    f32x4 O[2] = {{0.f,0.f,0.f,0.f},{0.f,0.f,0.f,0.f}};
    float mrow = -1e30f, lrow = 0.f;

    for (int k0 = 0; k0 < NQ; k0 += 64) {
        __syncthreads();
        {
            uint4 uk = {0u,0u,0u,0u}, uv = {0u,0u,0u,0u};
            if (k0 + srow < NQ) {
                const bf16* rp = base + (size_t)(k0 + srow) * 768 + h * DHEAD + sc;
                uk = *(const uint4*)(rp + 256);
                uv = *(const uint4*)(rp + 512);
            }
            *(uint4*)&Ks[srow][sc] = uk;
            const bf16* vv = (const bf16*)&uv;
            #pragma unroll
            for (int i = 0; i < 8; i++) Vt[sc + i][srow] = vv[i];
        }
        __syncthreads();

        float sv[16];
        #pragma unroll
        for (int mt = 0; mt < 4; mt++) {
            bf16x8 kf = *(const bf16x8*)&Ks[mt * 16 + lm][lq * 8];
            f32x4 d = __builtin_amdgcn_mfma_f32_16x16x32_bf16(kf, qf,
                        (f32x4){0.f,0.f,0.f,0.f}, 0, 0, 0);
            sv[mt*4+0] = d[0]; sv[mt*4+1] = d[1]; sv[mt*4+2] = d[2]; sv[mt*4+3] = d[3];
        }
        #pragma unroll
        for (int mt = 0; mt < 4; mt++)
            #pragma unroll
            for (int r = 0; r < 4; r++)
                if (k0 + mt * 16 + lq * 4 + r >= NQ) sv[mt*4+r] = -1e30f;

        float tmax = sv[0];
        #pragma unroll
        for (int j = 1; j < 16; j++) tmax = fmaxf(tmax, sv[j]);
        tmax = fmaxf(tmax, __shfl_xor(tmax, 16, 64));
        tmax = fmaxf(tmax, __shfl_xor(tmax, 32, 64));
        float mnew = fmaxf(mrow, tmax);
        float alpha = __expf(mrow - mnew);
        mrow = mnew;
        float psum = 0.f;
        #pragma unroll
        for (int j = 0; j < 16; j++) {
            float p = __expf(sv[j] - mnew);
            sv[j] = p; psum += p;
        }
        psum += __shfl_xor(psum, 16, 64);
        psum += __shfl_xor(psum, 32, 64);
        lrow = lrow * alpha + psum;

        #pragma unroll
        for (int mt = 0; mt < 4; mt++)
            #pragma unroll
            for (int r = 0; r < 4; r++)
                Pt[mt * 16 + lq * 4 + r][w * 16 + lm] = __float2bfloat16(sv[mt*4+r]);

        #pragma unroll
        for (int mt = 0; mt < 2; mt++)
            #pragma unroll
            for (int r = 0; r < 4; r++) O[mt][r] *= alpha;
        #pragma unroll
        for (int ks = 0; ks < 2; ks++) {
            union { bf16 a[8]; bf16x8 v; } pf;
            #pragma unroll
            for (int j = 0; j < 8; j++)
                pf.a[j] = Pt[ks * 32 + lq * 8 + j][w * 16 + lm];
            #pragma unroll
            for (int mt = 0; mt < 2; mt++) {
                bf16x8 vf = *(const bf16x8*)&Vt[mt * 16 + lm][ks * 32 + lq * 8];
                O[mt] = __builtin_amdgcn_mfma_f32_16x16x32_bf16(vf, pf.v, O[mt], 0, 0, 0);
            }
        }
    }

    int q = q0 + w * 16 + lm;
    if (q < NQ) {
        float invl = 1.f / lrow;
        bf16* op = out + ((size_t)(b * NQ + q)) * DM + h * DHEAD;
        #pragma unroll
        for (int mt = 0; mt < 2; mt++)
            #pragma unroll
            for (int r = 0; r < 4; r++)
                op[mt * 16 + lq * 4 + r] = __float2bfloat16(O[mt][r] * invl);
    }
}

// ---------------------------------------------------------------------------
// MSDA sampling with inline attention-weight softmax (raw logits in).
// ---------------------------------------------------------------------------
__global__ __launch_bounds__(256) void msda_sample(const bf16* __restrict__ value,
        const float* __restrict__ off, const float* __restrict__ aw,
        const void* __restrict__ refp, const void* __restrict__ vr,
        bf16* __restrict__ out, const float* __restrict__ flagp)
{
    const bool ef = flagp[0] > 0.5f;
    int bq = blockIdx.x; int b = bq / NQ;
    int tid = threadIdx.x; int h = tid >> 5, d = tid & 31;
    __shared__ float sOff[256];
    __shared__ float sAw[128];
    __shared__ float sref[2];
    __shared__ float svr[8];
    sOff[tid] = off[(size_t)bq * 256 + tid];
    if (tid < 128) sAw[tid] = aw[(size_t)bq * 128 + tid];
    if (tid < 2)   sref[tid] = ldv(refp, bq * 2 + tid, 2, ef);
    if (tid < 8)   svr[tid]  = ldv(vr, b * 8 + tid, 2, ef);
    __syncthreads();
    if (tid < 8) {
        float* p = &sAw[tid * 16];
        float mx = -1e30f;
        #pragma unroll
        for (int j = 0; j < 16; j++) mx = fmaxf(mx, p[j]);
        float s = 0.f;
        #pragma unroll
        for (int j = 0; j < 16; j++) { float e = __expf(p[j] - mx); p[j] = e; s += e; }
        float inv = 1.f / s;
        #pragma unroll
        for (int j = 0; j < 16; j++) p[j] *= inv;
    }
    __syncthreads();
    const bf16* vb = value + (size_t)b * NS * DM + h * DHEAD + d;
    const int HS[4] = {100, 50, 25, 13};
    const int ST[4] = {0, 10000, 12500, 13125};
    float acc = 0.f;
    #pragma unroll
    for (int lvl = 0; lvl < 4; lvl++) {
        int W_ = HS[lvl], H_ = HS[lvl], st = ST[lvl];
        float rx = sref[0] * svr[lvl*2 + 0] * (float)W_;
        float ry = sref[1] * svr[lvl*2 + 1] * (float)H_;
        #pragma unroll
        for (int p = 0; p < 4; p++) {
            int oi = h * 32 + lvl * 8 + p * 2;
            float x = fminf(fmaxf(rx + sOff[oi]     - 0.5f, -4.f), (float)W_ + 4.f);
            float y = fminf(fmaxf(ry + sOff[oi + 1] - 0.5f, -4.f), (float)H_ + 4.f);
            float x0f = floorf(x), y0f = floorf(y);
            float wx = x - x0f, wy = y - y0f;
            int x0 = (int)x0f, y0 = (int)y0f;
            int x1i = x0 + 1, y1i = y0 + 1;
            bool vx0 = (x0 >= 0) && (x0 < W_), vx1 = (x1i >= 0) && (x1i < W_);
            bool vy0 = (y0 >= 0) && (y0 < H_), vy1 = (y1i >= 0) && (y1i < H_);
            float g = 0.f;
            if (vy0) {
                int rowo = (st + y0 * W_) * DM;
                if (vx0) g += (1.f - wx) * (1.f - wy) * __bfloat162float(vb[rowo + x0  * DM]);
                if (vx1) g += wx         * (1.f - wy) * __bfloat162float(vb[rowo + x1i * DM]);
            }
            if (vy1) {
                int rowo = (st + y1i * W_) * DM;
                if (vx0) g += (1.f - wx) * wy * __bfloat162float(vb[rowo + x0  * DM]);
                if (vx1) g += wx         * wy * __bfloat162float(vb[rowo + x1i * DM]);
            }
            acc += g * sAw[h * 16 + lvl * 4 + p];
        }
    }
    out[(size_t)bq * DM + tid] = __float2bfloat16(acc);
}

// ---------------------------------------------------------------------------
__global__ __launch_bounds__(256) void copy_refs(const void* __restrict__ refp,
        void* __restrict__ out, const float* __restrict__ flagp)
{
    const bool ef = flagp[0] > 0.5f;
    int i = blockIdx.x * 256 + threadIdx.x;
    if (i >= NLAY * BQ * 2) return;
    float v = ldv(refp, i % (BQ * 2), 2, ef);
    size_t oi = (size_t)NLAY * BQ * DM + i;
    if (ef) ((float*)out)[oi] = v;
    else    ((bf16*)out)[oi] = __float2bfloat16(v);
}

// ---------------------------------------------------------------------------
extern "C" void kernel_launch(void* const* d_in, const int* in_sizes, int n_in,
                              void* d_out, int out_size, void* d_ws, size_t ws_size,
                              hipStream_t stream)
{
    const void* tgt     = d_in[0];
    const void* refp    = d_in[1];
    const void* memory  = d_in[2];
    const void* vr      = d_in[5];
    const void* qp      = d_in[6];
    const void* sa_in_w = d_in[7];
    const void* sa_in_b = d_in[8];
    const void* sa_out_w= d_in[9];
    const void* sa_out_b= d_in[10];
    const void* n1_g    = d_in[11];
    const void* n1_b    = d_in[12];
    const void* n2_g    = d_in[13];
    const void* n2_b    = d_in[14];
    const void* n3_g    = d_in[15];
    const void* n3_b    = d_in[16];
    const void* vp_w    = d_in[17];
    const void* vp_b    = d_in[18];
    const void* so_w    = d_in[19];
    const void* so_b    = d_in[20];
    const void* aw_w    = d_in[21];
    const void* aw_b    = d_in[22];
    const void* op_w    = d_in[23];
    const void* op_b    = d_in[24];
    const void* ff1_w   = d_in[25];
    const void* ff1_b   = d_in[26];
    const void* ff2_w   = d_in[27];
    const void* ff2_b   = d_in[28];

    // ---- workspace layout ----
    char* w = (char*)d_ws;
    float* flagp  = (float*)w;  w += 256;
    bf16*  value  = (bf16*)w;   w += (size_t)NB * NS * DM * 2;   // 54.45 MB
    float* outbuf = (float*)w;  w += (size_t)BQ * DM * 4;
    float* x1samp = (float*)w;  w += (size_t)BQ * DM * 4;
    bf16*  bigb   = (bf16*)w;   w += (size_t)BQ * NFF * 2;       // qkv / ffn hidden
    float* attoff = (float*)w;  w += (size_t)BQ * DM * 4;        // sampling offsets
    float* awb    = (float*)w;  w += (size_t)BQ * 128 * 4;       // aw logits
    bf16*  abuf   = (bf16*)w;   w += (size_t)BQ * DM * 2;        // x1/mha/msda bf16
    bf16*  outbf  = (bf16*)w;   w += (size_t)BQ * DM * 2;        // ln bf16 dup
    // pre-converted bf16 weights
    bf16* wb_sa_in = (bf16*)w;  w += (size_t)768 * 256 * 2;
    bf16* wb_sa_out= (bf16*)w;  w += (size_t)256 * 256 * 2;
    bf16* wb_soaw  = (bf16*)w;  w += (size_t)384 * 256 * 2;      // so(256) ++ aw(128)
    bf16* wb_op    = (bf16*)w;  w += (size_t)256 * 256 * 2;
    bf16* wb_ff1   = (bf16*)w;  w += (size_t)NFF * 256 * 2;
    bf16* wb_ff2   = (bf16*)w;  w += (size_t)256 * NFF * 2;
    bf16* wb_vp    = (bf16*)w;  w += (size_t)256 * 256 * 2;

    const int gy = (BQ + 31) / 32;      // 225
    const int MV = NB * NS;             // 106352

    // 0) detect external dtype, pre-convert weights to bf16
    detect_dtype<<<1, 256, 0, stream>>>(tgt, flagp);
    convert_w<<< 96, 256, 0, stream>>>(sa_in_w,  wb_sa_in,  flagp);
    convert_w<<< 32, 256, 0, stream>>>(sa_out_w, wb_sa_out, flagp);
    convert_w<<< 32, 256, 0, stream>>>(so_w,     wb_soaw,   flagp);
    convert_w<<< 16, 256, 0, stream>>>(aw_w,     wb_soaw + 256 * 256, flagp);
    convert_w<<< 32, 256, 0, stream>>>(op_w,     wb_op,     flagp);
    convert_w<<<128, 256, 0, stream>>>(ff1_w,    wb_ff1,    flagp);
    convert_w<<<128, 256, 0, stream>>>(ff2_w,    wb_ff2,    flagp);
    convert_w<<< 32, 256, 0, stream>>>(vp_w,     wb_vp,     flagp);

    // 1) value projection: persistent LDS-resident-W GEMM (1 block/CU)
    gemm_vp<<<256, 256, 0, stream>>>(memory, wb_vp, vp_b, value, MV, flagp);

    // 2) inter_refs output
    copy_refs<<<(NLAY * BQ * 2 + 255) / 256, 256, 0, stream>>>(refp, d_out, flagp);

    // 3) x1 = tgt + query_pos (layer 0 only; later layers fused into ff2 LN)
    add_qpos<<<BQ * DM / 256, 256, 0, stream>>>(tgt, 2, qp, x1samp, abuf, flagp);

    for (int l = 0; l < NLAY; l++) {
        // self-attention
        gemm_a<<<dim3(768/256, gy), 256, 0, stream>>>(
            abuf, 1, wb_sa_in, sa_in_b, bigb, 1, BQ, 768, DM, 0, flagp);
        mha_mfma<<<dim3(15, NHEADS, NB), 256, 0, stream>>>(bigb, abuf);
        gemm_ln<<<dim3(1, gy), 256, 0, stream>>>(
            abuf, wb_sa_out, sa_out_b, x1samp, n1_g, n1_b,
            outbuf, outbf, nullptr, 0, nullptr, BQ, DM, flagp);

        // MSDA: fused so+aw GEMM, sampling w/ inline softmax, op GEMM + LN2
        gemm_soaw<<<dim3(3, gy), 256, 0, stream>>>(
            outbf, wb_soaw, so_b, aw_b, attoff, awb, BQ, flagp);
        msda_sample<<<BQ, 256, 0, stream>>>(value, attoff, awb, refp, vr, abuf, flagp);
        gemm_ln<<<dim3(1, gy), 256, 0, stream>>>(
            abuf, wb_op, op_b, outbuf, n2_g, n2_b,
            outbuf, outbf, nullptr, 0, nullptr, BQ, DM, flagp);

        // FFN: ff1 (relu, bf16 hidden), ff2 + LN3 + d_out slice + next x1(+qp)
        gemm_a<<<dim3(NFF/256, gy), 256, 0, stream>>>(
            outbf, 1, wb_ff1, ff1_b, bigb, 1, BQ, NFF, DM, 1, flagp);
        gemm_ln<<<dim3(1, gy), 256, 0, stream>>>(
            bigb, wb_ff2, ff2_b, outbuf, n3_g, n3_b,
            x1samp, abuf, d_out, (size_t)l * BQ * DM, qp, BQ, NFF, flagp);
    }
}

// Round 6
// 1527.147 us; speedup vs baseline: 1.8368x; 1.1276x over previous
//
#include <hip/hip_runtime.h>
#include <hip/hip_bf16.h>

typedef __hip_bfloat16 bf16;
typedef __bf16 bf16x8 __attribute__((ext_vector_type(8)));
typedef float  f32x4  __attribute__((ext_vector_type(4)));

#define NB 8
#define NQ 900
#define DM 256
#define NHEADS 8
#define DHEAD 32
#define NFF 1024
#define NLAY 6
#define NS 13294
#define BQ (NB*NQ)            // 7200
#define LN_EPS 1e-5f
#define ATT_SCALE 0.17677669529663687f   // 1/sqrt(32)
#define SAK 40                // LDS row stride (bf16): 80B — measured ~2-way (free)
#define VWS 264               // vp kernel: W/A LDS row stride (256+8): 2-way banks

__device__ __forceinline__ float bfd(const bf16* p, size_t i){ return __bfloat162float(p[i]); }

// mode: 0 = fp32 (internal), 1 = bf16 (internal), 2 = external (dtype per flag)
__device__ __forceinline__ float ldv(const void* p, size_t i, int mode, bool extF32)
{
    if (mode == 0) return ((const float*)p)[i];
    if (mode == 1) return bfd((const bf16*)p, i);
    return extF32 ? ((const float*)p)[i] : bfd((const bf16*)p, i);
}

// unpack 8 bf16 (16B) to floats
__device__ __forceinline__ void unpack8(uint4 u, float* t)
{
    t[0] = __uint_as_float((u.x & 0xffffu) << 16);
    t[1] = __uint_as_float(u.x & 0xffff0000u);
    t[2] = __uint_as_float((u.y & 0xffffu) << 16);
    t[3] = __uint_as_float(u.y & 0xffff0000u);
    t[4] = __uint_as_float((u.z & 0xffffu) << 16);
    t[5] = __uint_as_float(u.z & 0xffff0000u);
    t[6] = __uint_as_float((u.w & 0xffffu) << 16);
    t[7] = __uint_as_float(u.w & 0xffff0000u);
}

// ---------------------------------------------------------------------------
__global__ __launch_bounds__(256) void detect_dtype(const void* __restrict__ tgt,
        float* __restrict__ flag)
{
    __shared__ float red[256];
    int t = threadIdx.x;
    const unsigned short* u = (const unsigned short*)tgt;
    float m = 0.f;
    for (int i = t; i < 2048; i += 256) {
        unsigned int bits = ((unsigned int)u[i]) << 16;
        float v = fabsf(__uint_as_float(bits));
        if (!isfinite(v)) v = 1e30f;
        m = fmaxf(m, v);
    }
    red[t] = m;
    __syncthreads();
    for (int st = 128; st; st >>= 1) {
        if (t < st) red[t] = fmaxf(red[t], red[t + st]);
        __syncthreads();
    }
    if (t == 0) flag[0] = (red[0] > 1e8f) ? 1.f : 0.f;
}

// ---------------------------------------------------------------------------
__global__ __launch_bounds__(256) void convert_w(const void* __restrict__ src,
        bf16* __restrict__ dst, const float* __restrict__ flagp)
{
    const bool ef = flagp[0] > 0.5f;
    size_t base = ((size_t)blockIdx.x * 256 + threadIdx.x) * 8;
    if (ef) {
        const float* s = (const float*)src + base;
        float4 f0 = *(const float4*)s;
        float4 f1 = *(const float4*)(s + 4);
        union { bf16 a[8]; uint4 u; } t;
        t.a[0] = __float2bfloat16(f0.x); t.a[1] = __float2bfloat16(f0.y);
        t.a[2] = __float2bfloat16(f0.z); t.a[3] = __float2bfloat16(f0.w);
        t.a[4] = __float2bfloat16(f1.x); t.a[5] = __float2bfloat16(f1.y);
        t.a[6] = __float2bfloat16(f1.z); t.a[7] = __float2bfloat16(f1.w);
        *(uint4*)(dst + base) = t.u;
    } else {
        *(uint4*)(dst + base) = *(const uint4*)((const bf16*)src + base);
    }
}

// ---------------------------------------------------------------------------
// Persistent value-projection GEMM: K=N=256. Whole W lives in LDS (132 KB).
// ---------------------------------------------------------------------------
__global__ __launch_bounds__(256) void gemm_vp(const void* __restrict__ A,
        const bf16* __restrict__ Wb, const void* __restrict__ bias,
        bf16* __restrict__ C, int M, const float* __restrict__ flagp)
{
    const bool ef = flagp[0] > 0.5f;          // true -> A is fp32
    __shared__ __align__(16) bf16 Wl[256 * VWS];   // 135168 B
    __shared__ __align__(16) bf16 Al[32 * VWS];    //  16896 B
    const int tid = threadIdx.x;
    const int w = tid >> 6, lane = tid & 63, lm = lane & 15, lq = lane >> 4;
    const int wq = w * 64;                    // wave's column quarter

    for (int u = tid; u < 8192; u += 256) {
        int row = u >> 5, col = (u & 31) * 8;
        *(uint4*)&Wl[row * VWS + col] = *(const uint4*)(Wb + (size_t)row * 256 + col);
    }

    float bv[4];
    #pragma unroll
    for (int nt = 0; nt < 4; nt++) bv[nt] = ldv(bias, wq + nt * 16 + lm, 2, ef);

    const int arow_l = tid >> 3;              // 0..31
    const int acol   = (tid & 7) * 32;        // 0,32,..,224

    const int ntiles = (M + 31) / 32;
    for (int tile = blockIdx.x; tile < ntiles; tile += gridDim.x) {
        const int m0 = tile * 32;
        __syncthreads();
        {
            const int grow = m0 + arow_l;
            if (grow < M) {
                if (ef) {
                    const float* ap = (const float*)A + (size_t)grow * 256 + acol;
                    #pragma unroll
                    for (int j = 0; j < 4; j++) {
                        float4 f0 = *(const float4*)(ap + j * 8);
                        float4 f1 = *(const float4*)(ap + j * 8 + 4);
                        union { bf16 a[8]; uint4 u; } t;
                        t.a[0] = __float2bfloat16(f0.x); t.a[1] = __float2bfloat16(f0.y);
                        t.a[2] = __float2bfloat16(f0.z); t.a[3] = __float2bfloat16(f0.w);
                        t.a[4] = __float2bfloat16(f1.x); t.a[5] = __float2bfloat16(f1.y);
                        t.a[6] = __float2bfloat16(f1.z); t.a[7] = __float2bfloat16(f1.w);
                        *(uint4*)&Al[arow_l * VWS + acol + j * 8] = t.u;
                    }
                } else {
                    const bf16* ap = (const bf16*)A + (size_t)grow * 256 + acol;
                    #pragma unroll
                    for (int j = 0; j < 4; j++)
                        *(uint4*)&Al[arow_l * VWS + acol + j * 8] =
                            *(const uint4*)(ap + j * 8);
                }
            } else {
                uint4 z = make_uint4(0u, 0u, 0u, 0u);
                #pragma unroll
                for (int j = 0; j < 4; j++)
                    *(uint4*)&Al[arow_l * VWS + acol + j * 8] = z;
            }
        }
        __syncthreads();

        f32x4 acc[2][4];
        #pragma unroll
        for (int mi = 0; mi < 2; mi++)
            #pragma unroll
            for (int nt = 0; nt < 4; nt++)
                acc[mi][nt] = (f32x4){0.f, 0.f, 0.f, 0.f};

        #pragma unroll
        for (int ks = 0; ks < 8; ks++) {
            bf16x8 af[2];
            #pragma unroll
            for (int mi = 0; mi < 2; mi++)
                af[mi] = *(const bf16x8*)&Al[(mi * 16 + lm) * VWS + ks * 32 + lq * 8];
            #pragma unroll
            for (int nt = 0; nt < 4; nt++) {
                bf16x8 bfr = *(const bf16x8*)&Wl[(wq + nt * 16 + lm) * VWS + ks * 32 + lq * 8];
                #pragma unroll
                for (int mi = 0; mi < 2; mi++)
                    acc[mi][nt] = __builtin_amdgcn_mfma_f32_16x16x32_bf16(
                                      af[mi], bfr, acc[mi][nt], 0, 0, 0);
            }
        }

        #pragma unroll
        for (int mi = 0; mi < 2; mi++) {
            #pragma unroll
            for (int r = 0; r < 4; r++) {
                int m = m0 + mi * 16 + lq * 4 + r;
                if (m >= M) continue;
                #pragma unroll
                for (int nt = 0; nt < 4; nt++) {
                    int col = wq + nt * 16 + lm;
                    C[(size_t)m * 256 + col] = __float2bfloat16(acc[mi][nt][r] + bv[nt]);
                }
            }
        }
    }
}

// ---------------------------------------------------------------------------
// stage A tile [32][32] : thread t -> row t>>3, col (t&7)*4  (uint2 / float4)
// ---------------------------------------------------------------------------
__device__ __forceinline__ void stage_a32(bf16* As, const void* A, bool a_bf16,
        int m0, int M, int K, int k0, int tid)
{
    const int row = tid >> 3, col = (tid & 7) * 4;
    const int arow = m0 + row;
    union { bf16 a[4]; uint2 u; } t;
    if (arow < M) {
        size_t base = (size_t)arow * K + k0 + col;
        if (a_bf16) {
            t.u = *(const uint2*)((const bf16*)A + base);
        } else {
            float4 f = *(const float4*)((const float*)A + base);
            t.a[0] = __float2bfloat16(f.x); t.a[1] = __float2bfloat16(f.y);
            t.a[2] = __float2bfloat16(f.z); t.a[3] = __float2bfloat16(f.w);
        }
    } else {
        t.u = make_uint2(0u, 0u);
    }
    *(uint2*)&As[row * SAK + col] = t.u;
}

// ---------------------------------------------------------------------------
// Plain GEMM, tile 32 x 256. grid: (N/256, ceil(M/32)).
// ---------------------------------------------------------------------------
__global__ __launch_bounds__(256) void gemm_a(const void* __restrict__ A, int amode,
        const bf16* __restrict__ Wb, const void* __restrict__ bias,
        void* __restrict__ C, int cmode, int M, int N, int K, int relu,
        const float* __restrict__ flagp)
{
    const bool ef = flagp[0] > 0.5f;
    const bool a_bf16 = (amode == 1) || (amode == 2 && !ef);
    __shared__ __align__(16) bf16 As[32 * SAK];
    __shared__ __align__(16) bf16 Ws[256 * SAK];
    const int tid = threadIdx.x;
    const int m0 = blockIdx.y * 32, n0 = blockIdx.x * 256;
    const int w = tid >> 6, lane = tid & 63, lm = lane & 15, lq = lane >> 4;
    const int wr = w >> 1, wc = w & 1;
    const int srow = tid >> 2, scol = (tid & 3) * 8;

    f32x4 acc[8];
    #pragma unroll
    for (int nt = 0; nt < 8; nt++) acc[nt] = (f32x4){0.f, 0.f, 0.f, 0.f};

    for (int k0 = 0; k0 < K; k0 += 32) {
        stage_a32(As, A, a_bf16, m0, M, K, k0, tid);
        #pragma unroll
        for (int it = 0; it < 4; it++) {
            int rr = it * 64 + srow;
            *(uint4*)&Ws[rr * SAK + scol] =
                *(const uint4*)(Wb + (size_t)(n0 + rr) * K + k0 + scol);
        }
        __syncthreads();

        bf16x8 af = *(const bf16x8*)&As[(wr * 16 + lm) * SAK + lq * 8];
        #pragma unroll
        for (int nt = 0; nt < 8; nt++) {
            bf16x8 bfr = *(const bf16x8*)&Ws[(wc * 128 + nt * 16 + lm) * SAK + lq * 8];
            acc[nt] = __builtin_amdgcn_mfma_f32_16x16x32_bf16(af, bfr, acc[nt], 0, 0, 0);
        }
        __syncthreads();
    }

    #pragma unroll
    for (int nt = 0; nt < 8; nt++) {
        int n = n0 + wc * 128 + nt * 16 + lm;
        float bv = ldv(bias, n, 2, ef);
        #pragma unroll
        for (int r = 0; r < 4; r++) {
            int m = m0 + wr * 16 + lq * 4 + r;
            if (m >= M) continue;
            float v = acc[nt][r] + bv;
            if (relu) v = fmaxf(v, 0.f);
            size_t ci = (size_t)m * N + n;
            if (cmode == 0) ((float*)C)[ci] = v;
            else            ((bf16*)C)[ci] = __float2bfloat16(v);
        }
    }
}

// ---------------------------------------------------------------------------
// Fused GEMM (N=256) + bias + residual + LayerNorm. Tile 32 x 256.
// ---------------------------------------------------------------------------
__global__ __launch_bounds__(256) void gemm_ln(const bf16* __restrict__ A,
        const bf16* __restrict__ Wb, const void* __restrict__ bias,
        const float* __restrict__ res, const void* __restrict__ gw,
        const void* __restrict__ bw, float* __restrict__ out32,
        bf16* __restrict__ outbf, void* __restrict__ dout, size_t obase,
        const void* __restrict__ qp, int M, int K,
        const float* __restrict__ flagp)
{
    const bool ef = flagp[0] > 0.5f;
    __shared__ __align__(16) bf16 As[32 * SAK];
    __shared__ __align__(16) bf16 Ws[256 * SAK];
    const int tid = threadIdx.x;
    const int m0 = blockIdx.y * 32;
    const int w = tid >> 6, lane = tid & 63, lm = lane & 15, lq = lane >> 4;
    const int wr = w >> 1, wc = w & 1;
    const int srow = tid >> 2, scol = (tid & 3) * 8;

    f32x4 acc[8];
    #pragma unroll
    for (int nt = 0; nt < 8; nt++) acc[nt] = (f32x4){0.f, 0.f, 0.f, 0.f};

    for (int k0 = 0; k0 < K; k0 += 32) {
        stage_a32(As, A, true, m0, M, K, k0, tid);
        #pragma unroll
        for (int it = 0; it < 4; it++) {
            int rr = it * 64 + srow;
            *(uint4*)&Ws[rr * SAK + scol] =
                *(const uint4*)(Wb + (size_t)rr * K + k0 + scol);
        }
        __syncthreads();

        bf16x8 af = *(const bf16x8*)&As[(wr * 16 + lm) * SAK + lq * 8];
        #pragma unroll
        for (int nt = 0; nt < 8; nt++) {
            bf16x8 bfr = *(const bf16x8*)&Ws[(wc * 128 + nt * 16 + lm) * SAK + lq * 8];
            acc[nt] = __builtin_amdgcn_mfma_f32_16x16x32_bf16(af, bfr, acc[nt], 0, 0, 0);
        }
        __syncthreads();
    }

    float bias_c[8], gcol[8], bcol[8];
    #pragma unroll
    for (int nt = 0; nt < 8; nt++) {
        int col = wc * 128 + nt * 16 + lm;
        bias_c[nt] = ldv(bias, col, 2, ef);
        gcol[nt]   = ldv(gw,   col, 2, ef);
        bcol[nt]   = ldv(bw,   col, 2, ef);
    }
    #pragma unroll
    for (int r = 0; r < 4; r++) {
        int row = m0 + wr * 16 + lq * 4 + r;
        bool vr_ = row < M;
        #pragma unroll
        for (int nt = 0; nt < 8; nt++) {
            int col = wc * 128 + nt * 16 + lm;
            float rv = vr_ ? res[(size_t)row * DM + col] : 0.f;
            acc[nt][r] += bias_c[nt] + rv;
        }
    }

    float* red = (float*)As;
    float mu[4], rstd[4];
    #pragma unroll
    for (int r = 0; r < 4; r++) {
        float s = 0.f;
        #pragma unroll
        for (int nt = 0; nt < 8; nt++) s += acc[nt][r];
        s += __shfl_xor(s, 1, 64); s += __shfl_xor(s, 2, 64);
        s += __shfl_xor(s, 4, 64); s += __shfl_xor(s, 8, 64);
        if (lm == 0) red[(wr * 16 + lq * 4 + r) * 2 + wc] = s;
    }
    __syncthreads();
    #pragma unroll
    for (int r = 0; r < 4; r++) {
        int rl = wr * 16 + lq * 4 + r;
        mu[r] = (red[rl * 2] + red[rl * 2 + 1]) * (1.f / DM);
    }
    #pragma unroll
    for (int r = 0; r < 4; r++) {
        float q = 0.f;
        #pragma unroll
        for (int nt = 0; nt < 8; nt++) {
            float d = acc[nt][r] - mu[r];
            q += d * d;
        }
        q += __shfl_xor(q, 1, 64); q += __shfl_xor(q, 2, 64);
        q += __shfl_xor(q, 4, 64); q += __shfl_xor(q, 8, 64);
        if (lm == 0) red[64 + (wr * 16 + lq * 4 + r) * 2 + wc] = q;
    }
    __syncthreads();
    #pragma unroll
    for (int r = 0; r < 4; r++) {
        int rl = wr * 16 + lq * 4 + r;
        float var = (red[64 + rl * 2] + red[64 + rl * 2 + 1]) * (1.f / DM);
        rstd[r] = rsqrtf(var + LN_EPS);
    }

    #pragma unroll
    for (int r = 0; r < 4; r++) {
        int row = m0 + wr * 16 + lq * 4 + r;
        if (row >= M) continue;
        size_t rbase = (size_t)row * DM;
        #pragma unroll
        for (int nt = 0; nt < 8; nt++) {
            int col = wc * 128 + nt * 16 + lm;
            float o = (acc[nt][r] - mu[r]) * rstd[r] * gcol[nt] + bcol[nt];
            if (dout) {
                if (ef) ((float*)dout)[obase + rbase + col] = o;
                else    ((bf16*)dout)[obase + rbase + col] = __float2bfloat16(o);
            }
            float o2 = o + (qp ? ldv(qp, rbase + col, 2, ef) : 0.f);
            out32[rbase + col] = o2;
            outbf[rbase + col] = __float2bfloat16(o2);
        }
    }
}

// ---------------------------------------------------------------------------
// Fused sampling-offset + attention-weight GEMM: W = concat(so_w, aw_w) rows
// (N=384). Tile 32 x 128; grid (3, ceil(M/32)).
// ---------------------------------------------------------------------------
__global__ __launch_bounds__(256) void gemm_soaw(const bf16* __restrict__ A,
        const bf16* __restrict__ Wb, const void* __restrict__ b1,
        const void* __restrict__ b2, float* __restrict__ C1,
        float* __restrict__ C2, int M, const float* __restrict__ flagp)
{
    const bool ef = flagp[0] > 0.5f;
    const int K = DM;
    __shared__ __align__(16) bf16 As[32 * SAK];
    __shared__ __align__(16) bf16 Ws[128 * SAK];
    const int tid = threadIdx.x;
    const int m0 = blockIdx.y * 32, n0 = blockIdx.x * 128;
    const int w = tid >> 6, lane = tid & 63, lm = lane & 15, lq = lane >> 4;
    const int wr = w >> 1, wc = w & 1;
    const int srow = tid >> 2, scol = (tid & 3) * 8;

    f32x4 acc[4];
    #pragma unroll
    for (int nt = 0; nt < 4; nt++) acc[nt] = (f32x4){0.f, 0.f, 0.f, 0.f};

    for (int k0 = 0; k0 < K; k0 += 32) {
        stage_a32(As, A, true, m0, M, K, k0, tid);
        #pragma unroll
        for (int it = 0; it < 2; it++) {
            int rr = it * 64 + srow;
            *(uint4*)&Ws[rr * SAK + scol] =
                *(const uint4*)(Wb + (size_t)(n0 + rr) * K + k0 + scol);
        }
        __syncthreads();

        bf16x8 af = *(const bf16x8*)&As[(wr * 16 + lm) * SAK + lq * 8];
        #pragma unroll
        for (int nt = 0; nt < 4; nt++) {
            bf16x8 bfr = *(const bf16x8*)&Ws[(wc * 64 + nt * 16 + lm) * SAK + lq * 8];
            acc[nt] = __builtin_amdgcn_mfma_f32_16x16x32_bf16(af, bfr, acc[nt], 0, 0, 0);
        }
        __syncthreads();
    }

    float* Cd; const void* bsrc; int nst, c0;
    if (n0 < 256) { Cd = C1; bsrc = b1; nst = 256; c0 = n0; }
    else          { Cd = C2; bsrc = b2; nst = 128; c0 = n0 - 256; }

    #pragma unroll
    for (int nt = 0; nt < 4; nt++) {
        int cl = wc * 64 + nt * 16 + lm;
        float bv = ldv(bsrc, c0 + cl, 2, ef);
        #pragma unroll
        for (int r = 0; r < 4; r++) {
            int m = m0 + wr * 16 + lq * 4 + r;
            if (m >= M) continue;
            Cd[(size_t)m * nst + c0 + cl] = acc[nt][r] + bv;
        }
    }
}

// ---------------------------------------------------------------------------
__global__ __launch_bounds__(256) void add_qpos(const void* __restrict__ a, int amode,
        const void* __restrict__ qp, float* __restrict__ o, bf16* __restrict__ ob,
        const float* __restrict__ flagp)
{
    const bool ef = flagp[0] > 0.5f;
    int i = blockIdx.x * 256 + threadIdx.x;
    float v = ldv(a, i, amode, ef) + ldv(qp, i, 2, ef);
    o[i]  = v;
    ob[i] = __float2bfloat16(v);
}

// ---------------------------------------------------------------------------
// MFMA flash MHA. grid (15 qtiles, 8 h, 8 b), 256 thr = 4 waves.
// ---------------------------------------------------------------------------
__global__ __launch_bounds__(256) void mha_mfma(const bf16* __restrict__ qkv,
        bf16* __restrict__ out)
{
    const int qt = blockIdx.x, h = blockIdx.y, b = blockIdx.z;
    const int q0 = qt * 64;
    const int tid = threadIdx.x;
    const int w = tid >> 6, lane = tid & 63;
    const int lm = lane & 15, lq = lane >> 4;
    const int srow = tid >> 2, sc = (tid & 3) * 8;

    __shared__ __align__(16) bf16 Qs[64][SAK];
    __shared__ __align__(16) bf16 Ks[64][SAK];
    __shared__ __align__(16) bf16 Vt[32][66];
    __shared__ __align__(16) bf16 Pt[64][66];

    const bf16* base = qkv + (size_t)b * NQ * 768;

    {
        bf16 tmp[8];
        if (q0 + srow < NQ) {
            uint4 u = *(const uint4*)(base + (size_t)(q0 + srow) * 768 + h * DHEAD + sc);
            float t[8]; unpack8(u, t);
            #pragma unroll
            for (int i = 0; i < 8; i++) tmp[i] = __float2bfloat16(t[i] * ATT_SCALE);
        } else {
            #pragma unroll
            for (int i = 0; i < 8; i++) tmp[i] = __float2bfloat16(0.f);
        }
        *(uint4*)&Qs[srow][sc] = *(const uint4*)tmp;
    }
    __syncthreads();
    const bf16x8 qf = *(const bf16x8*)&Qs[w * 16 + lm][lq * 8];

    f32x4 O[2] = {{0.f,0.f,0.f,0.f},{0.f,0.f,0.f,0.f}};
    float mrow = -1e30f, lrow = 0.f;

    for (int k0 = 0; k0 < NQ; k0 += 64) {
        __syncthreads();
        {
            uint4 uk = {0u,0u,0u,0u}, uv = {0u,0u,0u,0u};
            if (k0 + srow < NQ) {
                const bf16* rp = base + (size_t)(k0 + srow) * 768 + h * DHEAD + sc;
                uk = *(const uint4*)(rp + 256);
                uv = *(const uint4*)(rp + 512);
            }
            *(uint4*)&Ks[srow][sc] = uk;
            const bf16* vv = (const bf16*)&uv;
            #pragma unroll
            for (int i = 0; i < 8; i++) Vt[sc + i][srow] = vv[i];
        }
        __syncthreads();

        float sv[16];
        #pragma unroll
        for (int mt = 0; mt < 4; mt++) {
            bf16x8 kf = *(const bf16x8*)&Ks[mt * 16 + lm][lq * 8];
            f32x4 d = __builtin_amdgcn_mfma_f32_16x16x32_bf16(kf, qf,
                        (f32x4){0.f,0.f,0.f,0.f}, 0, 0, 0);
            sv[mt*4+0] = d[0]; sv[mt*4+1] = d[1]; sv[mt*4+2] = d[2]; sv[mt*4+3] = d[3];
        }
        #pragma unroll
        for (int mt = 0; mt < 4; mt++)
            #pragma unroll
            for (int r = 0; r < 4; r++)
                if (k0 + mt * 16 + lq * 4 + r >= NQ) sv[mt*4+r] = -1e30f;

        float tmax = sv[0];
        #pragma unroll
        for (int j = 1; j < 16; j++) tmax = fmaxf(tmax, sv[j]);
        tmax = fmaxf(tmax, __shfl_xor(tmax, 16, 64));
        tmax = fmaxf(tmax, __shfl_xor(tmax, 32, 64));
        float mnew = fmaxf(mrow, tmax);
        float alpha = __expf(mrow - mnew);
        mrow = mnew;
        float psum = 0.f;
        #pragma unroll
        for (int j = 0; j < 16; j++) {
            float p = __expf(sv[j] - mnew);
            sv[j] = p; psum += p;
        }
        psum += __shfl_xor(psum, 16, 64);
        psum += __shfl_xor(psum, 32, 64);
        lrow = lrow * alpha + psum;

        #pragma unroll
        for (int mt = 0; mt < 4; mt++)
            #pragma unroll
            for (int r = 0; r < 4; r++)
                Pt[mt * 16 + lq * 4 + r][w * 16 + lm] = __float2bfloat16(sv[mt*4+r]);

        #pragma unroll
        for (int mt = 0; mt < 2; mt++)
            #pragma unroll
            for (int r = 0; r < 4; r++) O[mt][r] *= alpha;
        #pragma unroll
        for (int ks = 0; ks < 2; ks++) {
            union { bf16 a[8]; bf16x8 v; } pf;
            #pragma unroll
            for (int j = 0; j < 8; j++)
                pf.a[j] = Pt[ks * 32 + lq * 8 + j][w * 16 + lm];
            #pragma unroll
            for (int mt = 0; mt < 2; mt++) {
                bf16x8 vf = *(const bf16x8*)&Vt[mt * 16 + lm][ks * 32 + lq * 8];
                O[mt] = __builtin_amdgcn_mfma_f32_16x16x32_bf16(vf, pf.v, O[mt], 0, 0, 0);
            }
        }
    }

    int q = q0 + w * 16 + lm;
    if (q < NQ) {
        float invl = 1.f / lrow;
        bf16* op = out + ((size_t)(b * NQ + q)) * DM + h * DHEAD;
        #pragma unroll
        for (int mt = 0; mt < 2; mt++)
            #pragma unroll
            for (int r = 0; r < 4; r++)
                op[mt * 16 + lq * 4 + r] = __float2bfloat16(O[mt][r] * invl);
    }
}

// ---------------------------------------------------------------------------
// MSDA sampling, 8 queries/block. Thread = (query qi, head h, chan-group cg).
// Each thread samples 8 channels via uint4 (16B) loads: 8x fewer VMEM
// instructions and 8x less duplicated address VALU vs 1-channel/thread.
// Inline attention-weight softmax (raw logits in). grid: BQ/8 = 900.
// ---------------------------------------------------------------------------
__global__ __launch_bounds__(256) void msda_sample8(const bf16* __restrict__ value,
        const float* __restrict__ off, const float* __restrict__ aw,
        const void* __restrict__ refp, const void* __restrict__ vr,
        bf16* __restrict__ out, const float* __restrict__ flagp)
{
    const bool ef = flagp[0] > 0.5f;
    const int tid = threadIdx.x;
    const int bq0 = blockIdx.x * 8;

    __shared__ float sOff[8][256];
    __shared__ float sAw[8][128];
    __shared__ float sref[8][2];
    __shared__ float svrq[8][8];

    // ---- stage offsets (2048 f), aw logits (1024 f), ref (16 f), vr (64 f)
    {
        const float* osrc = off + (size_t)bq0 * 256;
        #pragma unroll
        for (int i = 0; i < 2; i++) {
            int e = i * 1024 + tid * 4;
            *(float4*)&sOff[e >> 8][e & 255] = *(const float4*)(osrc + e);
        }
        int e2 = tid * 4;
        *(float4*)&sAw[e2 >> 7][e2 & 127] = *(const float4*)(aw + (size_t)bq0 * 128 + e2);
    }
    if (tid < 16) sref[tid >> 1][tid & 1] = ldv(refp, (size_t)(bq0 + (tid >> 1)) * 2 + (tid & 1), 2, ef);
    if (tid < 64) {
        int qi = tid >> 3, j = tid & 7;
        int b = (bq0 + qi) / NQ;
        svrq[qi][j] = ldv(vr, b * 8 + j, 2, ef);
    }
    __syncthreads();

    // ---- per-(query,head) softmax over 16 logits: 64 tasks ----
    if (tid < 64) {
        int qi = tid >> 3, h = tid & 7;
        float* p = &sAw[qi][h * 16];
        float mx = -1e30f;
        #pragma unroll
        for (int j = 0; j < 16; j++) mx = fmaxf(mx, p[j]);
        float s = 0.f;
        #pragma unroll
        for (int j = 0; j < 16; j++) { float e = __expf(p[j] - mx); p[j] = e; s += e; }
        float inv = 1.f / s;
        #pragma unroll
        for (int j = 0; j < 16; j++) p[j] *= inv;
    }
    __syncthreads();

    // ---- sampling: qi = tid>>5, h = (tid>>2)&7, cg = tid&3 (8 chans) ----
    const int qi = tid >> 5, sub = tid & 31;
    const int h = sub >> 2, cg = sub & 3;
    const int bq = bq0 + qi;
    const int b = bq / NQ;
    const bf16* vb = value + (size_t)b * NS * DM + h * DHEAD + cg * 8;

    float acc[8];
    #pragma unroll
    for (int j = 0; j < 8; j++) acc[j] = 0.f;

    const int HS[4] = {100, 50, 25, 13};
    const int ST[4] = {0, 10000, 12500, 13125};
    #pragma unroll
    for (int lvl = 0; lvl < 4; lvl++) {
        const int W_ = HS[lvl], H_ = HS[lvl], st = ST[lvl];
        float rx = sref[qi][0] * svrq[qi][lvl * 2 + 0] * (float)W_;
        float ry = sref[qi][1] * svrq[qi][lvl * 2 + 1] * (float)H_;
        #pragma unroll
        for (int p = 0; p < 4; p++) {
            int oi = h * 32 + lvl * 8 + p * 2;
            float x = fminf(fmaxf(rx + sOff[qi][oi]     - 0.5f, -4.f), (float)W_ + 4.f);
            float y = fminf(fmaxf(ry + sOff[qi][oi + 1] - 0.5f, -4.f), (float)H_ + 4.f);
            float x0f = floorf(x), y0f = floorf(y);
            float wx = x - x0f, wy = y - y0f;
            int x0 = (int)x0f, y0 = (int)y0f;
            int x1i = x0 + 1, y1i = y0 + 1;
            bool vx0 = (x0 >= 0) && (x0 < W_), vx1 = (x1i >= 0) && (x1i < W_);
            bool vy0 = (y0 >= 0) && (y0 < H_), vy1 = (y1i >= 0) && (y1i < H_);
            float g[8];
            #pragma unroll
            for (int j = 0; j < 8; j++) g[j] = 0.f;
            float t[8];
            if (vy0) {
                int rowo = (st + y0 * W_) * DM;
                if (vx0) {
                    uint4 u = *(const uint4*)(vb + rowo + x0 * DM);
                    unpack8(u, t);
                    float wgt = (1.f - wx) * (1.f - wy);
                    #pragma unroll
                    for (int j = 0; j < 8; j++) g[j] += wgt * t[j];
                }
                if (vx1) {
                    uint4 u = *(const uint4*)(vb + rowo + x1i * DM);
                    unpack8(u, t);
                    float wgt = wx * (1.f - wy);
                    #pragma unroll
                    for (int j = 0; j < 8; j++) g[j] += wgt * t[j];
                }
            }
            if (vy1) {
                int rowo = (st + y1i * W_) * DM;
                if (vx0) {
                    uint4 u = *(const uint4*)(vb + rowo + x0 * DM);
                    unpack8(u, t);
                    float wgt = (1.f - wx) * wy;
                    #pragma unroll
                    for (int j = 0; j < 8; j++) g[j] += wgt * t[j];
                }
                if (vx1) {
                    uint4 u = *(const uint4*)(vb + rowo + x1i * DM);
                    unpack8(u, t);
                    float wgt = wx * wy;
                    #pragma unroll
                    for (int j = 0; j < 8; j++) g[j] += wgt * t[j];
                }
            }
            float a = sAw[qi][h * 16 + lvl * 4 + p];
            #pragma unroll
            for (int j = 0; j < 8; j++) acc[j] += a * g[j];
        }
    }

    union { bf16 t[8]; uint4 u; } pk;
    #pragma unroll
    for (int j = 0; j < 8; j++) pk.t[j] = __float2bfloat16(acc[j]);
    *(uint4*)(out + (size_t)bq * DM + h * DHEAD + cg * 8) = pk.u;
}

// ---------------------------------------------------------------------------
__global__ __launch_bounds__(256) void copy_refs(const void* __restrict__ refp,
        void* __restrict__ out, const float* __restrict__ flagp)
{
    const bool ef = flagp[0] > 0.5f;
    int i = blockIdx.x * 256 + threadIdx.x;
    if (i >= NLAY * BQ * 2) return;
    float v = ldv(refp, i % (BQ * 2), 2, ef);
    size_t oi = (size_t)NLAY * BQ * DM + i;
    if (ef) ((float*)out)[oi] = v;
    else    ((bf16*)out)[oi] = __float2bfloat16(v);
}

// ---------------------------------------------------------------------------
extern "C" void kernel_launch(void* const* d_in, const int* in_sizes, int n_in,
                              void* d_out, int out_size, void* d_ws, size_t ws_size,
                              hipStream_t stream)
{
    const void* tgt     = d_in[0];
    const void* refp    = d_in[1];
    const void* memory  = d_in[2];
    const void* vr      = d_in[5];
    const void* qp      = d_in[6];
    const void* sa_in_w = d_in[7];
    const void* sa_in_b = d_in[8];
    const void* sa_out_w= d_in[9];
    const void* sa_out_b= d_in[10];
    const void* n1_g    = d_in[11];
    const void* n1_b    = d_in[12];
    const void* n2_g    = d_in[13];
    const void* n2_b    = d_in[14];
    const void* n3_g    = d_in[15];
    const void* n3_b    = d_in[16];
    const void* vp_w    = d_in[17];
    const void* vp_b    = d_in[18];
    const void* so_w    = d_in[19];
    const void* so_b    = d_in[20];
    const void* aw_w    = d_in[21];
    const void* aw_b    = d_in[22];
    const void* op_w    = d_in[23];
    const void* op_b    = d_in[24];
    const void* ff1_w   = d_in[25];
    const void* ff1_b   = d_in[26];
    const void* ff2_w   = d_in[27];
    const void* ff2_b   = d_in[28];

    // ---- workspace layout ----
    char* w = (char*)d_ws;
    float* flagp  = (float*)w;  w += 256;
    bf16*  value  = (bf16*)w;   w += (size_t)NB * NS * DM * 2;   // 54.45 MB
    float* outbuf = (float*)w;  w += (size_t)BQ * DM * 4;
    float* x1samp = (float*)w;  w += (size_t)BQ * DM * 4;
    bf16*  bigb   = (bf16*)w;   w += (size_t)BQ * NFF * 2;       // qkv / ffn hidden
    float* attoff = (float*)w;  w += (size_t)BQ * DM * 4;        // sampling offsets
    float* awb    = (float*)w;  w += (size_t)BQ * 128 * 4;       // aw logits
    bf16*  abuf   = (bf16*)w;   w += (size_t)BQ * DM * 2;        // x1/mha/msda bf16
    bf16*  outbf  = (bf16*)w;   w += (size_t)BQ * DM * 2;        // ln bf16 dup
    // pre-converted bf16 weights
    bf16* wb_sa_in = (bf16*)w;  w += (size_t)768 * 256 * 2;
    bf16* wb_sa_out= (bf16*)w;  w += (size_t)256 * 256 * 2;
    bf16* wb_soaw  = (bf16*)w;  w += (size_t)384 * 256 * 2;      // so(256) ++ aw(128)
    bf16* wb_op    = (bf16*)w;  w += (size_t)256 * 256 * 2;
    bf16* wb_ff1   = (bf16*)w;  w += (size_t)NFF * 256 * 2;
    bf16* wb_ff2   = (bf16*)w;  w += (size_t)256 * NFF * 2;
    bf16* wb_vp    = (bf16*)w;  w += (size_t)256 * 256 * 2;

    const int gy = (BQ + 31) / 32;      // 225
    const int MV = NB * NS;             // 106352

    // 0) detect external dtype, pre-convert weights to bf16
    detect_dtype<<<1, 256, 0, stream>>>(tgt, flagp);
    convert_w<<< 96, 256, 0, stream>>>(sa_in_w,  wb_sa_in,  flagp);
    convert_w<<< 32, 256, 0, stream>>>(sa_out_w, wb_sa_out, flagp);
    convert_w<<< 32, 256, 0, stream>>>(so_w,     wb_soaw,   flagp);
    convert_w<<< 16, 256, 0, stream>>>(aw_w,     wb_soaw + 256 * 256, flagp);
    convert_w<<< 32, 256, 0, stream>>>(op_w,     wb_op,     flagp);
    convert_w<<<128, 256, 0, stream>>>(ff1_w,    wb_ff1,    flagp);
    convert_w<<<128, 256, 0, stream>>>(ff2_w,    wb_ff2,    flagp);
    convert_w<<< 32, 256, 0, stream>>>(vp_w,     wb_vp,     flagp);

    // 1) value projection: persistent LDS-resident-W GEMM (1 block/CU)
    gemm_vp<<<256, 256, 0, stream>>>(memory, wb_vp, vp_b, value, MV, flagp);

    // 2) inter_refs output
    copy_refs<<<(NLAY * BQ * 2 + 255) / 256, 256, 0, stream>>>(refp, d_out, flagp);

    // 3) x1 = tgt + query_pos (layer 0 only; later layers fused into ff2 LN)
    add_qpos<<<BQ * DM / 256, 256, 0, stream>>>(tgt, 2, qp, x1samp, abuf, flagp);

    for (int l = 0; l < NLAY; l++) {
        // self-attention
        gemm_a<<<dim3(768/256, gy), 256, 0, stream>>>(
            abuf, 1, wb_sa_in, sa_in_b, bigb, 1, BQ, 768, DM, 0, flagp);
        mha_mfma<<<dim3(15, NHEADS, NB), 256, 0, stream>>>(bigb, abuf);
        gemm_ln<<<dim3(1, gy), 256, 0, stream>>>(
            abuf, wb_sa_out, sa_out_b, x1samp, n1_g, n1_b,
            outbuf, outbf, nullptr, 0, nullptr, BQ, DM, flagp);

        // MSDA: fused so+aw GEMM, 8-query sampling w/ inline softmax, op+LN2
        gemm_soaw<<<dim3(3, gy), 256, 0, stream>>>(
            outbf, wb_soaw, so_b, aw_b, attoff, awb, BQ, flagp);
        msda_sample8<<<BQ / 8, 256, 0, stream>>>(value, attoff, awb, refp, vr, abuf, flagp);
        gemm_ln<<<dim3(1, gy), 256, 0, stream>>>(
            abuf, wb_op, op_b, outbuf, n2_g, n2_b,
            outbuf, outbf, nullptr, 0, nullptr, BQ, DM, flagp);

        // FFN: ff1 (relu, bf16 hidden), ff2 + LN3 + d_out slice + next x1(+qp)
        gemm_a<<<dim3(NFF/256, gy), 256, 0, stream>>>(
            outbf, 1, wb_ff1, ff1_b, bigb, 1, BQ, NFF, DM, 1, flagp);
        gemm_ln<<<dim3(1, gy), 256, 0, stream>>>(
            bigb, wb_ff2, ff2_b, outbuf, n3_g, n3_b,
            x1samp, abuf, d_out, (size_t)l * BQ * DM, qp, BQ, NFF, flagp);
    }
}

// Round 7
// 1523.250 us; speedup vs baseline: 1.8415x; 1.0026x over previous
//
#include <hip/hip_runtime.h>
#include <hip/hip_bf16.h>

typedef __hip_bfloat16 bf16;
typedef __bf16 bf16x8 __attribute__((ext_vector_type(8)));
typedef float  f32x4  __attribute__((ext_vector_type(4)));

#define NB 8
#define NQ 900
#define DM 256
#define NHEADS 8
#define DHEAD 32
#define NFF 1024
#define NLAY 6
#define NS 13294
#define BQ (NB*NQ)            // 7200
#define LN_EPS 1e-5f
#define ATT_SCALE 0.17677669529663687f   // 1/sqrt(32)
#define SAK 40                // LDS row stride (bf16): 80B — measured ~2-way (free)
#define VWS 264               // vp kernel: A LDS row stride (256+8): 2-way banks

__device__ __forceinline__ float bfd(const bf16* p, size_t i){ return __bfloat162float(p[i]); }

// mode: 0 = fp32 (internal), 1 = bf16 (internal), 2 = external (dtype per flag)
__device__ __forceinline__ float ldv(const void* p, size_t i, int mode, bool extF32)
{
    if (mode == 0) return ((const float*)p)[i];
    if (mode == 1) return bfd((const bf16*)p, i);
    return extF32 ? ((const float*)p)[i] : bfd((const bf16*)p, i);
}

// unpack 8 bf16 (16B) to floats
__device__ __forceinline__ void unpack8(uint4 u, float* t)
{
    t[0] = __uint_as_float((u.x & 0xffffu) << 16);
    t[1] = __uint_as_float(u.x & 0xffff0000u);
    t[2] = __uint_as_float((u.y & 0xffffu) << 16);
    t[3] = __uint_as_float(u.y & 0xffff0000u);
    t[4] = __uint_as_float((u.z & 0xffffu) << 16);
    t[5] = __uint_as_float(u.z & 0xffff0000u);
    t[6] = __uint_as_float((u.w & 0xffffu) << 16);
    t[7] = __uint_as_float(u.w & 0xffff0000u);
}

// ---------------------------------------------------------------------------
__global__ __launch_bounds__(256) void detect_dtype(const void* __restrict__ tgt,
        float* __restrict__ flag)
{
    __shared__ float red[256];
    int t = threadIdx.x;
    const unsigned short* u = (const unsigned short*)tgt;
    float m = 0.f;
    for (int i = t; i < 2048; i += 256) {
        unsigned int bits = ((unsigned int)u[i]) << 16;
        float v = fabsf(__uint_as_float(bits));
        if (!isfinite(v)) v = 1e30f;
        m = fmaxf(m, v);
    }
    red[t] = m;
    __syncthreads();
    for (int st = 128; st; st >>= 1) {
        if (t < st) red[t] = fmaxf(red[t], red[t + st]);
        __syncthreads();
    }
    if (t == 0) flag[0] = (red[0] > 1e8f) ? 1.f : 0.f;
}

// ---------------------------------------------------------------------------
__global__ __launch_bounds__(256) void convert_w(const void* __restrict__ src,
        bf16* __restrict__ dst, const float* __restrict__ flagp)
{
    const bool ef = flagp[0] > 0.5f;
    size_t base = ((size_t)blockIdx.x * 256 + threadIdx.x) * 8;
    if (ef) {
        const float* s = (const float*)src + base;
        float4 f0 = *(const float4*)s;
        float4 f1 = *(const float4*)(s + 4);
        union { bf16 a[8]; uint4 u; } t;
        t.a[0] = __float2bfloat16(f0.x); t.a[1] = __float2bfloat16(f0.y);
        t.a[2] = __float2bfloat16(f0.z); t.a[3] = __float2bfloat16(f0.w);
        t.a[4] = __float2bfloat16(f1.x); t.a[5] = __float2bfloat16(f1.y);
        t.a[6] = __float2bfloat16(f1.z); t.a[7] = __float2bfloat16(f1.w);
        *(uint4*)(dst + base) = t.u;
    } else {
        *(uint4*)(dst + base) = *(const uint4*)((const bf16*)src + base);
    }
}

// ---------------------------------------------------------------------------
// Value-projection GEMM, W-in-registers. K=N=256. Each wave preloads its
// 64-col W quarter as 32 bf16x8 frags (128 VGPR) ONCE; LDS holds only the
// 64-row A tile (34 KB) -> 2 blocks/CU (2 waves/SIMD). K-loop does only
// A ds_reads: 4 reads per 16 MFMAs. Numerics identical to LDS-W version.
// grid: 512 persistent blocks, stride over ceil(M/64) tiles.
// ---------------------------------------------------------------------------
__global__ __launch_bounds__(256, 2) void gemm_vp(const void* __restrict__ A,
        const bf16* __restrict__ Wb, const void* __restrict__ bias,
        bf16* __restrict__ C, int M, const float* __restrict__ flagp)
{
    const bool ef = flagp[0] > 0.5f;          // true -> A is fp32
    __shared__ __align__(16) bf16 Al[64 * VWS];    // 33792 B
    const int tid = threadIdx.x;
    const int w = tid >> 6, lane = tid & 63, lm = lane & 15, lq = lane >> 4;
    const int wq = w * 64;                    // wave's column quarter

    // ---- preload W quarter into registers (once; L2-hot) ----
    bf16x8 wf[4][8];
    #pragma unroll
    for (int nt = 0; nt < 4; nt++)
        #pragma unroll
        for (int ks = 0; ks < 8; ks++)
            wf[nt][ks] = *(const bf16x8*)(Wb +
                (size_t)(wq + nt * 16 + lm) * 256 + ks * 32 + lq * 8);

    float bv[4];
    #pragma unroll
    for (int nt = 0; nt < 4; nt++) bv[nt] = ldv(bias, wq + nt * 16 + lm, 2, ef);

    const int arow_l = tid >> 2;              // 0..63
    const int asub   = tid & 3;

    const int ntiles = (M + 63) / 64;
    for (int tile = blockIdx.x; tile < ntiles; tile += gridDim.x) {
        const int m0 = tile * 64;
        __syncthreads();                      // prior tile's reads done
        // ---- stage A tile [64][256] ----
        {
            const int grow = m0 + arow_l;
            if (grow < M) {
                if (ef) {
                    const float* ap = (const float*)A + (size_t)grow * 256;
                    #pragma unroll
                    for (int j = 0; j < 16; j++) {
                        int colf = j * 16 + asub * 4;    // quad covers 64B
                        float4 f = *(const float4*)(ap + colf);
                        union { bf16 a[4]; uint2 u; } t;
                        t.a[0] = __float2bfloat16(f.x); t.a[1] = __float2bfloat16(f.y);
                        t.a[2] = __float2bfloat16(f.z); t.a[3] = __float2bfloat16(f.w);
                        *(uint2*)&Al[arow_l * VWS + colf] = t.u;
                    }
                } else {
                    const bf16* ap = (const bf16*)A + (size_t)grow * 256;
                    #pragma unroll
                    for (int j = 0; j < 8; j++) {
                        int cole = j * 32 + asub * 8;    // quad covers 64B
                        *(uint4*)&Al[arow_l * VWS + cole] = *(const uint4*)(ap + cole);
                    }
                }
            } else {
                uint4 z = make_uint4(0u, 0u, 0u, 0u);
                #pragma unroll
                for (int j = 0; j < 8; j++)
                    *(uint4*)&Al[arow_l * VWS + j * 32 + asub * 8] = z;
            }
        }
        __syncthreads();                      // A tile ready

        // ---- compute: 8 K-steps x (4 m-frags x 4 n-frags) = 128 MFMAs ----
        f32x4 acc[4][4];
        #pragma unroll
        for (int mi = 0; mi < 4; mi++)
            #pragma unroll
            for (int nt = 0; nt < 4; nt++)
                acc[mi][nt] = (f32x4){0.f, 0.f, 0.f, 0.f};

        #pragma unroll
        for (int ks = 0; ks < 8; ks++) {
            bf16x8 af[4];
            #pragma unroll
            for (int mi = 0; mi < 4; mi++)
                af[mi] = *(const bf16x8*)&Al[(mi * 16 + lm) * VWS + ks * 32 + lq * 8];
            #pragma unroll
            for (int nt = 0; nt < 4; nt++)
                #pragma unroll
                for (int mi = 0; mi < 4; mi++)
                    acc[mi][nt] = __builtin_amdgcn_mfma_f32_16x16x32_bf16(
                                      af[mi], wf[nt][ks], acc[mi][nt], 0, 0, 0);
        }

        // ---- write C tile (bf16) ----
        #pragma unroll
        for (int mi = 0; mi < 4; mi++) {
            #pragma unroll
            for (int r = 0; r < 4; r++) {
                int m = m0 + mi * 16 + lq * 4 + r;
                if (m >= M) continue;
                #pragma unroll
                for (int nt = 0; nt < 4; nt++) {
                    int col = wq + nt * 16 + lm;
                    C[(size_t)m * 256 + col] = __float2bfloat16(acc[mi][nt][r] + bv[nt]);
                }
            }
        }
    }
}

// ---------------------------------------------------------------------------
// stage A tile [32][32] : thread t -> row t>>3, col (t&7)*4  (uint2 / float4)
// ---------------------------------------------------------------------------
__device__ __forceinline__ void stage_a32(bf16* As, const void* A, bool a_bf16,
        int m0, int M, int K, int k0, int tid)
{
    const int row = tid >> 3, col = (tid & 7) * 4;
    const int arow = m0 + row;
    union { bf16 a[4]; uint2 u; } t;
    if (arow < M) {
        size_t base = (size_t)arow * K + k0 + col;
        if (a_bf16) {
            t.u = *(const uint2*)((const bf16*)A + base);
        } else {
            float4 f = *(const float4*)((const float*)A + base);
            t.a[0] = __float2bfloat16(f.x); t.a[1] = __float2bfloat16(f.y);
            t.a[2] = __float2bfloat16(f.z); t.a[3] = __float2bfloat16(f.w);
        }
    } else {
        t.u = make_uint2(0u, 0u);
    }
    *(uint2*)&As[row * SAK + col] = t.u;
}

// ---------------------------------------------------------------------------
// Plain GEMM, tile 32 x 256. grid: (N/256, ceil(M/32)).
// ---------------------------------------------------------------------------
__global__ __launch_bounds__(256) void gemm_a(const void* __restrict__ A, int amode,
        const bf16* __restrict__ Wb, const void* __restrict__ bias,
        void* __restrict__ C, int cmode, int M, int N, int K, int relu,
        const float* __restrict__ flagp)
{
    const bool ef = flagp[0] > 0.5f;
    const bool a_bf16 = (amode == 1) || (amode == 2 && !ef);
    __shared__ __align__(16) bf16 As[32 * SAK];
    __shared__ __align__(16) bf16 Ws[256 * SAK];
    const int tid = threadIdx.x;
    const int m0 = blockIdx.y * 32, n0 = blockIdx.x * 256;
    const int w = tid >> 6, lane = tid & 63, lm = lane & 15, lq = lane >> 4;
    const int wr = w >> 1, wc = w & 1;
    const int srow = tid >> 2, scol = (tid & 3) * 8;

    f32x4 acc[8];
    #pragma unroll
    for (int nt = 0; nt < 8; nt++) acc[nt] = (f32x4){0.f, 0.f, 0.f, 0.f};

    for (int k0 = 0; k0 < K; k0 += 32) {
        stage_a32(As, A, a_bf16, m0, M, K, k0, tid);
        #pragma unroll
        for (int it = 0; it < 4; it++) {
            int rr = it * 64 + srow;
            *(uint4*)&Ws[rr * SAK + scol] =
                *(const uint4*)(Wb + (size_t)(n0 + rr) * K + k0 + scol);
        }
        __syncthreads();

        bf16x8 af = *(const bf16x8*)&As[(wr * 16 + lm) * SAK + lq * 8];
        #pragma unroll
        for (int nt = 0; nt < 8; nt++) {
            bf16x8 bfr = *(const bf16x8*)&Ws[(wc * 128 + nt * 16 + lm) * SAK + lq * 8];
            acc[nt] = __builtin_amdgcn_mfma_f32_16x16x32_bf16(af, bfr, acc[nt], 0, 0, 0);
        }
        __syncthreads();
    }

    #pragma unroll
    for (int nt = 0; nt < 8; nt++) {
        int n = n0 + wc * 128 + nt * 16 + lm;
        float bv = ldv(bias, n, 2, ef);
        #pragma unroll
        for (int r = 0; r < 4; r++) {
            int m = m0 + wr * 16 + lq * 4 + r;
            if (m >= M) continue;
            float v = acc[nt][r] + bv;
            if (relu) v = fmaxf(v, 0.f);
            size_t ci = (size_t)m * N + n;
            if (cmode == 0) ((float*)C)[ci] = v;
            else            ((bf16*)C)[ci] = __float2bfloat16(v);
        }
    }
}

// ---------------------------------------------------------------------------
// Fused GEMM (N=256) + bias + residual + LayerNorm. Tile 32 x 256.
// ---------------------------------------------------------------------------
__global__ __launch_bounds__(256) void gemm_ln(const bf16* __restrict__ A,
        const bf16* __restrict__ Wb, const void* __restrict__ bias,
        const float* __restrict__ res, const void* __restrict__ gw,
        const void* __restrict__ bw, float* __restrict__ out32,
        bf16* __restrict__ outbf, void* __restrict__ dout, size_t obase,
        const void* __restrict__ qp, int M, int K,
        const float* __restrict__ flagp)
{
    const bool ef = flagp[0] > 0.5f;
    __shared__ __align__(16) bf16 As[32 * SAK];
    __shared__ __align__(16) bf16 Ws[256 * SAK];
    const int tid = threadIdx.x;
    const int m0 = blockIdx.y * 32;
    const int w = tid >> 6, lane = tid & 63, lm = lane & 15, lq = lane >> 4;
    const int wr = w >> 1, wc = w & 1;
    const int srow = tid >> 2, scol = (tid & 3) * 8;

    f32x4 acc[8];
    #pragma unroll
    for (int nt = 0; nt < 8; nt++) acc[nt] = (f32x4){0.f, 0.f, 0.f, 0.f};

    for (int k0 = 0; k0 < K; k0 += 32) {
        stage_a32(As, A, true, m0, M, K, k0, tid);
        #pragma unroll
        for (int it = 0; it < 4; it++) {
            int rr = it * 64 + srow;
            *(uint4*)&Ws[rr * SAK + scol] =
                *(const uint4*)(Wb + (size_t)rr * K + k0 + scol);
        }
        __syncthreads();

        bf16x8 af = *(const bf16x8*)&As[(wr * 16 + lm) * SAK + lq * 8];
        #pragma unroll
        for (int nt = 0; nt < 8; nt++) {
            bf16x8 bfr = *(const bf16x8*)&Ws[(wc * 128 + nt * 16 + lm) * SAK + lq * 8];
            acc[nt] = __builtin_amdgcn_mfma_f32_16x16x32_bf16(af, bfr, acc[nt], 0, 0, 0);
        }
        __syncthreads();
    }

    float bias_c[8], gcol[8], bcol[8];
    #pragma unroll
    for (int nt = 0; nt < 8; nt++) {
        int col = wc * 128 + nt * 16 + lm;
        bias_c[nt] = ldv(bias, col, 2, ef);
        gcol[nt]   = ldv(gw,   col, 2, ef);
        bcol[nt]   = ldv(bw,   col, 2, ef);
    }
    #pragma unroll
    for (int r = 0; r < 4; r++) {
        int row = m0 + wr * 16 + lq * 4 + r;
        bool vr_ = row < M;
        #pragma unroll
        for (int nt = 0; nt < 8; nt++) {
            int col = wc * 128 + nt * 16 + lm;
            float rv = vr_ ? res[(size_t)row * DM + col] : 0.f;
            acc[nt][r] += bias_c[nt] + rv;
        }
    }

    float* red = (float*)As;
    float mu[4], rstd[4];
    #pragma unroll
    for (int r = 0; r < 4; r++) {
        float s = 0.f;
        #pragma unroll
        for (int nt = 0; nt < 8; nt++) s += acc[nt][r];
        s += __shfl_xor(s, 1, 64); s += __shfl_xor(s, 2, 64);
        s += __shfl_xor(s, 4, 64); s += __shfl_xor(s, 8, 64);
        if (lm == 0) red[(wr * 16 + lq * 4 + r) * 2 + wc] = s;
    }
    __syncthreads();
    #pragma unroll
    for (int r = 0; r < 4; r++) {
        int rl = wr * 16 + lq * 4 + r;
        mu[r] = (red[rl * 2] + red[rl * 2 + 1]) * (1.f / DM);
    }
    #pragma unroll
    for (int r = 0; r < 4; r++) {
        float q = 0.f;
        #pragma unroll
        for (int nt = 0; nt < 8; nt++) {
            float d = acc[nt][r] - mu[r];
            q += d * d;
        }
        q += __shfl_xor(q, 1, 64); q += __shfl_xor(q, 2, 64);
        q += __shfl_xor(q, 4, 64); q += __shfl_xor(q, 8, 64);
        if (lm == 0) red[64 + (wr * 16 + lq * 4 + r) * 2 + wc] = q;
    }
    __syncthreads();
    #pragma unroll
    for (int r = 0; r < 4; r++) {
        int rl = wr * 16 + lq * 4 + r;
        float var = (red[64 + rl * 2] + red[64 + rl * 2 + 1]) * (1.f / DM);
        rstd[r] = rsqrtf(var + LN_EPS);
    }

    #pragma unroll
    for (int r = 0; r < 4; r++) {
        int row = m0 + wr * 16 + lq * 4 + r;
        if (row >= M) continue;
        size_t rbase = (size_t)row * DM;
        #pragma unroll
        for (int nt = 0; nt < 8; nt++) {
            int col = wc * 128 + nt * 16 + lm;
            float o = (acc[nt][r] - mu[r]) * rstd[r] * gcol[nt] + bcol[nt];
            if (dout) {
                if (ef) ((float*)dout)[obase + rbase + col] = o;
                else    ((bf16*)dout)[obase + rbase + col] = __float2bfloat16(o);
            }
            float o2 = o + (qp ? ldv(qp, rbase + col, 2, ef) : 0.f);
            out32[rbase + col] = o2;
            outbf[rbase + col] = __float2bfloat16(o2);
        }
    }
}

// ---------------------------------------------------------------------------
// Fused sampling-offset + attention-weight GEMM: W = concat(so_w, aw_w) rows
// (N=384). Tile 32 x 128; grid (3, ceil(M/32)).
// ---------------------------------------------------------------------------
__global__ __launch_bounds__(256) void gemm_soaw(const bf16* __restrict__ A,
        const bf16* __restrict__ Wb, const void* __restrict__ b1,
        const void* __restrict__ b2, float* __restrict__ C1,
        float* __restrict__ C2, int M, const float* __restrict__ flagp)
{
    const bool ef = flagp[0] > 0.5f;
    const int K = DM;
    __shared__ __align__(16) bf16 As[32 * SAK];
    __shared__ __align__(16) bf16 Ws[128 * SAK];
    const int tid = threadIdx.x;
    const int m0 = blockIdx.y * 32, n0 = blockIdx.x * 128;
    const int w = tid >> 6, lane = tid & 63, lm = lane & 15, lq = lane >> 4;
    const int wr = w >> 1, wc = w & 1;
    const int srow = tid >> 2, scol = (tid & 3) * 8;

    f32x4 acc[4];
    #pragma unroll
    for (int nt = 0; nt < 4; nt++) acc[nt] = (f32x4){0.f, 0.f, 0.f, 0.f};

    for (int k0 = 0; k0 < K; k0 += 32) {
        stage_a32(As, A, true, m0, M, K, k0, tid);
        #pragma unroll
        for (int it = 0; it < 2; it++) {
            int rr = it * 64 + srow;
            *(uint4*)&Ws[rr * SAK + scol] =
                *(const uint4*)(Wb + (size_t)(n0 + rr) * K + k0 + scol);
        }
        __syncthreads();

        bf16x8 af = *(const bf16x8*)&As[(wr * 16 + lm) * SAK + lq * 8];
        #pragma unroll
        for (int nt = 0; nt < 4; nt++) {
            bf16x8 bfr = *(const bf16x8*)&Ws[(wc * 64 + nt * 16 + lm) * SAK + lq * 8];
            acc[nt] = __builtin_amdgcn_mfma_f32_16x16x32_bf16(af, bfr, acc[nt], 0, 0, 0);
        }
        __syncthreads();
    }

    float* Cd; const void* bsrc; int nst, c0;
    if (n0 < 256) { Cd = C1; bsrc = b1; nst = 256; c0 = n0; }
    else          { Cd = C2; bsrc = b2; nst = 128; c0 = n0 - 256; }

    #pragma unroll
    for (int nt = 0; nt < 4; nt++) {
        int cl = wc * 64 + nt * 16 + lm;
        float bv = ldv(bsrc, c0 + cl, 2, ef);
        #pragma unroll
        for (int r = 0; r < 4; r++) {
            int m = m0 + wr * 16 + lq * 4 + r;
            if (m >= M) continue;
            Cd[(size_t)m * nst + c0 + cl] = acc[nt][r] + bv;
        }
    }
}

// ---------------------------------------------------------------------------
__global__ __launch_bounds__(256) void add_qpos(const void* __restrict__ a, int amode,
        const void* __restrict__ qp, float* __restrict__ o, bf16* __restrict__ ob,
        const float* __restrict__ flagp)
{
    const bool ef = flagp[0] > 0.5f;
    int i = blockIdx.x * 256 + threadIdx.x;
    float v = ldv(a, i, amode, ef) + ldv(qp, i, 2, ef);
    o[i]  = v;
    ob[i] = __float2bfloat16(v);
}

// ---------------------------------------------------------------------------
// MFMA flash MHA. grid (15 qtiles, 8 h, 8 b), 256 thr = 4 waves.
// ---------------------------------------------------------------------------
__global__ __launch_bounds__(256) void mha_mfma(const bf16* __restrict__ qkv,
        bf16* __restrict__ out)
{
    const int qt = blockIdx.x, h = blockIdx.y, b = blockIdx.z;
    const int q0 = qt * 64;
    const int tid = threadIdx.x;
    const int w = tid >> 6, lane = tid & 63;
    const int lm = lane & 15, lq = lane >> 4;
    const int srow = tid >> 2, sc = (tid & 3) * 8;

    __shared__ __align__(16) bf16 Qs[64][SAK];
    __shared__ __align__(16) bf16 Ks[64][SAK];
    __shared__ __align__(16) bf16 Vt[32][66];
    __shared__ __align__(16) bf16 Pt[64][66];

    const bf16* base = qkv + (size_t)b * NQ * 768;

    {
        bf16 tmp[8];
        if (q0 + srow < NQ) {
            uint4 u = *(const uint4*)(base + (size_t)(q0 + srow) * 768 + h * DHEAD + sc);
            float t[8]; unpack8(u, t);
            #pragma unroll
            for (int i = 0; i < 8; i++) tmp[i] = __float2bfloat16(t[i] * ATT_SCALE);
        } else {
            #pragma unroll
            for (int i = 0; i < 8; i++) tmp[i] = __float2bfloat16(0.f);
        }
        *(uint4*)&Qs[srow][sc] = *(const uint4*)tmp;
    }
    __syncthreads();
    const bf16x8 qf = *(const bf16x8*)&Qs[w * 16 + lm][lq * 8];

    f32x4 O[2] = {{0.f,0.f,0.f,0.f},{0.f,0.f,0.f,0.f}};
    float mrow = -1e30f, lrow = 0.f;

    for (int k0 = 0; k0 < NQ; k0 += 64) {
        __syncthreads();
        {
            uint4 uk = {0u,0u,0u,0u}, uv = {0u,0u,0u,0u};
            if (k0 + srow < NQ) {
                const bf16* rp = base + (size_t)(k0 + srow) * 768 + h * DHEAD + sc;
                uk = *(const uint4*)(rp + 256);
                uv = *(const uint4*)(rp + 512);
            }
            *(uint4*)&Ks[srow][sc] = uk;
            const bf16* vv = (const bf16*)&uv;
            #pragma unroll
            for (int i = 0; i < 8; i++) Vt[sc + i][srow] = vv[i];
        }
        __syncthreads();

        float sv[16];
        #pragma unroll
        for (int mt = 0; mt < 4; mt++) {
            bf16x8 kf = *(const bf16x8*)&Ks[mt * 16 + lm][lq * 8];
            f32x4 d = __builtin_amdgcn_mfma_f32_16x16x32_bf16(kf, qf,
                        (f32x4){0.f,0.f,0.f,0.f}, 0, 0, 0);
            sv[mt*4+0] = d[0]; sv[mt*4+1] = d[1]; sv[mt*4+2] = d[2]; sv[mt*4+3] = d[3];
        }
        #pragma unroll
        for (int mt = 0; mt < 4; mt++)
            #pragma unroll
            for (int r = 0; r < 4; r++)
                if (k0 + mt * 16 + lq * 4 + r >= NQ) sv[mt*4+r] = -1e30f;

        float tmax = sv[0];
        #pragma unroll
        for (int j = 1; j < 16; j++) tmax = fmaxf(tmax, sv[j]);
        tmax = fmaxf(tmax, __shfl_xor(tmax, 16, 64));
        tmax = fmaxf(tmax, __shfl_xor(tmax, 32, 64));
        float mnew = fmaxf(mrow, tmax);
        float alpha = __expf(mrow - mnew);
        mrow = mnew;
        float psum = 0.f;
        #pragma unroll
        for (int j = 0; j < 16; j++) {
            float p = __expf(sv[j] - mnew);
            sv[j] = p; psum += p;
        }
        psum += __shfl_xor(psum, 16, 64);
        psum += __shfl_xor(psum, 32, 64);
        lrow = lrow * alpha + psum;

        #pragma unroll
        for (int mt = 0; mt < 4; mt++)
            #pragma unroll
            for (int r = 0; r < 4; r++)
                Pt[mt * 16 + lq * 4 + r][w * 16 + lm] = __float2bfloat16(sv[mt*4+r]);

        #pragma unroll
        for (int mt = 0; mt < 2; mt++)
            #pragma unroll
            for (int r = 0; r < 4; r++) O[mt][r] *= alpha;
        #pragma unroll
        for (int ks = 0; ks < 2; ks++) {
            union { bf16 a[8]; bf16x8 v; } pf;
            #pragma unroll
            for (int j = 0; j < 8; j++)
                pf.a[j] = Pt[ks * 32 + lq * 8 + j][w * 16 + lm];
            #pragma unroll
            for (int mt = 0; mt < 2; mt++) {
                bf16x8 vf = *(const bf16x8*)&Vt[mt * 16 + lm][ks * 32 + lq * 8];
                O[mt] = __builtin_amdgcn_mfma_f32_16x16x32_bf16(vf, pf.v, O[mt], 0, 0, 0);
            }
        }
    }

    int q = q0 + w * 16 + lm;
    if (q < NQ) {
        float invl = 1.f / lrow;
        bf16* op = out + ((size_t)(b * NQ + q)) * DM + h * DHEAD;
        #pragma unroll
        for (int mt = 0; mt < 2; mt++)
            #pragma unroll
            for (int r = 0; r < 4; r++)
                op[mt * 16 + lq * 4 + r] = __float2bfloat16(O[mt][r] * invl);
    }
}

// ---------------------------------------------------------------------------
// MSDA sampling, 8 queries/block. Thread = (query qi, head h, chan-group cg).
// ---------------------------------------------------------------------------
__global__ __launch_bounds__(256) void msda_sample8(const bf16* __restrict__ value,
        const float* __restrict__ off, const float* __restrict__ aw,
        const void* __restrict__ refp, const void* __restrict__ vr,
        bf16* __restrict__ out, const float* __restrict__ flagp)
{
    const bool ef = flagp[0] > 0.5f;
    const int tid = threadIdx.x;
    const int bq0 = blockIdx.x * 8;

    __shared__ float sOff[8][256];
    __shared__ float sAw[8][128];
    __shared__ float sref[8][2];
    __shared__ float svrq[8][8];

    {
        const float* osrc = off + (size_t)bq0 * 256;
        #pragma unroll
        for (int i = 0; i < 2; i++) {
            int e = i * 1024 + tid * 4;
            *(float4*)&sOff[e >> 8][e & 255] = *(const float4*)(osrc + e);
        }
        int e2 = tid * 4;
        *(float4*)&sAw[e2 >> 7][e2 & 127] = *(const float4*)(aw + (size_t)bq0 * 128 + e2);
    }
    if (tid < 16) sref[tid >> 1][tid & 1] = ldv(refp, (size_t)(bq0 + (tid >> 1)) * 2 + (tid & 1), 2, ef);
    if (tid < 64) {
        int qi = tid >> 3, j = tid & 7;
        int b = (bq0 + qi) / NQ;
        svrq[qi][j] = ldv(vr, b * 8 + j, 2, ef);
    }
    __syncthreads();

    if (tid < 64) {
        int qi = tid >> 3, h = tid & 7;
        float* p = &sAw[qi][h * 16];
        float mx = -1e30f;
        #pragma unroll
        for (int j = 0; j < 16; j++) mx = fmaxf(mx, p[j]);
        float s = 0.f;
        #pragma unroll
        for (int j = 0; j < 16; j++) { float e = __expf(p[j] - mx); p[j] = e; s += e; }
        float inv = 1.f / s;
        #pragma unroll
        for (int j = 0; j < 16; j++) p[j] *= inv;
    }
    __syncthreads();

    const int qi = tid >> 5, sub = tid & 31;
    const int h = sub >> 2, cg = sub & 3;
    const int bq = bq0 + qi;
    const int b = bq / NQ;
    const bf16* vb = value + (size_t)b * NS * DM + h * DHEAD + cg * 8;

    float acc[8];
    #pragma unroll
    for (int j = 0; j < 8; j++) acc[j] = 0.f;

    const int HS[4] = {100, 50, 25, 13};
    const int ST[4] = {0, 10000, 12500, 13125};
    #pragma unroll
    for (int lvl = 0; lvl < 4; lvl++) {
        const int W_ = HS[lvl], H_ = HS[lvl], st = ST[lvl];
        float rx = sref[qi][0] * svrq[qi][lvl * 2 + 0] * (float)W_;
        float ry = sref[qi][1] * svrq[qi][lvl * 2 + 1] * (float)H_;
        #pragma unroll
        for (int p = 0; p < 4; p++) {
            int oi = h * 32 + lvl * 8 + p * 2;
            float x = fminf(fmaxf(rx + sOff[qi][oi]     - 0.5f, -4.f), (float)W_ + 4.f);
            float y = fminf(fmaxf(ry + sOff[qi][oi + 1] - 0.5f, -4.f), (float)H_ + 4.f);
            float x0f = floorf(x), y0f = floorf(y);
            float wx = x - x0f, wy = y - y0f;
            int x0 = (int)x0f, y0 = (int)y0f;
            int x1i = x0 + 1, y1i = y0 + 1;
            bool vx0 = (x0 >= 0) && (x0 < W_), vx1 = (x1i >= 0) && (x1i < W_);
            bool vy0 = (y0 >= 0) && (y0 < H_), vy1 = (y1i >= 0) && (y1i < H_);
            float g[8];
            #pragma unroll
            for (int j = 0; j < 8; j++) g[j] = 0.f;
            float t[8];
            if (vy0) {
                int rowo = (st + y0 * W_) * DM;
                if (vx0) {
                    uint4 u = *(const uint4*)(vb + rowo + x0 * DM);
                    unpack8(u, t);
                    float wgt = (1.f - wx) * (1.f - wy);
                    #pragma unroll
                    for (int j = 0; j < 8; j++) g[j] += wgt * t[j];
                }
                if (vx1) {
                    uint4 u = *(const uint4*)(vb + rowo + x1i * DM);
                    unpack8(u, t);
                    float wgt = wx * (1.f - wy);
                    #pragma unroll
                    for (int j = 0; j < 8; j++) g[j] += wgt * t[j];
                }
            }
            if (vy1) {
                int rowo = (st + y1i * W_) * DM;
                if (vx0) {
                    uint4 u = *(const uint4*)(vb + rowo + x0 * DM);
                    unpack8(u, t);
                    float wgt = (1.f - wx) * wy;
                    #pragma unroll
                    for (int j = 0; j < 8; j++) g[j] += wgt * t[j];
                }
                if (vx1) {
                    uint4 u = *(const uint4*)(vb + rowo + x1i * DM);
                    unpack8(u, t);
                    float wgt = wx * wy;
                    #pragma unroll
                    for (int j = 0; j < 8; j++) g[j] += wgt * t[j];
                }
            }
            float a = sAw[qi][h * 16 + lvl * 4 + p];
            #pragma unroll
            for (int j = 0; j < 8; j++) acc[j] += a * g[j];
        }
    }

    union { bf16 t[8]; uint4 u; } pk;
    #pragma unroll
    for (int j = 0; j < 8; j++) pk.t[j] = __float2bfloat16(acc[j]);
    *(uint4*)(out + (size_t)bq * DM + h * DHEAD + cg * 8) = pk.u;
}

// ---------------------------------------------------------------------------
__global__ __launch_bounds__(256) void copy_refs(const void* __restrict__ refp,
        void* __restrict__ out, const float* __restrict__ flagp)
{
    const bool ef = flagp[0] > 0.5f;
    int i = blockIdx.x * 256 + threadIdx.x;
    if (i >= NLAY * BQ * 2) return;
    float v = ldv(refp, i % (BQ * 2), 2, ef);
    size_t oi = (size_t)NLAY * BQ * DM + i;
    if (ef) ((float*)out)[oi] = v;
    else    ((bf16*)out)[oi] = __float2bfloat16(v);
}

// ---------------------------------------------------------------------------
extern "C" void kernel_launch(void* const* d_in, const int* in_sizes, int n_in,
                              void* d_out, int out_size, void* d_ws, size_t ws_size,
                              hipStream_t stream)
{
    const void* tgt     = d_in[0];
    const void* refp    = d_in[1];
    const void* memory  = d_in[2];
    const void* vr      = d_in[5];
    const void* qp      = d_in[6];
    const void* sa_in_w = d_in[7];
    const void* sa_in_b = d_in[8];
    const void* sa_out_w= d_in[9];
    const void* sa_out_b= d_in[10];
    const void* n1_g    = d_in[11];
    const void* n1_b    = d_in[12];
    const void* n2_g    = d_in[13];
    const void* n2_b    = d_in[14];
    const void* n3_g    = d_in[15];
    const void* n3_b    = d_in[16];
    const void* vp_w    = d_in[17];
    const void* vp_b    = d_in[18];
    const void* so_w    = d_in[19];
    const void* so_b    = d_in[20];
    const void* aw_w    = d_in[21];
    const void* aw_b    = d_in[22];
    const void* op_w    = d_in[23];
    const void* op_b    = d_in[24];
    const void* ff1_w   = d_in[25];
    const void* ff1_b   = d_in[26];
    const void* ff2_w   = d_in[27];
    const void* ff2_b   = d_in[28];

    // ---- workspace layout ----
    char* w = (char*)d_ws;
    float* flagp  = (float*)w;  w += 256;
    bf16*  value  = (bf16*)w;   w += (size_t)NB * NS * DM * 2;   // 54.45 MB
    float* outbuf = (float*)w;  w += (size_t)BQ * DM * 4;
    float* x1samp = (float*)w;  w += (size_t)BQ * DM * 4;
    bf16*  bigb   = (bf16*)w;   w += (size_t)BQ * NFF * 2;       // qkv / ffn hidden
    float* attoff = (float*)w;  w += (size_t)BQ * DM * 4;        // sampling offsets
    float* awb    = (float*)w;  w += (size_t)BQ * 128 * 4;       // aw logits
    bf16*  abuf   = (bf16*)w;   w += (size_t)BQ * DM * 2;        // x1/mha/msda bf16
    bf16*  outbf  = (bf16*)w;   w += (size_t)BQ * DM * 2;        // ln bf16 dup
    // pre-converted bf16 weights
    bf16* wb_sa_in = (bf16*)w;  w += (size_t)768 * 256 * 2;
    bf16* wb_sa_out= (bf16*)w;  w += (size_t)256 * 256 * 2;
    bf16* wb_soaw  = (bf16*)w;  w += (size_t)384 * 256 * 2;      // so(256) ++ aw(128)
    bf16* wb_op    = (bf16*)w;  w += (size_t)256 * 256 * 2;
    bf16* wb_ff1   = (bf16*)w;  w += (size_t)NFF * 256 * 2;
    bf16* wb_ff2   = (bf16*)w;  w += (size_t)256 * NFF * 2;
    bf16* wb_vp    = (bf16*)w;  w += (size_t)256 * 256 * 2;

    const int gy = (BQ + 31) / 32;      // 225
    const int MV = NB * NS;             // 106352

    // 0) detect external dtype, pre-convert weights to bf16
    detect_dtype<<<1, 256, 0, stream>>>(tgt, flagp);
    convert_w<<< 96, 256, 0, stream>>>(sa_in_w,  wb_sa_in,  flagp);
    convert_w<<< 32, 256, 0, stream>>>(sa_out_w, wb_sa_out, flagp);
    convert_w<<< 32, 256, 0, stream>>>(so_w,     wb_soaw,   flagp);
    convert_w<<< 16, 256, 0, stream>>>(aw_w,     wb_soaw + 256 * 256, flagp);
    convert_w<<< 32, 256, 0, stream>>>(op_w,     wb_op,     flagp);
    convert_w<<<128, 256, 0, stream>>>(ff1_w,    wb_ff1,    flagp);
    convert_w<<<128, 256, 0, stream>>>(ff2_w,    wb_ff2,    flagp);
    convert_w<<< 32, 256, 0, stream>>>(vp_w,     wb_vp,     flagp);

    // 1) value projection: W-in-registers GEMM, 2 blocks/CU
    gemm_vp<<<512, 256, 0, stream>>>(memory, wb_vp, vp_b, value, MV, flagp);

    // 2) inter_refs output
    copy_refs<<<(NLAY * BQ * 2 + 255) / 256, 256, 0, stream>>>(refp, d_out, flagp);

    // 3) x1 = tgt + query_pos (layer 0 only; later layers fused into ff2 LN)
    add_qpos<<<BQ * DM / 256, 256, 0, stream>>>(tgt, 2, qp, x1samp, abuf, flagp);

    for (int l = 0; l < NLAY; l++) {
        // self-attention
        gemm_a<<<dim3(768/256, gy), 256, 0, stream>>>(
            abuf, 1, wb_sa_in, sa_in_b, bigb, 1, BQ, 768, DM, 0, flagp);
        mha_mfma<<<dim3(15, NHEADS, NB), 256, 0, stream>>>(bigb, abuf);
        gemm_ln<<<dim3(1, gy), 256, 0, stream>>>(
            abuf, wb_sa_out, sa_out_b, x1samp, n1_g, n1_b,
            outbuf, outbf, nullptr, 0, nullptr, BQ, DM, flagp);

        // MSDA: fused so+aw GEMM, 8-query sampling w/ inline softmax, op+LN2
        gemm_soaw<<<dim3(3, gy), 256, 0, stream>>>(
            outbf, wb_soaw, so_b, aw_b, attoff, awb, BQ, flagp);
        msda_sample8<<<BQ / 8, 256, 0, stream>>>(value, attoff, awb, refp, vr, abuf, flagp);
        gemm_ln<<<dim3(1, gy), 256, 0, stream>>>(
            abuf, wb_op, op_b, outbuf, n2_g, n2_b,
            outbuf, outbf, nullptr, 0, nullptr, BQ, DM, flagp);

        // FFN: ff1 (relu, bf16 hidden), ff2 + LN3 + d_out slice + next x1(+qp)
        gemm_a<<<dim3(NFF/256, gy), 256, 0, stream>>>(
            outbf, 1, wb_ff1, ff1_b, bigb, 1, BQ, NFF, DM, 1, flagp);
        gemm_ln<<<dim3(1, gy), 256, 0, stream>>>(
            bigb, wb_ff2, ff2_b, outbuf, n3_g, n3_b,
            x1samp, abuf, d_out, (size_t)l * BQ * DM, qp, BQ, NFF, flagp);
    }
}